// Round 1
// baseline (2165.579 us; speedup 1.0000x reference)
//
#include <hip/hip_runtime.h>
#include <math.h>

#define NEG 0.2f
#define BNEPS 1e-5f
#define NGRAPH 64

// ---------- float <-> orderable uint encoding for atomic max ----------
__device__ __forceinline__ unsigned enc_f(float f) {
    unsigned u = __float_as_uint(f);
    return (u & 0x80000000u) ? ~u : (u | 0x80000000u);
}
__device__ __forceinline__ float dec_f(unsigned u) {
    return (u & 0x80000000u) ? __uint_as_float(u & 0x7FFFFFFFu)
                             : __uint_as_float(~u);
}

// ---------- generic f32 GEMM: C[M,Nc] = A[M,K]@W[K,Nc] (+bias) (+BN+ELU) ----------
// grid: (ceil(M/32), Nc/64), block 256. mode 0: +bias; mode 1: +bias, BN, ELU.
__global__ __launch_bounds__(256)
void gemm_f32(const float* __restrict__ A, int lda,
              const float* __restrict__ W, int Nc,
              const float* __restrict__ bias,
              float* __restrict__ C, int ldc,
              int M, int K, int mode,
              const float* __restrict__ bn_g, const float* __restrict__ bn_b,
              const float* __restrict__ bn_m, const float* __restrict__ bn_v)
{
    __shared__ __align__(16) float As[32][36];  // transposed tile: As[k][row]
    int col  = blockIdx.y * 64 + (threadIdx.x & 63);
    int rg   = threadIdx.x >> 6;   // 0..3, wave id -> row group
    int row0 = blockIdx.x * 32;
    float acc[8] = {0.f,0.f,0.f,0.f,0.f,0.f,0.f,0.f};

    for (int k0 = 0; k0 < K; k0 += 32) {
        for (int i = threadIdx.x; i < 1024; i += 256) {
            int r = i >> 5, c = i & 31;
            int gr = row0 + r;
            As[c][r] = (gr < M) ? A[(size_t)gr * lda + k0 + c] : 0.f;
        }
        __syncthreads();
        #pragma unroll
        for (int kk = 0; kk < 32; ++kk) {
            float w = W[(size_t)(k0 + kk) * Nc + col];
            const float4* ap = (const float4*)&As[kk][rg * 8];
            float4 a0 = ap[0], a1 = ap[1];
            acc[0] += a0.x * w; acc[1] += a0.y * w;
            acc[2] += a0.z * w; acc[3] += a0.w * w;
            acc[4] += a1.x * w; acc[5] += a1.y * w;
            acc[6] += a1.z * w; acc[7] += a1.w * w;
        }
        __syncthreads();
    }

    float bs = bias ? bias[col] : 0.f;
    float sg = 1.f, sb = 0.f;
    if (mode == 1) {
        sg = bn_g[col] / sqrtf(bn_v[col] + BNEPS);
        sb = bn_b[col] - bn_m[col] * sg;
    }
    #pragma unroll
    for (int r = 0; r < 8; ++r) {
        int row = row0 + rg * 8 + r;
        if (row < M) {
            float v = acc[r] + bs;
            if (mode == 1) {
                v = v * sg + sb;
                v = v > 0.f ? v : expf(v) - 1.f;   // ELU
            }
            C[(size_t)row * ldc + col] = v;
        }
    }
}

// ---------- per-node attention dot products: one wave per node ----------
__global__ __launch_bounds__(256)
void dots_kernel(const float* __restrict__ xh,
                 const float* __restrict__ att_s, const float* __restrict__ att_d,
                 float* __restrict__ as_n, float* __restrict__ ad_n, int N)
{
    int wid  = (blockIdx.x * blockDim.x + threadIdx.x) >> 6;
    int lane = threadIdx.x & 63;
    if (wid >= N) return;
    #pragma unroll
    for (int h = 0; h < 4; ++h) {
        float x  = xh[(size_t)wid * 256 + h * 64 + lane];
        float vs = x * att_s[h * 64 + lane];
        float vd = x * att_d[h * 64 + lane];
        #pragma unroll
        for (int off = 32; off; off >>= 1) {
            vs += __shfl_xor(vs, off);
            vd += __shfl_xor(vd, off);
        }
        if (lane == 0) { as_n[wid * 4 + h] = vs; ad_n[wid * 4 + h] = vd; }
    }
}

// ---------- edge pass A: segment max of leaky-relu logits ----------
__global__ __launch_bounds__(256)
void edge_max_kernel(const int* __restrict__ ei, int E, int N,
                     const float* __restrict__ as_n, const float* __restrict__ ad_n,
                     unsigned* __restrict__ segmax)
{
    int e = blockIdx.x * blockDim.x + threadIdx.x;
    int Etot = E + N;
    if (e >= Etot) return;
    int s, d;
    if (e < E) { s = ei[e]; d = ei[E + e]; } else { s = d = e - E; }
    #pragma unroll
    for (int h = 0; h < 4; ++h) {
        float logit = as_n[s * 4 + h] + ad_n[d * 4 + h];
        logit = logit >= 0.f ? logit : NEG * logit;
        atomicMax(&segmax[d * 4 + h], enc_f(logit));
    }
}

// ---------- edge pass B: accumulate sum(w) and sum(w * xh[src]) ----------
// one wave per edge, lane = channel within head
__global__ __launch_bounds__(256)
void edge_accum_kernel(const int* __restrict__ ei, int E, int N,
                       const float* __restrict__ as_n, const float* __restrict__ ad_n,
                       const unsigned* __restrict__ segmax,
                       float* __restrict__ segsum,
                       const float* __restrict__ xh,
                       float* __restrict__ agg)
{
    int w    = (blockIdx.x * blockDim.x + threadIdx.x) >> 6;
    int lane = threadIdx.x & 63;
    int Etot = E + N;
    if (w >= Etot) return;
    int s, d;
    if (w < E) { s = ei[w]; d = ei[E + w]; } else { s = d = w - E; }
    #pragma unroll
    for (int h = 0; h < 4; ++h) {
        float logit = as_n[s * 4 + h] + ad_n[d * 4 + h];
        logit = logit >= 0.f ? logit : NEG * logit;
        float wgt = expf(logit - dec_f(segmax[d * 4 + h]));
        if (lane == 0) atomicAdd(&segsum[d * 4 + h], wgt);
        atomicAdd(&agg[(size_t)d * 256 + h * 64 + lane],
                  wgt * xh[(size_t)s * 256 + h * 64 + lane]);
    }
}

// ---------- finalize layer 0: concat heads, divide by segsum, +bias (in place) ----------
__global__ __launch_bounds__(256)
void finalize_concat(float* __restrict__ agg, const float* __restrict__ segsum,
                     const float* __restrict__ bias, int N)
{
    int idx = blockIdx.x * blockDim.x + threadIdx.x;
    if (idx >= N * 256) return;
    int n = idx >> 8, t = idx & 255, h = t >> 6;
    agg[idx] = agg[idx] / segsum[n * 4 + h] + bias[t];
}

// ---------- finalize layers 1/2: mean heads, +bias, BN, ELU, +residual ----------
__global__ __launch_bounds__(256)
void finalize_mean(const float* __restrict__ agg, const float* __restrict__ segsum,
                   const float* __restrict__ bias,
                   const float* __restrict__ bn_g, const float* __restrict__ bn_b,
                   const float* __restrict__ bn_m, const float* __restrict__ bn_v,
                   const float* __restrict__ resid,   // stride 192
                   float* __restrict__ outp,          // stride 192
                   int N)
{
    int idx = blockIdx.x * blockDim.x + threadIdx.x;
    if (idx >= N * 64) return;
    int n = idx >> 6, c = idx & 63;
    float s = 0.f;
    #pragma unroll
    for (int h = 0; h < 4; ++h)
        s += agg[(size_t)n * 256 + h * 64 + c] / segsum[n * 4 + h];
    float v = 0.25f * s + bias[c];
    float sg = bn_g[c] / sqrtf(bn_v[c] + BNEPS);
    v = (v - bn_m[c]) * sg + bn_b[c];
    v = v > 0.f ? v : expf(v) - 1.f;
    v += resid[(size_t)n * 192 + c];
    outp[(size_t)n * 192 + c] = v;
}

// ---------- per-node pooling logits: one wave per node ----------
__global__ __launch_bounds__(256)
void att_logit_kernel(const float* __restrict__ hjk, const float* __restrict__ attW,
                      const float* __restrict__ attb, float* __restrict__ l, int N)
{
    int wid  = (blockIdx.x * blockDim.x + threadIdx.x) >> 6;
    int lane = threadIdx.x & 63;
    if (wid >= N) return;
    float v = hjk[(size_t)wid * 64 + lane] * attW[lane];
    #pragma unroll
    for (int off = 32; off; off >>= 1) v += __shfl_xor(v, off);
    if (lane == 0) l[wid] = v + attb[0];
}

// ---------- graph boundaries (batch is sorted) ----------
__global__ void gstart_kernel(const int* __restrict__ batch, int N, int* __restrict__ gstart)
{
    int t = threadIdx.x;
    if (t > NGRAPH) return;
    int lo = 0, hi = N;
    while (lo < hi) {
        int mid = (lo + hi) >> 1;
        if (batch[mid] < t) lo = mid + 1; else hi = mid;
    }
    gstart[t] = lo;
}

// ---------- attention pooling: one block per graph ----------
__global__ __launch_bounds__(256)
void pool_kernel(const float* __restrict__ hjk, const float* __restrict__ l,
                 const int* __restrict__ gstart, float* __restrict__ hg)
{
    int g = blockIdx.x;
    int s0 = gstart[g], s1 = gstart[g + 1];
    __shared__ float red[256];
    int tid = threadIdx.x;

    float m = -INFINITY;
    for (int n = s0 + tid; n < s1; n += 256) m = fmaxf(m, l[n]);
    red[tid] = m; __syncthreads();
    for (int o = 128; o; o >>= 1) {
        if (tid < o) red[tid] = fmaxf(red[tid], red[tid + o]);
        __syncthreads();
    }
    m = red[0]; __syncthreads();

    float ssum = 0.f;
    for (int n = s0 + tid; n < s1; n += 256) ssum += expf(l[n] - m);
    red[tid] = ssum; __syncthreads();
    for (int o = 128; o; o >>= 1) {
        if (tid < o) red[tid] += red[tid + o];
        __syncthreads();
    }
    float ssal = red[0]; __syncthreads();

    int c = tid & 63, q = tid >> 6;
    float acc = 0.f;
    for (int n = s0 + q; n < s1; n += 4)
        acc += expf(l[n] - m) * hjk[(size_t)n * 64 + c];
    red[tid] = acc; __syncthreads();
    if (q == 0) {
        float v = red[c] + red[64 + c] + red[128 + c] + red[192 + c];
        hg[g * 64 + c] = (s1 > s0) ? v / ssal : 0.f;
    }
}

// ---------- classifier head: one block (32 threads) per graph ----------
__global__ void cls_kernel(const float* __restrict__ hg,
                           const float* __restrict__ W1, const float* __restrict__ b1,
                           const float* __restrict__ W2, const float* __restrict__ b2,
                           float* __restrict__ out)
{
    int g = blockIdx.x, t = threadIdx.x;  // 32 threads
    __shared__ float z[32];
    float acc = b1[t];
    for (int k = 0; k < 64; ++k) acc += hg[g * 64 + k] * W1[k * 32 + t];
    z[t] = fmaxf(acc, 0.f);
    __syncthreads();
    if (t < 2) {
        float o = b2[t];
        for (int j = 0; j < 32; ++j) o += z[j] * W2[j * 2 + t];
        out[g * 2 + t] = o;
    }
}

extern "C" void kernel_launch(void* const* d_in, const int* in_sizes, int n_in,
                              void* d_out, int out_size, void* d_ws, size_t ws_size,
                              hipStream_t stream)
{
    const float* x        = (const float*)d_in[0];
    const int*   ei       = (const int*)d_in[1];
    const int*   batch    = (const int*)d_in[2];
    const float* conv0_W  = (const float*)d_in[3];
    const float* conv0_as = (const float*)d_in[4];
    const float* conv0_ad = (const float*)d_in[5];
    const float* conv0_b  = (const float*)d_in[6];
    const float* pre0_W   = (const float*)d_in[7];
    const float* pre0_b   = (const float*)d_in[8];
    const float* convs_W  = (const float*)d_in[9];
    const float* convs_as = (const float*)d_in[10];
    const float* convs_ad = (const float*)d_in[11];
    const float* convs_b  = (const float*)d_in[12];
    const float* bn_g     = (const float*)d_in[13];
    const float* bn_b     = (const float*)d_in[14];
    const float* bn_m     = (const float*)d_in[15];
    const float* bn_v     = (const float*)d_in[16];
    const float* jump_W   = (const float*)d_in[17];
    const float* jump_b   = (const float*)d_in[18];
    const float* att_W    = (const float*)d_in[19];
    const float* att_b    = (const float*)d_in[20];
    const float* cls_W1   = (const float*)d_in[21];
    const float* cls_b1   = (const float*)d_in[22];
    const float* cls_W2   = (const float*)d_in[23];
    const float* cls_b2   = (const float*)d_in[24];
    float* out = (float*)d_out;

    const int N = in_sizes[0] / 128;   // 50000
    const int E = in_sizes[1] / 2;     // 400000
    const int Etot = E + N;

    // workspace layout
    float* ws      = (float*)d_ws;
    float* xh      = ws;                                 // N*256
    float* agg     = xh + (size_t)N * 256;               // N*256 (also h256 in place)
    float* repsAll = agg + (size_t)N * 256;              // N*192
    float* as_n    = repsAll + (size_t)N * 192;          // N*4
    float* ad_n    = as_n + (size_t)N * 4;               // N*4
    unsigned* segmax = (unsigned*)(ad_n + (size_t)N * 4);// N*4
    float* segsum  = (float*)(segmax + (size_t)N * 4);   // N*4
    float* hg      = segsum + (size_t)N * 4;             // 64*64
    int*   gstart  = (int*)(hg + NGRAPH * 64);           // 65
    float* hjk     = xh;    // reuse (xh free after layer GEMMs)
    float* lbuf    = as_n;  // reuse (free after last layer)

    dim3 blk(256);
    int dot_blocks  = (N + 3) / 4;
    int emax_blocks = (Etot + 255) / 256;
    int eacc_blocks = (Etot + 3) / 4;

    // ---------------- layer 0 ----------------
    {
        dim3 g1((N + 31) / 32, 4);
        gemm_f32<<<g1, blk, 0, stream>>>(x, 128, conv0_W, 256, nullptr, xh, 256,
                                         N, 128, 0, nullptr, nullptr, nullptr, nullptr);
        dots_kernel<<<dot_blocks, blk, 0, stream>>>(xh, conv0_as, conv0_ad, as_n, ad_n, N);
        hipMemsetAsync(segmax, 0, (size_t)N * 4 * sizeof(unsigned), stream);
        hipMemsetAsync(segsum, 0, (size_t)N * 4 * sizeof(float), stream);
        hipMemsetAsync(agg, 0, (size_t)N * 256 * sizeof(float), stream);
        edge_max_kernel<<<emax_blocks, blk, 0, stream>>>(ei, E, N, as_n, ad_n, segmax);
        edge_accum_kernel<<<eacc_blocks, blk, 0, stream>>>(ei, E, N, as_n, ad_n, segmax,
                                                           segsum, xh, agg);
        finalize_concat<<<(N * 256 + 255) / 256, blk, 0, stream>>>(agg, segsum, conv0_b, N);
        dim3 g2((N + 31) / 32, 1);
        gemm_f32<<<g2, blk, 0, stream>>>(agg, 256, pre0_W, 64, pre0_b, repsAll, 192,
                                         N, 256, 1, bn_g, bn_b, bn_m, bn_v);
    }

    // ---------------- layers 1, 2 ----------------
    for (int i = 0; i < 2; ++i) {
        dim3 g1((N + 31) / 32, 4);
        gemm_f32<<<g1, blk, 0, stream>>>(repsAll + i * 64, 192,
                                         convs_W + (size_t)i * 64 * 256, 256, nullptr,
                                         xh, 256, N, 64, 0, nullptr, nullptr, nullptr, nullptr);
        dots_kernel<<<dot_blocks, blk, 0, stream>>>(xh, convs_as + i * 256,
                                                    convs_ad + i * 256, as_n, ad_n, N);
        hipMemsetAsync(segmax, 0, (size_t)N * 4 * sizeof(unsigned), stream);
        hipMemsetAsync(segsum, 0, (size_t)N * 4 * sizeof(float), stream);
        hipMemsetAsync(agg, 0, (size_t)N * 256 * sizeof(float), stream);
        edge_max_kernel<<<emax_blocks, blk, 0, stream>>>(ei, E, N, as_n, ad_n, segmax);
        edge_accum_kernel<<<eacc_blocks, blk, 0, stream>>>(ei, E, N, as_n, ad_n, segmax,
                                                           segsum, xh, agg);
        finalize_mean<<<(N * 64 + 255) / 256, blk, 0, stream>>>(
            agg, segsum, convs_b + i * 64,
            bn_g + (i + 1) * 64, bn_b + (i + 1) * 64,
            bn_m + (i + 1) * 64, bn_v + (i + 1) * 64,
            repsAll + i * 64, repsAll + (i + 1) * 64, N);
    }

    // ---------------- JK projection ----------------
    {
        dim3 g2((N + 31) / 32, 1);
        gemm_f32<<<g2, blk, 0, stream>>>(repsAll, 192, jump_W, 64, jump_b, hjk, 64,
                                         N, 192, 0, nullptr, nullptr, nullptr, nullptr);
    }

    // ---------------- pooling + classifier ----------------
    att_logit_kernel<<<dot_blocks, blk, 0, stream>>>(hjk, att_W, att_b, lbuf, N);
    gstart_kernel<<<1, 128, 0, stream>>>(batch, N, gstart);
    pool_kernel<<<NGRAPH, blk, 0, stream>>>(hjk, lbuf, gstart, hg);
    cls_kernel<<<NGRAPH, 32, 0, stream>>>(hg, cls_W1, cls_b1, cls_W2, cls_b2, out);
}

// Round 2
// 900.584 us; speedup vs baseline: 2.4046x; 2.4046x over previous
//
#include <hip/hip_runtime.h>
#include <math.h>

#define NEG 0.2f
#define BNEPS 1e-5f
#define NGRAPH 64

// ---------- generic f32 GEMM: C[M,Nc] = A[M,K]@W[K,Nc] (+bias) (+BN+ELU) ----------
// grid: (ceil(M/32), Nc/64), block 256. mode 0: +bias; mode 1: +bias, BN, ELU.
__global__ __launch_bounds__(256)
void gemm_f32(const float* __restrict__ A, int lda,
              const float* __restrict__ W, int Nc,
              const float* __restrict__ bias,
              float* __restrict__ C, int ldc,
              int M, int K, int mode,
              const float* __restrict__ bn_g, const float* __restrict__ bn_b,
              const float* __restrict__ bn_m, const float* __restrict__ bn_v)
{
    __shared__ __align__(16) float As[32][36];  // transposed tile: As[k][row]
    int col  = blockIdx.y * 64 + (threadIdx.x & 63);
    int rg   = threadIdx.x >> 6;   // 0..3, wave id -> row group
    int row0 = blockIdx.x * 32;
    float acc[8] = {0.f,0.f,0.f,0.f,0.f,0.f,0.f,0.f};

    for (int k0 = 0; k0 < K; k0 += 32) {
        for (int i = threadIdx.x; i < 1024; i += 256) {
            int r = i >> 5, c = i & 31;
            int gr = row0 + r;
            As[c][r] = (gr < M) ? A[(size_t)gr * lda + k0 + c] : 0.f;
        }
        __syncthreads();
        #pragma unroll
        for (int kk = 0; kk < 32; ++kk) {
            float w = W[(size_t)(k0 + kk) * Nc + col];
            const float4* ap = (const float4*)&As[kk][rg * 8];
            float4 a0 = ap[0], a1 = ap[1];
            acc[0] += a0.x * w; acc[1] += a0.y * w;
            acc[2] += a0.z * w; acc[3] += a0.w * w;
            acc[4] += a1.x * w; acc[5] += a1.y * w;
            acc[6] += a1.z * w; acc[7] += a1.w * w;
        }
        __syncthreads();
    }

    float bs = bias ? bias[col] : 0.f;
    float sg = 1.f, sb = 0.f;
    if (mode == 1) {
        sg = bn_g[col] / sqrtf(bn_v[col] + BNEPS);
        sb = bn_b[col] - bn_m[col] * sg;
    }
    #pragma unroll
    for (int r = 0; r < 8; ++r) {
        int row = row0 + rg * 8 + r;
        if (row < M) {
            float v = acc[r] + bs;
            if (mode == 1) {
                v = v * sg + sb;
                v = v > 0.f ? v : expf(v) - 1.f;   // ELU
            }
            C[(size_t)row * ldc + col] = v;
        }
    }
}

// ---------- per-node attention dot products: one wave per node ----------
__global__ __launch_bounds__(256)
void dots_kernel(const float* __restrict__ xh,
                 const float* __restrict__ att_s, const float* __restrict__ att_d,
                 float* __restrict__ as_n, float* __restrict__ ad_n, int N)
{
    int wid  = (blockIdx.x * blockDim.x + threadIdx.x) >> 6;
    int lane = threadIdx.x & 63;
    if (wid >= N) return;
    #pragma unroll
    for (int h = 0; h < 4; ++h) {
        float x  = xh[(size_t)wid * 256 + h * 64 + lane];
        float vs = x * att_s[h * 64 + lane];
        float vd = x * att_d[h * 64 + lane];
        #pragma unroll
        for (int off = 32; off; off >>= 1) {
            vs += __shfl_xor(vs, off);
            vd += __shfl_xor(vd, off);
        }
        if (lane == 0) { as_n[wid * 4 + h] = vs; ad_n[wid * 4 + h] = vd; }
    }
}

// ---------- CSR build: histogram over dst ----------
__global__ __launch_bounds__(256)
void hist_kernel(const int* __restrict__ ei, int E, int N, int* __restrict__ counts)
{
    int e = blockIdx.x * blockDim.x + threadIdx.x;
    int Etot = E + N;
    if (e >= Etot) return;
    int d = (e < E) ? ei[E + e] : e - E;
    atomicAdd(&counts[d], 1);
}

// ---------- CSR build: single-block exclusive scan (N ~ 50k) ----------
__global__ __launch_bounds__(1024)
void scan_kernel(const int* __restrict__ counts, int N,
                 int* __restrict__ rowptr, int* __restrict__ cursor)
{
    __shared__ int lds[1024];
    __shared__ int carry;
    int tid = threadIdx.x;
    if (tid == 0) carry = 0;
    __syncthreads();
    for (int base = 0; base < N; base += 1024) {
        int v = (base + tid < N) ? counts[base + tid] : 0;
        lds[tid] = v; __syncthreads();
        #pragma unroll
        for (int o = 1; o < 1024; o <<= 1) {
            int t = (tid >= o) ? lds[tid - o] : 0;
            __syncthreads();
            lds[tid] += t;
            __syncthreads();
        }
        int excl = lds[tid] - v;
        if (base + tid < N) {
            rowptr[base + tid] = carry + excl;
            cursor[base + tid] = carry + excl;
        }
        int tot = lds[1023];
        __syncthreads();
        if (tid == 0) carry += tot;
        __syncthreads();
    }
    if (tid == 0) rowptr[N] = carry;
}

// ---------- CSR build: scatter src ids into buckets ----------
__global__ __launch_bounds__(256)
void scatter_kernel(const int* __restrict__ ei, int E, int N,
                    int* __restrict__ cursor, int* __restrict__ csr_src)
{
    int e = blockIdx.x * blockDim.x + threadIdx.x;
    int Etot = E + N;
    if (e >= Etot) return;
    int s, d;
    if (e < E) { s = ei[e]; d = ei[E + e]; } else { s = d = e - E; }
    int pos = atomicAdd(&cursor[d], 1);
    csr_src[pos] = s;
}

// ---------- fused per-node GAT aggregation (softmax + weighted sum + epilogue) ----------
// one wave per node; lane = channel within head (64 ch x 4 heads).
// mode 0: concat heads -> out[node*256 + h*64+lane] = acc/wsum + bias[h*64+lane]
// mode 1: mean heads -> +bias, BN, ELU, +resid -> outp[node*ldo + lane]
__global__ __launch_bounds__(256)
void aggregate_kernel(const int* __restrict__ rowptr, const int* __restrict__ csr_src,
                      const float* __restrict__ as_n, const float* __restrict__ ad_n,
                      const float* __restrict__ xh,
                      const float* __restrict__ bias,
                      float* __restrict__ outp, int ldo,
                      int N, int mode,
                      const float* __restrict__ bn_g, const float* __restrict__ bn_b,
                      const float* __restrict__ bn_m, const float* __restrict__ bn_v,
                      const float* __restrict__ resid)
{
    int node = (blockIdx.x * blockDim.x + threadIdx.x) >> 6;
    int lane = threadIdx.x & 63;
    if (node >= N) return;
    int e0 = rowptr[node], e1 = rowptr[node + 1];

    float4 adv = ((const float4*)ad_n)[node];

    // pass 1: per-head max over incoming edges (lanes parallel over edges)
    float mx0 = -INFINITY, mx1 = -INFINITY, mx2 = -INFINITY, mx3 = -INFINITY;
    for (int e = e0 + lane; e < e1; e += 64) {
        int s = csr_src[e];
        float4 asv = ((const float4*)as_n)[s];
        float l0 = asv.x + adv.x; l0 = l0 >= 0.f ? l0 : NEG * l0;
        float l1 = asv.y + adv.y; l1 = l1 >= 0.f ? l1 : NEG * l1;
        float l2 = asv.z + adv.z; l2 = l2 >= 0.f ? l2 : NEG * l2;
        float l3 = asv.w + adv.w; l3 = l3 >= 0.f ? l3 : NEG * l3;
        mx0 = fmaxf(mx0, l0); mx1 = fmaxf(mx1, l1);
        mx2 = fmaxf(mx2, l2); mx3 = fmaxf(mx3, l3);
    }
    #pragma unroll
    for (int off = 32; off; off >>= 1) {
        mx0 = fmaxf(mx0, __shfl_xor(mx0, off));
        mx1 = fmaxf(mx1, __shfl_xor(mx1, off));
        mx2 = fmaxf(mx2, __shfl_xor(mx2, off));
        mx3 = fmaxf(mx3, __shfl_xor(mx3, off));
    }

    // pass 2: weighted accumulation (lanes cooperate per edge across channels)
    float acc0 = 0.f, acc1 = 0.f, acc2 = 0.f, acc3 = 0.f;
    float ws0 = 0.f, ws1 = 0.f, ws2 = 0.f, ws3 = 0.f;
    for (int e = e0; e < e1; ++e) {
        int s = csr_src[e];
        float4 asv = ((const float4*)as_n)[s];
        float l0 = asv.x + adv.x; l0 = l0 >= 0.f ? l0 : NEG * l0;
        float l1 = asv.y + adv.y; l1 = l1 >= 0.f ? l1 : NEG * l1;
        float l2 = asv.z + adv.z; l2 = l2 >= 0.f ? l2 : NEG * l2;
        float l3 = asv.w + adv.w; l3 = l3 >= 0.f ? l3 : NEG * l3;
        float w0 = expf(l0 - mx0), w1 = expf(l1 - mx1);
        float w2 = expf(l2 - mx2), w3 = expf(l3 - mx3);
        const float* xs = xh + (size_t)s * 256 + lane;
        acc0 += w0 * xs[0];
        acc1 += w1 * xs[64];
        acc2 += w2 * xs[128];
        acc3 += w3 * xs[192];
        ws0 += w0; ws1 += w1; ws2 += w2; ws3 += w3;
    }

    if (mode == 0) {
        float* o = outp + (size_t)node * 256 + lane;
        o[0]   = acc0 / ws0 + bias[lane];
        o[64]  = acc1 / ws1 + bias[64 + lane];
        o[128] = acc2 / ws2 + bias[128 + lane];
        o[192] = acc3 / ws3 + bias[192 + lane];
    } else {
        float v = 0.25f * (acc0 / ws0 + acc1 / ws1 + acc2 / ws2 + acc3 / ws3)
                  + bias[lane];
        float sg = bn_g[lane] / sqrtf(bn_v[lane] + BNEPS);
        v = (v - bn_m[lane]) * sg + bn_b[lane];
        v = v > 0.f ? v : expf(v) - 1.f;
        v += resid[(size_t)node * ldo + lane];
        outp[(size_t)node * ldo + lane] = v;
    }
}

// ---------- per-node pooling logits: one wave per node ----------
__global__ __launch_bounds__(256)
void att_logit_kernel(const float* __restrict__ hjk, const float* __restrict__ attW,
                      const float* __restrict__ attb, float* __restrict__ l, int N)
{
    int wid  = (blockIdx.x * blockDim.x + threadIdx.x) >> 6;
    int lane = threadIdx.x & 63;
    if (wid >= N) return;
    float v = hjk[(size_t)wid * 64 + lane] * attW[lane];
    #pragma unroll
    for (int off = 32; off; off >>= 1) v += __shfl_xor(v, off);
    if (lane == 0) l[wid] = v + attb[0];
}

// ---------- graph boundaries (batch is sorted) ----------
__global__ void gstart_kernel(const int* __restrict__ batch, int N, int* __restrict__ gstart)
{
    int t = threadIdx.x;
    if (t > NGRAPH) return;
    int lo = 0, hi = N;
    while (lo < hi) {
        int mid = (lo + hi) >> 1;
        if (batch[mid] < t) lo = mid + 1; else hi = mid;
    }
    gstart[t] = lo;
}

// ---------- attention pooling: one block per graph ----------
__global__ __launch_bounds__(256)
void pool_kernel(const float* __restrict__ hjk, const float* __restrict__ l,
                 const int* __restrict__ gstart, float* __restrict__ hg)
{
    int g = blockIdx.x;
    int s0 = gstart[g], s1 = gstart[g + 1];
    __shared__ float red[256];
    int tid = threadIdx.x;

    float m = -INFINITY;
    for (int n = s0 + tid; n < s1; n += 256) m = fmaxf(m, l[n]);
    red[tid] = m; __syncthreads();
    for (int o = 128; o; o >>= 1) {
        if (tid < o) red[tid] = fmaxf(red[tid], red[tid + o]);
        __syncthreads();
    }
    m = red[0]; __syncthreads();

    float ssum = 0.f;
    for (int n = s0 + tid; n < s1; n += 256) ssum += expf(l[n] - m);
    red[tid] = ssum; __syncthreads();
    for (int o = 128; o; o >>= 1) {
        if (tid < o) red[tid] += red[tid + o];
        __syncthreads();
    }
    float ssal = red[0]; __syncthreads();

    int c = tid & 63, q = tid >> 6;
    float acc = 0.f;
    for (int n = s0 + q; n < s1; n += 4)
        acc += expf(l[n] - m) * hjk[(size_t)n * 64 + c];
    red[tid] = acc; __syncthreads();
    if (q == 0) {
        float v = red[c] + red[64 + c] + red[128 + c] + red[192 + c];
        hg[g * 64 + c] = (s1 > s0) ? v / ssal : 0.f;
    }
}

// ---------- classifier head: one block (32 threads) per graph ----------
__global__ void cls_kernel(const float* __restrict__ hg,
                           const float* __restrict__ W1, const float* __restrict__ b1,
                           const float* __restrict__ W2, const float* __restrict__ b2,
                           float* __restrict__ out)
{
    int g = blockIdx.x, t = threadIdx.x;  // 32 threads
    __shared__ float z[32];
    float acc = b1[t];
    for (int k = 0; k < 64; ++k) acc += hg[g * 64 + k] * W1[k * 32 + t];
    z[t] = fmaxf(acc, 0.f);
    __syncthreads();
    if (t < 2) {
        float o = b2[t];
        for (int j = 0; j < 32; ++j) o += z[j] * W2[j * 2 + t];
        out[g * 2 + t] = o;
    }
}

extern "C" void kernel_launch(void* const* d_in, const int* in_sizes, int n_in,
                              void* d_out, int out_size, void* d_ws, size_t ws_size,
                              hipStream_t stream)
{
    const float* x        = (const float*)d_in[0];
    const int*   ei       = (const int*)d_in[1];
    const int*   batch    = (const int*)d_in[2];
    const float* conv0_W  = (const float*)d_in[3];
    const float* conv0_as = (const float*)d_in[4];
    const float* conv0_ad = (const float*)d_in[5];
    const float* conv0_b  = (const float*)d_in[6];
    const float* pre0_W   = (const float*)d_in[7];
    const float* pre0_b   = (const float*)d_in[8];
    const float* convs_W  = (const float*)d_in[9];
    const float* convs_as = (const float*)d_in[10];
    const float* convs_ad = (const float*)d_in[11];
    const float* convs_b  = (const float*)d_in[12];
    const float* bn_g     = (const float*)d_in[13];
    const float* bn_b     = (const float*)d_in[14];
    const float* bn_m     = (const float*)d_in[15];
    const float* bn_v     = (const float*)d_in[16];
    const float* jump_W   = (const float*)d_in[17];
    const float* jump_b   = (const float*)d_in[18];
    const float* att_W    = (const float*)d_in[19];
    const float* att_b    = (const float*)d_in[20];
    const float* cls_W1   = (const float*)d_in[21];
    const float* cls_b1   = (const float*)d_in[22];
    const float* cls_W2   = (const float*)d_in[23];
    const float* cls_b2   = (const float*)d_in[24];
    float* out = (float*)d_out;

    const int N = in_sizes[0] / 128;   // 50000
    const int E = in_sizes[1] / 2;     // 400000
    const int Etot = E + N;

    // workspace layout
    float* ws      = (float*)d_ws;
    float* xh      = ws;                                 // N*256
    float* h256    = xh + (size_t)N * 256;               // N*256 (layer-0 concat out)
    float* repsAll = h256 + (size_t)N * 256;             // N*192
    float* as_n    = repsAll + (size_t)N * 192;          // N*4
    float* ad_n    = as_n + (size_t)N * 4;               // N*4
    float* hg      = ad_n + (size_t)N * 4;               // 64*64
    int*   rowptr  = (int*)(hg + NGRAPH * 64);           // N+1
    int*   cursor  = rowptr + (N + 1);                   // N
    int*   counts  = cursor + N;                         // N
    int*   csr_src = counts + N;                         // Etot
    int*   gstart  = csr_src + Etot;                     // 65
    float* hjk     = xh;    // reuse (xh free after last aggregate)
    float* lbuf    = as_n;  // reuse

    dim3 blk(256);
    int node_wave_blocks = (N + 3) / 4;          // 1 wave/node
    int edge_blocks      = (Etot + 255) / 256;

    // ---------------- CSR build (graph is layer-invariant) ----------------
    hipMemsetAsync(counts, 0, (size_t)N * sizeof(int), stream);
    hist_kernel<<<edge_blocks, blk, 0, stream>>>(ei, E, N, counts);
    scan_kernel<<<1, 1024, 0, stream>>>(counts, N, rowptr, cursor);
    scatter_kernel<<<edge_blocks, blk, 0, stream>>>(ei, E, N, cursor, csr_src);

    // ---------------- layer 0 ----------------
    {
        dim3 g1((N + 31) / 32, 4);
        gemm_f32<<<g1, blk, 0, stream>>>(x, 128, conv0_W, 256, nullptr, xh, 256,
                                         N, 128, 0, nullptr, nullptr, nullptr, nullptr);
        dots_kernel<<<node_wave_blocks, blk, 0, stream>>>(xh, conv0_as, conv0_ad, as_n, ad_n, N);
        aggregate_kernel<<<node_wave_blocks, blk, 0, stream>>>(
            rowptr, csr_src, as_n, ad_n, xh, conv0_b, h256, 256, N, 0,
            nullptr, nullptr, nullptr, nullptr, nullptr);
        dim3 g2((N + 31) / 32, 1);
        gemm_f32<<<g2, blk, 0, stream>>>(h256, 256, pre0_W, 64, pre0_b, repsAll, 192,
                                         N, 256, 1, bn_g, bn_b, bn_m, bn_v);
    }

    // ---------------- layers 1, 2 ----------------
    for (int i = 0; i < 2; ++i) {
        dim3 g1((N + 31) / 32, 4);
        gemm_f32<<<g1, blk, 0, stream>>>(repsAll + i * 64, 192,
                                         convs_W + (size_t)i * 64 * 256, 256, nullptr,
                                         xh, 256, N, 64, 0, nullptr, nullptr, nullptr, nullptr);
        dots_kernel<<<node_wave_blocks, blk, 0, stream>>>(xh, convs_as + i * 256,
                                                          convs_ad + i * 256, as_n, ad_n, N);
        aggregate_kernel<<<node_wave_blocks, blk, 0, stream>>>(
            rowptr, csr_src, as_n, ad_n, xh, convs_b + i * 64,
            repsAll + (i + 1) * 64, 192, N, 1,
            bn_g + (i + 1) * 64, bn_b + (i + 1) * 64,
            bn_m + (i + 1) * 64, bn_v + (i + 1) * 64,
            repsAll + i * 64);
    }

    // ---------------- JK projection ----------------
    {
        dim3 g2((N + 31) / 32, 1);
        gemm_f32<<<g2, blk, 0, stream>>>(repsAll, 192, jump_W, 64, jump_b, hjk, 64,
                                         N, 192, 0, nullptr, nullptr, nullptr, nullptr);
    }

    // ---------------- pooling + classifier ----------------
    att_logit_kernel<<<node_wave_blocks, blk, 0, stream>>>(hjk, att_W, att_b, lbuf, N);
    gstart_kernel<<<1, 128, 0, stream>>>(batch, N, gstart);
    pool_kernel<<<NGRAPH, blk, 0, stream>>>(hjk, lbuf, gstart, hg);
    cls_kernel<<<NGRAPH, 32, 0, stream>>>(hg, cls_W1, cls_b1, cls_W2, cls_b2, out);
}

// Round 3
// 770.336 us; speedup vs baseline: 2.8112x; 1.1691x over previous
//
#include <hip/hip_runtime.h>
#include <math.h>

#define NEG 0.2f
#define BNEPS 1e-5f
#define NGRAPH 64

// ---------- f32 GEMM: C[M,Nc] = A[M,K]@W[K,Nc] (+bias) (+BN+ELU) ----------
// 64x64 tile per 256-thread block, 16 outputs/thread.
// grid: (ceil(M/64), Nc/64). K must be a multiple of 32.
__global__ __launch_bounds__(256)
void gemm_f32(const float* __restrict__ A, int lda,
              const float* __restrict__ W, int Nc,
              const float* __restrict__ bias,
              float* __restrict__ C, int ldc,
              int M, int K, int mode,
              const float* __restrict__ bn_g, const float* __restrict__ bn_b,
              const float* __restrict__ bn_m, const float* __restrict__ bn_v)
{
    __shared__ __align__(16) float As[32][68];  // As[k][row]
    __shared__ __align__(16) float Ws[32][68];  // Ws[k][col]
    int tid  = threadIdx.x;
    int lane = tid & 63, wave = tid >> 6;
    int row0 = blockIdx.x * 64;
    int colb = blockIdx.y * 64;
    int r4 = wave * 16 + (lane >> 4) * 4;   // tile-local row base (4 rows)
    int c4 = (lane & 15) * 4;               // tile-local col base (4 cols)

    float4 acc[4];
    #pragma unroll
    for (int i = 0; i < 4; ++i) acc[i] = make_float4(0.f, 0.f, 0.f, 0.f);

    // staging coords
    int ar = tid & 63, akq = (tid >> 6) * 8;          // A: row, k-quad
    int wk = tid >> 3, wcq = (tid & 7) * 8;           // W: k, col-quad

    for (int k0 = 0; k0 < K; k0 += 32) {
        // stage A (64 rows x 32 k, transposed)
        int gr = row0 + ar;
        float4 av0, av1;
        if (gr < M) {
            const float* ap = A + (size_t)gr * lda + k0 + akq;
            av0 = *(const float4*)ap;
            av1 = *(const float4*)(ap + 4);
        } else {
            av0 = make_float4(0.f,0.f,0.f,0.f);
            av1 = av0;
        }
        As[akq + 0][ar] = av0.x; As[akq + 1][ar] = av0.y;
        As[akq + 2][ar] = av0.z; As[akq + 3][ar] = av0.w;
        As[akq + 4][ar] = av1.x; As[akq + 5][ar] = av1.y;
        As[akq + 6][ar] = av1.z; As[akq + 7][ar] = av1.w;
        // stage W (32 k x 64 cols)
        const float* wp = W + (size_t)(k0 + wk) * Nc + colb + wcq;
        *(float4*)&Ws[wk][wcq]     = *(const float4*)wp;
        *(float4*)&Ws[wk][wcq + 4] = *(const float4*)(wp + 4);
        __syncthreads();

        #pragma unroll
        for (int kk = 0; kk < 32; ++kk) {
            float4 a = *(const float4*)&As[kk][r4];
            float4 b = *(const float4*)&Ws[kk][c4];
            acc[0].x += a.x * b.x; acc[0].y += a.x * b.y; acc[0].z += a.x * b.z; acc[0].w += a.x * b.w;
            acc[1].x += a.y * b.x; acc[1].y += a.y * b.y; acc[1].z += a.y * b.z; acc[1].w += a.y * b.w;
            acc[2].x += a.z * b.x; acc[2].y += a.z * b.y; acc[2].z += a.z * b.z; acc[2].w += a.z * b.w;
            acc[3].x += a.w * b.x; acc[3].y += a.w * b.y; acc[3].z += a.w * b.z; acc[3].w += a.w * b.w;
        }
        __syncthreads();
    }

    // epilogue
    int gc = colb + c4;
    float4 bs = make_float4(0.f,0.f,0.f,0.f);
    if (bias) bs = *(const float4*)(bias + gc);
    float4 sg = make_float4(1.f,1.f,1.f,1.f), sb = make_float4(0.f,0.f,0.f,0.f);
    if (mode == 1) {
        float4 g = *(const float4*)(bn_g + gc);
        float4 b = *(const float4*)(bn_b + gc);
        float4 m = *(const float4*)(bn_m + gc);
        float4 v = *(const float4*)(bn_v + gc);
        sg.x = g.x / sqrtf(v.x + BNEPS); sb.x = b.x - m.x * sg.x;
        sg.y = g.y / sqrtf(v.y + BNEPS); sb.y = b.y - m.y * sg.y;
        sg.z = g.z / sqrtf(v.z + BNEPS); sb.z = b.z - m.z * sg.z;
        sg.w = g.w / sqrtf(v.w + BNEPS); sb.w = b.w - m.w * sg.w;
    }
    #pragma unroll
    for (int i = 0; i < 4; ++i) {
        int row = row0 + r4 + i;
        if (row >= M) continue;
        float4 o = acc[i];
        o.x += bs.x; o.y += bs.y; o.z += bs.z; o.w += bs.w;
        if (mode == 1) {
            o.x = o.x * sg.x + sb.x; o.y = o.y * sg.y + sb.y;
            o.z = o.z * sg.z + sb.z; o.w = o.w * sg.w + sb.w;
            o.x = o.x > 0.f ? o.x : __expf(o.x) - 1.f;
            o.y = o.y > 0.f ? o.y : __expf(o.y) - 1.f;
            o.z = o.z > 0.f ? o.z : __expf(o.z) - 1.f;
            o.w = o.w > 0.f ? o.w : __expf(o.w) - 1.f;
        }
        *(float4*)(C + (size_t)row * ldc + gc) = o;
    }
}

// ---------- per-node attention dot products (one wave per node, float4) ----------
__global__ __launch_bounds__(256)
void dots_kernel(const float* __restrict__ xh,
                 const float* __restrict__ att_s, const float* __restrict__ att_d,
                 float* __restrict__ as_n, float* __restrict__ ad_n, int N)
{
    int node = (blockIdx.x * blockDim.x + threadIdx.x) >> 6;
    int lane = threadIdx.x & 63;
    if (node >= N) return;
    float4 xv = *(const float4*)(xh + (size_t)node * 256 + lane * 4);
    float4 s4 = *(const float4*)(att_s + lane * 4);
    float4 d4 = *(const float4*)(att_d + lane * 4);
    float vs = xv.x * s4.x + xv.y * s4.y + xv.z * s4.z + xv.w * s4.w;
    float vd = xv.x * d4.x + xv.y * d4.y + xv.z * d4.z + xv.w * d4.w;
    #pragma unroll
    for (int o = 1; o < 16; o <<= 1) {
        vs += __shfl_xor(vs, o);
        vd += __shfl_xor(vd, o);
    }
    if ((lane & 15) == 0) {
        as_n[node * 4 + (lane >> 4)] = vs;
        ad_n[node * 4 + (lane >> 4)] = vd;
    }
}

// ---------- CSR build: histogram over dst ----------
__global__ __launch_bounds__(256)
void hist_kernel(const int* __restrict__ ei, int E, int N, int* __restrict__ counts)
{
    int e = blockIdx.x * blockDim.x + threadIdx.x;
    int Etot = E + N;
    if (e >= Etot) return;
    int d = (e < E) ? ei[E + e] : e - E;
    atomicAdd(&counts[d], 1);
}

// ---------- CSR build: single-block chunked exclusive scan ----------
__global__ __launch_bounds__(1024)
void scan_kernel(const int* __restrict__ counts, int N,
                 int* __restrict__ rowptr, int* __restrict__ cursor)
{
    __shared__ int wsum[16];
    int tid = threadIdx.x;
    int lane = tid & 63, wave = tid >> 6;
    int chunk = (N + 1023) / 1024;
    int start = tid * chunk;
    int end = start + chunk; if (end > N) end = N;
    int s = 0;
    for (int i = start; i < end; ++i) s += counts[i];
    // wave-inclusive scan
    int incl = s;
    #pragma unroll
    for (int o = 1; o < 64; o <<= 1) {
        int t = __shfl_up(incl, o);
        if (lane >= o) incl += t;
    }
    if (lane == 63) wsum[wave] = incl;
    __syncthreads();
    if (wave == 0) {
        int v = (lane < 16) ? wsum[lane] : 0;
        #pragma unroll
        for (int o = 1; o < 16; o <<= 1) {
            int t = __shfl_up(v, o);
            if (lane >= o) v += t;
        }
        if (lane < 16) wsum[lane] = v;  // inclusive wave totals
    }
    __syncthreads();
    int waveoff = wave ? wsum[wave - 1] : 0;
    int run = waveoff + incl - s;   // exclusive prefix at chunk start
    for (int i = start; i < end; ++i) {
        rowptr[i] = run; cursor[i] = run;
        run += counts[i];
    }
    if (tid == 0) rowptr[N] = wsum[15];
}

// ---------- CSR build: scatter src ids into buckets ----------
__global__ __launch_bounds__(256)
void scatter_kernel(const int* __restrict__ ei, int E, int N,
                    int* __restrict__ cursor, int* __restrict__ csr_src)
{
    int e = blockIdx.x * blockDim.x + threadIdx.x;
    int Etot = E + N;
    if (e >= Etot) return;
    int s, d;
    if (e < E) { s = ei[e]; d = ei[E + e]; } else { s = d = e - E; }
    int pos = atomicAdd(&cursor[d], 1);
    csr_src[pos] = s;
}

// ---------- fused per-node GAT aggregation ----------
// one wave per node; lane owns concat channels [lane*4, lane*4+4),
// i.e. head h = lane>>4, in-head channels cin = (lane&15)*4 ...+4.
// mode 0: concat -> out[node*256 + lane*4] (float4)
// mode 1: head-mean -> +bias, BN, ELU, +resid -> outp[node*ldo + cin] (lanes 0..15)
__global__ __launch_bounds__(256)
void aggregate_kernel(const int* __restrict__ rowptr, const int* __restrict__ csr_src,
                      const float* __restrict__ as_n, const float* __restrict__ ad_n,
                      const float* __restrict__ xh,
                      const float* __restrict__ bias,
                      float* __restrict__ outp, int ldo,
                      int N, int mode,
                      const float* __restrict__ bn_g, const float* __restrict__ bn_b,
                      const float* __restrict__ bn_m, const float* __restrict__ bn_v,
                      const float* __restrict__ resid)
{
    int node = (blockIdx.x * blockDim.x + threadIdx.x) >> 6;
    int lane = threadIdx.x & 63;
    if (node >= N) return;
    int h = lane >> 4;
    int e0 = rowptr[node], e1 = rowptr[node + 1];

    float4 adv = ((const float4*)ad_n)[node];

    // pass 1: per-head max (lanes parallel over edges, each lane all 4 heads)
    float mx0 = -INFINITY, mx1 = -INFINITY, mx2 = -INFINITY, mx3 = -INFINITY;
    for (int e = e0 + lane; e < e1; e += 64) {
        int s = csr_src[e];
        float4 asv = ((const float4*)as_n)[s];
        float l0 = asv.x + adv.x; l0 = fmaxf(l0, NEG * l0);
        float l1 = asv.y + adv.y; l1 = fmaxf(l1, NEG * l1);
        float l2 = asv.z + adv.z; l2 = fmaxf(l2, NEG * l2);
        float l3 = asv.w + adv.w; l3 = fmaxf(l3, NEG * l3);
        mx0 = fmaxf(mx0, l0); mx1 = fmaxf(mx1, l1);
        mx2 = fmaxf(mx2, l2); mx3 = fmaxf(mx3, l3);
    }
    #pragma unroll
    for (int off = 32; off; off >>= 1) {
        mx0 = fmaxf(mx0, __shfl_xor(mx0, off));
        mx1 = fmaxf(mx1, __shfl_xor(mx1, off));
        mx2 = fmaxf(mx2, __shfl_xor(mx2, off));
        mx3 = fmaxf(mx3, __shfl_xor(mx3, off));
    }
    // select this lane's head values
    float mxh = (h < 2) ? (h == 0 ? mx0 : mx1) : (h == 2 ? mx2 : mx3);
    float adh = (h < 2) ? (h == 0 ? adv.x : adv.y) : (h == 2 ? adv.z : adv.w);

    // pass 2: weighted accumulation; lane covers 4 channels of its head
    float4 acc = make_float4(0.f, 0.f, 0.f, 0.f);
    float wsum = 0.f;
    for (int e = e0; e < e1; ++e) {
        int s = csr_src[e];
        float l = as_n[s * 4 + h] + adh;
        l = fmaxf(l, NEG * l);
        float w = __expf(l - mxh);
        float4 xv = *(const float4*)(xh + (size_t)s * 256 + lane * 4);
        acc.x += w * xv.x; acc.y += w * xv.y;
        acc.z += w * xv.z; acc.w += w * xv.w;
        wsum += w;
    }
    float rw = 1.f / wsum;
    acc.x *= rw; acc.y *= rw; acc.z *= rw; acc.w *= rw;

    if (mode == 0) {
        float4 bs = *(const float4*)(bias + lane * 4);
        acc.x += bs.x; acc.y += bs.y; acc.z += bs.z; acc.w += bs.w;
        *(float4*)(outp + (size_t)node * 256 + lane * 4) = acc;
    } else {
        // mean over heads: sum across the 4 head-groups (xor 16, 32)
        #pragma unroll
        for (int off = 16; off <= 32; off <<= 1) {
            acc.x += __shfl_xor(acc.x, off);
            acc.y += __shfl_xor(acc.y, off);
            acc.z += __shfl_xor(acc.z, off);
            acc.w += __shfl_xor(acc.w, off);
        }
        if (lane < 16) {
            int cin = lane * 4;
            float4 bs = *(const float4*)(bias + cin);
            float4 g = *(const float4*)(bn_g + cin);
            float4 b = *(const float4*)(bn_b + cin);
            float4 m = *(const float4*)(bn_m + cin);
            float4 vv = *(const float4*)(bn_v + cin);
            float4 rs = *(const float4*)(resid + (size_t)node * ldo + cin);
            float o[4] = {acc.x, acc.y, acc.z, acc.w};
            float bb[4] = {bs.x, bs.y, bs.z, bs.w};
            float gg[4] = {g.x, g.y, g.z, g.w};
            float be[4] = {b.x, b.y, b.z, b.w};
            float mm[4] = {m.x, m.y, m.z, m.w};
            float va[4] = {vv.x, vv.y, vv.z, vv.w};
            float rr[4] = {rs.x, rs.y, rs.z, rs.w};
            float4 res;
            float* rp = &res.x;
            #pragma unroll
            for (int j = 0; j < 4; ++j) {
                float v = 0.25f * o[j] + bb[j];
                float sg = gg[j] / sqrtf(va[j] + BNEPS);
                v = (v - mm[j]) * sg + be[j];
                v = v > 0.f ? v : __expf(v) - 1.f;
                rp[j] = v + rr[j];
            }
            *(float4*)(outp + (size_t)node * ldo + cin) = res;
        }
    }
}

// ---------- per-node pooling logits: one wave per node ----------
__global__ __launch_bounds__(256)
void att_logit_kernel(const float* __restrict__ hjk, const float* __restrict__ attW,
                      const float* __restrict__ attb, float* __restrict__ l, int N)
{
    int wid  = (blockIdx.x * blockDim.x + threadIdx.x) >> 6;
    int lane = threadIdx.x & 63;
    if (wid >= N) return;
    float v = hjk[(size_t)wid * 64 + lane] * attW[lane];
    #pragma unroll
    for (int off = 32; off; off >>= 1) v += __shfl_xor(v, off);
    if (lane == 0) l[wid] = v + attb[0];
}

// ---------- graph boundaries (batch is sorted) ----------
__global__ void gstart_kernel(const int* __restrict__ batch, int N, int* __restrict__ gstart)
{
    int t = threadIdx.x;
    if (t > NGRAPH) return;
    int lo = 0, hi = N;
    while (lo < hi) {
        int mid = (lo + hi) >> 1;
        if (batch[mid] < t) lo = mid + 1; else hi = mid;
    }
    gstart[t] = lo;
}

// ---------- attention pooling: one block per graph ----------
__global__ __launch_bounds__(256)
void pool_kernel(const float* __restrict__ hjk, const float* __restrict__ l,
                 const int* __restrict__ gstart, float* __restrict__ hg)
{
    int g = blockIdx.x;
    int s0 = gstart[g], s1 = gstart[g + 1];
    __shared__ float red[256];
    int tid = threadIdx.x;

    float m = -INFINITY;
    for (int n = s0 + tid; n < s1; n += 256) m = fmaxf(m, l[n]);
    red[tid] = m; __syncthreads();
    for (int o = 128; o; o >>= 1) {
        if (tid < o) red[tid] = fmaxf(red[tid], red[tid + o]);
        __syncthreads();
    }
    m = red[0]; __syncthreads();

    float ssum = 0.f;
    for (int n = s0 + tid; n < s1; n += 256) ssum += __expf(l[n] - m);
    red[tid] = ssum; __syncthreads();
    for (int o = 128; o; o >>= 1) {
        if (tid < o) red[tid] += red[tid + o];
        __syncthreads();
    }
    float ssal = red[0]; __syncthreads();

    int c = tid & 63, q = tid >> 6;
    float acc = 0.f;
    for (int n = s0 + q; n < s1; n += 4)
        acc += __expf(l[n] - m) * hjk[(size_t)n * 64 + c];
    red[tid] = acc; __syncthreads();
    if (q == 0) {
        float v = red[c] + red[64 + c] + red[128 + c] + red[192 + c];
        hg[g * 64 + c] = (s1 > s0) ? v / ssal : 0.f;
    }
}

// ---------- classifier head: one block (32 threads) per graph ----------
__global__ void cls_kernel(const float* __restrict__ hg,
                           const float* __restrict__ W1, const float* __restrict__ b1,
                           const float* __restrict__ W2, const float* __restrict__ b2,
                           float* __restrict__ out)
{
    int g = blockIdx.x, t = threadIdx.x;  // 32 threads
    __shared__ float z[32];
    float acc = b1[t];
    for (int k = 0; k < 64; ++k) acc += hg[g * 64 + k] * W1[k * 32 + t];
    z[t] = fmaxf(acc, 0.f);
    __syncthreads();
    if (t < 2) {
        float o = b2[t];
        for (int j = 0; j < 32; ++j) o += z[j] * W2[j * 2 + t];
        out[g * 2 + t] = o;
    }
}

extern "C" void kernel_launch(void* const* d_in, const int* in_sizes, int n_in,
                              void* d_out, int out_size, void* d_ws, size_t ws_size,
                              hipStream_t stream)
{
    const float* x        = (const float*)d_in[0];
    const int*   ei       = (const int*)d_in[1];
    const int*   batch    = (const int*)d_in[2];
    const float* conv0_W  = (const float*)d_in[3];
    const float* conv0_as = (const float*)d_in[4];
    const float* conv0_ad = (const float*)d_in[5];
    const float* conv0_b  = (const float*)d_in[6];
    const float* pre0_W   = (const float*)d_in[7];
    const float* pre0_b   = (const float*)d_in[8];
    const float* convs_W  = (const float*)d_in[9];
    const float* convs_as = (const float*)d_in[10];
    const float* convs_ad = (const float*)d_in[11];
    const float* convs_b  = (const float*)d_in[12];
    const float* bn_g     = (const float*)d_in[13];
    const float* bn_b     = (const float*)d_in[14];
    const float* bn_m     = (const float*)d_in[15];
    const float* bn_v     = (const float*)d_in[16];
    const float* jump_W   = (const float*)d_in[17];
    const float* jump_b   = (const float*)d_in[18];
    const float* att_W    = (const float*)d_in[19];
    const float* att_b    = (const float*)d_in[20];
    const float* cls_W1   = (const float*)d_in[21];
    const float* cls_b1   = (const float*)d_in[22];
    const float* cls_W2   = (const float*)d_in[23];
    const float* cls_b2   = (const float*)d_in[24];
    float* out = (float*)d_out;

    const int N = in_sizes[0] / 128;   // 50000
    const int E = in_sizes[1] / 2;     // 400000
    const int Etot = E + N;

    // workspace layout
    float* ws      = (float*)d_ws;
    float* xh      = ws;                                 // N*256
    float* h256    = xh + (size_t)N * 256;               // N*256
    float* repsAll = h256 + (size_t)N * 256;             // N*192
    float* as_n    = repsAll + (size_t)N * 192;          // N*4
    float* ad_n    = as_n + (size_t)N * 4;               // N*4
    float* hg      = ad_n + (size_t)N * 4;               // 64*64
    int*   rowptr  = (int*)(hg + NGRAPH * 64);           // N+1
    int*   cursor  = rowptr + (N + 1);                   // N
    int*   counts  = cursor + N;                         // N
    int*   csr_src = counts + N;                         // Etot
    int*   gstart  = csr_src + Etot;                     // 65
    float* hjk     = xh;    // reuse
    float* lbuf    = as_n;  // reuse

    dim3 blk(256);
    int node_wave_blocks = (N + 3) / 4;          // 1 wave/node
    int edge_blocks      = (Etot + 255) / 256;

    // ---------------- CSR build ----------------
    hipMemsetAsync(counts, 0, (size_t)N * sizeof(int), stream);
    hist_kernel<<<edge_blocks, blk, 0, stream>>>(ei, E, N, counts);
    scan_kernel<<<1, 1024, 0, stream>>>(counts, N, rowptr, cursor);
    scatter_kernel<<<edge_blocks, blk, 0, stream>>>(ei, E, N, cursor, csr_src);

    // ---------------- layer 0 ----------------
    {
        dim3 g1((N + 63) / 64, 4);
        gemm_f32<<<g1, blk, 0, stream>>>(x, 128, conv0_W, 256, nullptr, xh, 256,
                                         N, 128, 0, nullptr, nullptr, nullptr, nullptr);
        dots_kernel<<<node_wave_blocks, blk, 0, stream>>>(xh, conv0_as, conv0_ad, as_n, ad_n, N);
        aggregate_kernel<<<node_wave_blocks, blk, 0, stream>>>(
            rowptr, csr_src, as_n, ad_n, xh, conv0_b, h256, 256, N, 0,
            nullptr, nullptr, nullptr, nullptr, nullptr);
        dim3 g2((N + 63) / 64, 1);
        gemm_f32<<<g2, blk, 0, stream>>>(h256, 256, pre0_W, 64, pre0_b, repsAll, 192,
                                         N, 256, 1, bn_g, bn_b, bn_m, bn_v);
    }

    // ---------------- layers 1, 2 ----------------
    for (int i = 0; i < 2; ++i) {
        dim3 g1((N + 63) / 64, 4);
        gemm_f32<<<g1, blk, 0, stream>>>(repsAll + i * 64, 192,
                                         convs_W + (size_t)i * 64 * 256, 256, nullptr,
                                         xh, 256, N, 64, 0, nullptr, nullptr, nullptr, nullptr);
        dots_kernel<<<node_wave_blocks, blk, 0, stream>>>(xh, convs_as + i * 256,
                                                          convs_ad + i * 256, as_n, ad_n, N);
        aggregate_kernel<<<node_wave_blocks, blk, 0, stream>>>(
            rowptr, csr_src, as_n, ad_n, xh, convs_b + i * 64,
            repsAll + (i + 1) * 64, 192, N, 1,
            bn_g + (i + 1) * 64, bn_b + (i + 1) * 64,
            bn_m + (i + 1) * 64, bn_v + (i + 1) * 64,
            repsAll + i * 64);
    }

    // ---------------- JK projection ----------------
    {
        dim3 g2((N + 63) / 64, 1);
        gemm_f32<<<g2, blk, 0, stream>>>(repsAll, 192, jump_W, 64, jump_b, hjk, 64,
                                         N, 192, 0, nullptr, nullptr, nullptr, nullptr);
    }

    // ---------------- pooling + classifier ----------------
    att_logit_kernel<<<node_wave_blocks, blk, 0, stream>>>(hjk, att_W, att_b, lbuf, N);
    gstart_kernel<<<1, 128, 0, stream>>>(batch, N, gstart);
    pool_kernel<<<NGRAPH, blk, 0, stream>>>(hjk, lbuf, gstart, hg);
    cls_kernel<<<NGRAPH, 32, 0, stream>>>(hg, cls_W1, cls_b1, cls_W2, cls_b2, out);
}

// Round 4
// 676.349 us; speedup vs baseline: 3.2019x; 1.1390x over previous
//
#include <hip/hip_runtime.h>
#include <math.h>

#define NEG 0.2f
#define BNEPS 1e-5f
#define NGRAPH 64
#define SCAN_CHUNK 2048

// ---------- f32 GEMM: C[M,Nc] = A[M,K]@W[K,Nc] (+bias) (+BN+ELU) ----------
// 64x64 tile per 256-thread block, 16 outputs/thread.
// grid: (ceil(M/64), Nc/64). K must be a multiple of 32.
__global__ __launch_bounds__(256)
void gemm_f32(const float* __restrict__ A, int lda,
              const float* __restrict__ W, int Nc,
              const float* __restrict__ bias,
              float* __restrict__ C, int ldc,
              int M, int K, int mode,
              const float* __restrict__ bn_g, const float* __restrict__ bn_b,
              const float* __restrict__ bn_m, const float* __restrict__ bn_v)
{
    __shared__ __align__(16) float As[32][68];  // As[k][row]
    __shared__ __align__(16) float Ws[32][68];  // Ws[k][col]
    int tid  = threadIdx.x;
    int lane = tid & 63, wave = tid >> 6;
    int row0 = blockIdx.x * 64;
    int colb = blockIdx.y * 64;
    int r4 = wave * 16 + (lane >> 4) * 4;   // tile-local row base (4 rows)
    int c4 = (lane & 15) * 4;               // tile-local col base (4 cols)

    float4 acc[4];
    #pragma unroll
    for (int i = 0; i < 4; ++i) acc[i] = make_float4(0.f, 0.f, 0.f, 0.f);

    // staging coords
    int ar = tid & 63, akq = (tid >> 6) * 8;          // A: row, k-quad
    int wk = tid >> 3, wcq = (tid & 7) * 8;           // W: k, col-quad

    for (int k0 = 0; k0 < K; k0 += 32) {
        // stage A (64 rows x 32 k, transposed)
        int gr = row0 + ar;
        float4 av0, av1;
        if (gr < M) {
            const float* ap = A + (size_t)gr * lda + k0 + akq;
            av0 = *(const float4*)ap;
            av1 = *(const float4*)(ap + 4);
        } else {
            av0 = make_float4(0.f,0.f,0.f,0.f);
            av1 = av0;
        }
        As[akq + 0][ar] = av0.x; As[akq + 1][ar] = av0.y;
        As[akq + 2][ar] = av0.z; As[akq + 3][ar] = av0.w;
        As[akq + 4][ar] = av1.x; As[akq + 5][ar] = av1.y;
        As[akq + 6][ar] = av1.z; As[akq + 7][ar] = av1.w;
        // stage W (32 k x 64 cols)
        const float* wp = W + (size_t)(k0 + wk) * Nc + colb + wcq;
        *(float4*)&Ws[wk][wcq]     = *(const float4*)wp;
        *(float4*)&Ws[wk][wcq + 4] = *(const float4*)(wp + 4);
        __syncthreads();

        #pragma unroll
        for (int kk = 0; kk < 32; ++kk) {
            float4 a = *(const float4*)&As[kk][r4];
            float4 b = *(const float4*)&Ws[kk][c4];
            acc[0].x += a.x * b.x; acc[0].y += a.x * b.y; acc[0].z += a.x * b.z; acc[0].w += a.x * b.w;
            acc[1].x += a.y * b.x; acc[1].y += a.y * b.y; acc[1].z += a.y * b.z; acc[1].w += a.y * b.w;
            acc[2].x += a.z * b.x; acc[2].y += a.z * b.y; acc[2].z += a.z * b.z; acc[2].w += a.z * b.w;
            acc[3].x += a.w * b.x; acc[3].y += a.w * b.y; acc[3].z += a.w * b.z; acc[3].w += a.w * b.w;
        }
        __syncthreads();
    }

    // epilogue
    int gc = colb + c4;
    float4 bs = make_float4(0.f,0.f,0.f,0.f);
    if (bias) bs = *(const float4*)(bias + gc);
    float4 sg = make_float4(1.f,1.f,1.f,1.f), sb = make_float4(0.f,0.f,0.f,0.f);
    if (mode == 1) {
        float4 g = *(const float4*)(bn_g + gc);
        float4 b = *(const float4*)(bn_b + gc);
        float4 m = *(const float4*)(bn_m + gc);
        float4 v = *(const float4*)(bn_v + gc);
        sg.x = g.x / sqrtf(v.x + BNEPS); sb.x = b.x - m.x * sg.x;
        sg.y = g.y / sqrtf(v.y + BNEPS); sb.y = b.y - m.y * sg.y;
        sg.z = g.z / sqrtf(v.z + BNEPS); sb.z = b.z - m.z * sg.z;
        sg.w = g.w / sqrtf(v.w + BNEPS); sb.w = b.w - m.w * sg.w;
    }
    #pragma unroll
    for (int i = 0; i < 4; ++i) {
        int row = row0 + r4 + i;
        if (row >= M) continue;
        float4 o = acc[i];
        o.x += bs.x; o.y += bs.y; o.z += bs.z; o.w += bs.w;
        if (mode == 1) {
            o.x = o.x * sg.x + sb.x; o.y = o.y * sg.y + sb.y;
            o.z = o.z * sg.z + sb.z; o.w = o.w * sg.w + sb.w;
            o.x = o.x > 0.f ? o.x : __expf(o.x) - 1.f;
            o.y = o.y > 0.f ? o.y : __expf(o.y) - 1.f;
            o.z = o.z > 0.f ? o.z : __expf(o.z) - 1.f;
            o.w = o.w > 0.f ? o.w : __expf(o.w) - 1.f;
        }
        *(float4*)(C + (size_t)row * ldc + gc) = o;
    }
}

// ---------- per-node attention dot products (one wave per node, float4) ----------
__global__ __launch_bounds__(256)
void dots_kernel(const float* __restrict__ xh,
                 const float* __restrict__ att_s, const float* __restrict__ att_d,
                 float* __restrict__ as_n, float* __restrict__ ad_n, int N)
{
    int node = (blockIdx.x * blockDim.x + threadIdx.x) >> 6;
    int lane = threadIdx.x & 63;
    if (node >= N) return;
    float4 xv = *(const float4*)(xh + (size_t)node * 256 + lane * 4);
    float4 s4 = *(const float4*)(att_s + lane * 4);
    float4 d4 = *(const float4*)(att_d + lane * 4);
    float vs = xv.x * s4.x + xv.y * s4.y + xv.z * s4.z + xv.w * s4.w;
    float vd = xv.x * d4.x + xv.y * d4.y + xv.z * d4.z + xv.w * d4.w;
    #pragma unroll
    for (int o = 1; o < 16; o <<= 1) {
        vs += __shfl_xor(vs, o);
        vd += __shfl_xor(vd, o);
    }
    if ((lane & 15) == 0) {
        as_n[node * 4 + (lane >> 4)] = vs;
        ad_n[node * 4 + (lane >> 4)] = vd;
    }
}

// ---------- CSR build: histogram over dst ----------
__global__ __launch_bounds__(256)
void hist_kernel(const int* __restrict__ ei, int E, int N, int* __restrict__ counts)
{
    int e = blockIdx.x * blockDim.x + threadIdx.x;
    int Etot = E + N;
    if (e >= Etot) return;
    int d = (e < E) ? ei[E + e] : e - E;
    atomicAdd(&counts[d], 1);
}

// ---------- scan phase 1: per-block partial sums (2048 elems/block) ----------
__global__ __launch_bounds__(256)
void scan_phase1(const int* __restrict__ counts, int N, int* __restrict__ blocksum)
{
    __shared__ int wsum[4];
    int tid = threadIdx.x, lane = tid & 63, wave = tid >> 6;
    int base = blockIdx.x * SCAN_CHUNK;
    int s = 0;
    #pragma unroll
    for (int j = 0; j < SCAN_CHUNK / 256; ++j) {
        int idx = base + tid + j * 256;
        if (idx < N) s += counts[idx];
    }
    #pragma unroll
    for (int o = 32; o; o >>= 1) s += __shfl_xor(s, o);
    if (lane == 0) wsum[wave] = s;
    __syncthreads();
    if (tid == 0) blocksum[blockIdx.x] = wsum[0] + wsum[1] + wsum[2] + wsum[3];
}

// ---------- scan phase 2: exclusive scan of block sums (nb <= 64), 1 wave ----------
__global__ void scan_phase2(const int* __restrict__ blocksum, int nb,
                            int* __restrict__ blockoff, int* __restrict__ rowptr, int N)
{
    int lane = threadIdx.x;  // 64 threads
    int v = (lane < nb) ? blocksum[lane] : 0;
    int incl = v;
    #pragma unroll
    for (int o = 1; o < 64; o <<= 1) {
        int t = __shfl_up(incl, o);
        if (lane >= o) incl += t;
    }
    if (lane < nb) blockoff[lane + 1] = incl;
    if (lane == 0) blockoff[0] = 0;
    int total = __shfl(incl, nb - 1);
    if (lane == 0) rowptr[N] = total;
}

// ---------- scan phase 3: per-block exclusive scan + offset ----------
__global__ __launch_bounds__(256)
void scan_phase3(const int* __restrict__ counts, int N,
                 const int* __restrict__ blockoff,
                 int* __restrict__ rowptr, int* __restrict__ cursor)
{
    __shared__ int wsum[4];
    int tid = threadIdx.x, lane = tid & 63, wave = tid >> 6;
    int start = blockIdx.x * SCAN_CHUNK + tid * 8;
    int v[8];
    int s = 0;
    #pragma unroll
    for (int j = 0; j < 8; ++j) {
        v[j] = (start + j < N) ? counts[start + j] : 0;
        s += v[j];
    }
    int incl = s;
    #pragma unroll
    for (int o = 1; o < 64; o <<= 1) {
        int t = __shfl_up(incl, o);
        if (lane >= o) incl += t;
    }
    if (lane == 63) wsum[wave] = incl;
    __syncthreads();
    int woff = 0;
    #pragma unroll
    for (int w = 0; w < 4; ++w) if (w < wave) woff += wsum[w];
    int run = blockoff[blockIdx.x] + woff + incl - s;
    #pragma unroll
    for (int j = 0; j < 8; ++j) {
        int idx = start + j;
        if (idx < N) { rowptr[idx] = run; cursor[idx] = run; }
        run += v[j];
    }
}

// ---------- CSR build: scatter src ids into buckets ----------
__global__ __launch_bounds__(256)
void scatter_kernel(const int* __restrict__ ei, int E, int N,
                    int* __restrict__ cursor, int* __restrict__ csr_src)
{
    int e = blockIdx.x * blockDim.x + threadIdx.x;
    int Etot = E + N;
    if (e >= Etot) return;
    int s, d;
    if (e < E) { s = ei[e]; d = ei[E + e]; } else { s = d = e - E; }
    int pos = atomicAdd(&cursor[d], 1);
    csr_src[pos] = s;
}

// ---------- fused per-node GAT aggregation ----------
// one wave per node; lane owns concat channels [lane*4, lane*4+4),
// i.e. head h = lane>>4, in-head channels cin = (lane&15)*4 ...+4.
// mode 0: concat -> out[node*256 + lane*4] (float4)
// mode 1: head-mean -> +bias, BN, ELU, +resid -> outp[node*ldo + cin] (lanes 0..15)
__global__ __launch_bounds__(256)
void aggregate_kernel(const int* __restrict__ rowptr, const int* __restrict__ csr_src,
                      const float* __restrict__ as_n, const float* __restrict__ ad_n,
                      const float* __restrict__ xh,
                      const float* __restrict__ bias,
                      float* __restrict__ outp, int ldo,
                      int N, int mode,
                      const float* __restrict__ bn_g, const float* __restrict__ bn_b,
                      const float* __restrict__ bn_m, const float* __restrict__ bn_v,
                      const float* __restrict__ resid)
{
    int node = (blockIdx.x * blockDim.x + threadIdx.x) >> 6;
    int lane = threadIdx.x & 63;
    if (node >= N) return;
    int h = lane >> 4;
    int e0 = rowptr[node], e1 = rowptr[node + 1];

    float4 adv = ((const float4*)ad_n)[node];

    // pass 1: per-head max (lanes parallel over edges, each lane all 4 heads)
    float mx0 = -INFINITY, mx1 = -INFINITY, mx2 = -INFINITY, mx3 = -INFINITY;
    for (int e = e0 + lane; e < e1; e += 64) {
        int s = csr_src[e];
        float4 asv = ((const float4*)as_n)[s];
        float l0 = asv.x + adv.x; l0 = fmaxf(l0, NEG * l0);
        float l1 = asv.y + adv.y; l1 = fmaxf(l1, NEG * l1);
        float l2 = asv.z + adv.z; l2 = fmaxf(l2, NEG * l2);
        float l3 = asv.w + adv.w; l3 = fmaxf(l3, NEG * l3);
        mx0 = fmaxf(mx0, l0); mx1 = fmaxf(mx1, l1);
        mx2 = fmaxf(mx2, l2); mx3 = fmaxf(mx3, l3);
    }
    #pragma unroll
    for (int off = 32; off; off >>= 1) {
        mx0 = fmaxf(mx0, __shfl_xor(mx0, off));
        mx1 = fmaxf(mx1, __shfl_xor(mx1, off));
        mx2 = fmaxf(mx2, __shfl_xor(mx2, off));
        mx3 = fmaxf(mx3, __shfl_xor(mx3, off));
    }
    // select this lane's head values
    float mxh = (h < 2) ? (h == 0 ? mx0 : mx1) : (h == 2 ? mx2 : mx3);
    float adh = (h < 2) ? (h == 0 ? adv.x : adv.y) : (h == 2 ? adv.z : adv.w);

    // pass 2: weighted accumulation; lane covers 4 channels of its head
    float4 acc = make_float4(0.f, 0.f, 0.f, 0.f);
    float wsum = 0.f;
    for (int e = e0; e < e1; ++e) {
        int s = csr_src[e];
        float l = as_n[s * 4 + h] + adh;
        l = fmaxf(l, NEG * l);
        float w = __expf(l - mxh);
        float4 xv = *(const float4*)(xh + (size_t)s * 256 + lane * 4);
        acc.x += w * xv.x; acc.y += w * xv.y;
        acc.z += w * xv.z; acc.w += w * xv.w;
        wsum += w;
    }
    float rw = 1.f / wsum;
    acc.x *= rw; acc.y *= rw; acc.z *= rw; acc.w *= rw;

    if (mode == 0) {
        float4 bs = *(const float4*)(bias + lane * 4);
        acc.x += bs.x; acc.y += bs.y; acc.z += bs.z; acc.w += bs.w;
        *(float4*)(outp + (size_t)node * 256 + lane * 4) = acc;
    } else {
        // mean over heads: sum across the 4 head-groups (xor 16, 32)
        #pragma unroll
        for (int off = 16; off <= 32; off <<= 1) {
            acc.x += __shfl_xor(acc.x, off);
            acc.y += __shfl_xor(acc.y, off);
            acc.z += __shfl_xor(acc.z, off);
            acc.w += __shfl_xor(acc.w, off);
        }
        if (lane < 16) {
            int cin = lane * 4;
            float4 bs = *(const float4*)(bias + cin);
            float4 g = *(const float4*)(bn_g + cin);
            float4 b = *(const float4*)(bn_b + cin);
            float4 m = *(const float4*)(bn_m + cin);
            float4 vv = *(const float4*)(bn_v + cin);
            float4 rs = *(const float4*)(resid + (size_t)node * ldo + cin);
            float o[4] = {acc.x, acc.y, acc.z, acc.w};
            float bb[4] = {bs.x, bs.y, bs.z, bs.w};
            float gg[4] = {g.x, g.y, g.z, g.w};
            float be[4] = {b.x, b.y, b.z, b.w};
            float mm[4] = {m.x, m.y, m.z, m.w};
            float va[4] = {vv.x, vv.y, vv.z, vv.w};
            float rr[4] = {rs.x, rs.y, rs.z, rs.w};
            float4 res;
            float* rp = &res.x;
            #pragma unroll
            for (int j = 0; j < 4; ++j) {
                float v = 0.25f * o[j] + bb[j];
                float sg = gg[j] / sqrtf(va[j] + BNEPS);
                v = (v - mm[j]) * sg + be[j];
                v = v > 0.f ? v : __expf(v) - 1.f;
                rp[j] = v + rr[j];
            }
            *(float4*)(outp + (size_t)node * ldo + cin) = res;
        }
    }
}

// ---------- per-node pooling logits: one wave per node ----------
__global__ __launch_bounds__(256)
void att_logit_kernel(const float* __restrict__ hjk, const float* __restrict__ attW,
                      const float* __restrict__ attb, float* __restrict__ l, int N)
{
    int wid  = (blockIdx.x * blockDim.x + threadIdx.x) >> 6;
    int lane = threadIdx.x & 63;
    if (wid >= N) return;
    float v = hjk[(size_t)wid * 64 + lane] * attW[lane];
    #pragma unroll
    for (int off = 32; off; off >>= 1) v += __shfl_xor(v, off);
    if (lane == 0) l[wid] = v + attb[0];
}

// ---------- graph boundaries (batch is sorted) ----------
__global__ void gstart_kernel(const int* __restrict__ batch, int N, int* __restrict__ gstart)
{
    int t = threadIdx.x;
    if (t > NGRAPH) return;
    int lo = 0, hi = N;
    while (lo < hi) {
        int mid = (lo + hi) >> 1;
        if (batch[mid] < t) lo = mid + 1; else hi = mid;
    }
    gstart[t] = lo;
}

// ---------- attention pooling: one block per graph ----------
__global__ __launch_bounds__(256)
void pool_kernel(const float* __restrict__ hjk, const float* __restrict__ l,
                 const int* __restrict__ gstart, float* __restrict__ hg)
{
    int g = blockIdx.x;
    int s0 = gstart[g], s1 = gstart[g + 1];
    __shared__ float red[256];
    int tid = threadIdx.x;

    float m = -INFINITY;
    for (int n = s0 + tid; n < s1; n += 256) m = fmaxf(m, l[n]);
    red[tid] = m; __syncthreads();
    for (int o = 128; o; o >>= 1) {
        if (tid < o) red[tid] = fmaxf(red[tid], red[tid + o]);
        __syncthreads();
    }
    m = red[0]; __syncthreads();

    float ssum = 0.f;
    for (int n = s0 + tid; n < s1; n += 256) ssum += __expf(l[n] - m);
    red[tid] = ssum; __syncthreads();
    for (int o = 128; o; o >>= 1) {
        if (tid < o) red[tid] += red[tid + o];
        __syncthreads();
    }
    float ssal = red[0]; __syncthreads();

    int c = tid & 63, q = tid >> 6;
    float acc = 0.f;
    for (int n = s0 + q; n < s1; n += 4)
        acc += __expf(l[n] - m) * hjk[(size_t)n * 64 + c];
    red[tid] = acc; __syncthreads();
    if (q == 0) {
        float v = red[c] + red[64 + c] + red[128 + c] + red[192 + c];
        hg[g * 64 + c] = (s1 > s0) ? v / ssal : 0.f;
    }
}

// ---------- classifier head: one block (32 threads) per graph ----------
__global__ void cls_kernel(const float* __restrict__ hg,
                           const float* __restrict__ W1, const float* __restrict__ b1,
                           const float* __restrict__ W2, const float* __restrict__ b2,
                           float* __restrict__ out)
{
    int g = blockIdx.x, t = threadIdx.x;  // 32 threads
    __shared__ float z[32];
    float acc = b1[t];
    for (int k = 0; k < 64; ++k) acc += hg[g * 64 + k] * W1[k * 32 + t];
    z[t] = fmaxf(acc, 0.f);
    __syncthreads();
    if (t < 2) {
        float o = b2[t];
        for (int j = 0; j < 32; ++j) o += z[j] * W2[j * 2 + t];
        out[g * 2 + t] = o;
    }
}

extern "C" void kernel_launch(void* const* d_in, const int* in_sizes, int n_in,
                              void* d_out, int out_size, void* d_ws, size_t ws_size,
                              hipStream_t stream)
{
    const float* x        = (const float*)d_in[0];
    const int*   ei       = (const int*)d_in[1];
    const int*   batch    = (const int*)d_in[2];
    const float* conv0_W  = (const float*)d_in[3];
    const float* conv0_as = (const float*)d_in[4];
    const float* conv0_ad = (const float*)d_in[5];
    const float* conv0_b  = (const float*)d_in[6];
    const float* pre0_W   = (const float*)d_in[7];
    const float* pre0_b   = (const float*)d_in[8];
    const float* convs_W  = (const float*)d_in[9];
    const float* convs_as = (const float*)d_in[10];
    const float* convs_ad = (const float*)d_in[11];
    const float* convs_b  = (const float*)d_in[12];
    const float* bn_g     = (const float*)d_in[13];
    const float* bn_b     = (const float*)d_in[14];
    const float* bn_m     = (const float*)d_in[15];
    const float* bn_v     = (const float*)d_in[16];
    const float* jump_W   = (const float*)d_in[17];
    const float* jump_b   = (const float*)d_in[18];
    const float* att_W    = (const float*)d_in[19];
    const float* att_b    = (const float*)d_in[20];
    const float* cls_W1   = (const float*)d_in[21];
    const float* cls_b1   = (const float*)d_in[22];
    const float* cls_W2   = (const float*)d_in[23];
    const float* cls_b2   = (const float*)d_in[24];
    float* out = (float*)d_out;

    const int N = in_sizes[0] / 128;   // 50000
    const int E = in_sizes[1] / 2;     // 400000
    const int Etot = E + N;
    const int nb = (N + SCAN_CHUNK - 1) / SCAN_CHUNK;   // scan blocks (25), must be <= 64

    // workspace layout
    float* ws      = (float*)d_ws;
    float* xh      = ws;                                 // N*256
    float* h256    = xh + (size_t)N * 256;               // N*256
    float* repsAll = h256 + (size_t)N * 256;             // N*192
    float* as_n    = repsAll + (size_t)N * 192;          // N*4
    float* ad_n    = as_n + (size_t)N * 4;               // N*4
    float* hg      = ad_n + (size_t)N * 4;               // 64*64
    int*   rowptr  = (int*)(hg + NGRAPH * 64);           // N+1
    int*   cursor  = rowptr + (N + 1);                   // N
    int*   counts  = cursor + N;                         // N
    int*   csr_src = counts + N;                         // Etot
    int*   gstart  = csr_src + Etot;                     // 65
    int*   blocksum = gstart + (NGRAPH + 1);             // 64
    int*   blockoff = blocksum + 64;                     // 65
    float* hjk     = xh;    // reuse
    float* lbuf    = as_n;  // reuse

    dim3 blk(256);
    int node_wave_blocks = (N + 3) / 4;          // 1 wave/node
    int edge_blocks      = (Etot + 255) / 256;

    // ---------------- CSR build ----------------
    hipMemsetAsync(counts, 0, (size_t)N * sizeof(int), stream);
    hist_kernel<<<edge_blocks, blk, 0, stream>>>(ei, E, N, counts);
    scan_phase1<<<nb, blk, 0, stream>>>(counts, N, blocksum);
    scan_phase2<<<1, 64, 0, stream>>>(blocksum, nb, blockoff, rowptr, N);
    scan_phase3<<<nb, blk, 0, stream>>>(counts, N, blockoff, rowptr, cursor);
    scatter_kernel<<<edge_blocks, blk, 0, stream>>>(ei, E, N, cursor, csr_src);

    // ---------------- layer 0 ----------------
    {
        dim3 g1((N + 63) / 64, 4);
        gemm_f32<<<g1, blk, 0, stream>>>(x, 128, conv0_W, 256, nullptr, xh, 256,
                                         N, 128, 0, nullptr, nullptr, nullptr, nullptr);
        dots_kernel<<<node_wave_blocks, blk, 0, stream>>>(xh, conv0_as, conv0_ad, as_n, ad_n, N);
        aggregate_kernel<<<node_wave_blocks, blk, 0, stream>>>(
            rowptr, csr_src, as_n, ad_n, xh, conv0_b, h256, 256, N, 0,
            nullptr, nullptr, nullptr, nullptr, nullptr);
        dim3 g2((N + 63) / 64, 1);
        gemm_f32<<<g2, blk, 0, stream>>>(h256, 256, pre0_W, 64, pre0_b, repsAll, 192,
                                         N, 256, 1, bn_g, bn_b, bn_m, bn_v);
    }

    // ---------------- layers 1, 2 ----------------
    for (int i = 0; i < 2; ++i) {
        dim3 g1((N + 63) / 64, 4);
        gemm_f32<<<g1, blk, 0, stream>>>(repsAll + i * 64, 192,
                                         convs_W + (size_t)i * 64 * 256, 256, nullptr,
                                         xh, 256, N, 64, 0, nullptr, nullptr, nullptr, nullptr);
        dots_kernel<<<node_wave_blocks, blk, 0, stream>>>(xh, convs_as + i * 256,
                                                          convs_ad + i * 256, as_n, ad_n, N);
        aggregate_kernel<<<node_wave_blocks, blk, 0, stream>>>(
            rowptr, csr_src, as_n, ad_n, xh, convs_b + i * 64,
            repsAll + (i + 1) * 64, 192, N, 1,
            bn_g + (i + 1) * 64, bn_b + (i + 1) * 64,
            bn_m + (i + 1) * 64, bn_v + (i + 1) * 64,
            repsAll + i * 64);
    }

    // ---------------- JK projection ----------------
    {
        dim3 g2((N + 63) / 64, 1);
        gemm_f32<<<g2, blk, 0, stream>>>(repsAll, 192, jump_W, 64, jump_b, hjk, 64,
                                         N, 192, 0, nullptr, nullptr, nullptr, nullptr);
    }

    // ---------------- pooling + classifier ----------------
    att_logit_kernel<<<node_wave_blocks, blk, 0, stream>>>(hjk, att_W, att_b, lbuf, N);
    gstart_kernel<<<1, 128, 0, stream>>>(batch, N, gstart);
    pool_kernel<<<NGRAPH, blk, 0, stream>>>(hjk, lbuf, gstart, hg);
    cls_kernel<<<NGRAPH, 32, 0, stream>>>(hg, cls_W1, cls_b1, cls_W2, cls_b2, out);
}

// Round 5
// 615.092 us; speedup vs baseline: 3.5207x; 1.0996x over previous
//
#include <hip/hip_runtime.h>
#include <math.h>

#define NEG 0.2f
#define BNEPS 1e-5f
#define NGRAPH 64
#define SCAN_CHUNK 2048

// ---------- f32 GEMM: C[M,Nc] = A[M,K]@W[K,Nc] (+bias) (+BN+ELU) (+fused att dots) ----------
// 64x64 tile per 256-thread block, 16 outputs/thread.
// grid: (ceil(M/64), Nc/64). K must be a multiple of 32.
// If att_s != null (xh GEMMs, Nc=256): blockIdx.y == head; epilogue computes
// as_n[row*4+head] = sum_c xh[row, head*64+c]*att_s[head*64+c] (exact, no atomics).
__global__ __launch_bounds__(256)
void gemm_f32(const float* __restrict__ A, int lda,
              const float* __restrict__ W, int Nc,
              const float* __restrict__ bias,
              float* __restrict__ C, int ldc,
              int M, int K, int mode,
              const float* __restrict__ bn_g, const float* __restrict__ bn_b,
              const float* __restrict__ bn_m, const float* __restrict__ bn_v,
              const float* __restrict__ att_s, const float* __restrict__ att_d,
              float* __restrict__ as_out, float* __restrict__ ad_out)
{
    __shared__ __align__(16) float As[32][68];  // As[k][row]
    __shared__ __align__(16) float Ws[32][68];  // Ws[k][col]
    int tid  = threadIdx.x;
    int lane = tid & 63, wave = tid >> 6;
    int row0 = blockIdx.x * 64;
    int colb = blockIdx.y * 64;
    int r4 = wave * 16 + (lane >> 4) * 4;   // tile-local row base (4 rows)
    int c4 = (lane & 15) * 4;               // tile-local col base (4 cols)

    float4 acc[4];
    #pragma unroll
    for (int i = 0; i < 4; ++i) acc[i] = make_float4(0.f, 0.f, 0.f, 0.f);

    // staging coords
    int ar = tid & 63, akq = (tid >> 6) * 8;          // A: row, k-quad
    int wk = tid >> 3, wcq = (tid & 7) * 8;           // W: k, col-quad

    for (int k0 = 0; k0 < K; k0 += 32) {
        // stage A (64 rows x 32 k, transposed)
        int gr = row0 + ar;
        float4 av0, av1;
        if (gr < M) {
            const float* ap = A + (size_t)gr * lda + k0 + akq;
            av0 = *(const float4*)ap;
            av1 = *(const float4*)(ap + 4);
        } else {
            av0 = make_float4(0.f,0.f,0.f,0.f);
            av1 = av0;
        }
        As[akq + 0][ar] = av0.x; As[akq + 1][ar] = av0.y;
        As[akq + 2][ar] = av0.z; As[akq + 3][ar] = av0.w;
        As[akq + 4][ar] = av1.x; As[akq + 5][ar] = av1.y;
        As[akq + 6][ar] = av1.z; As[akq + 7][ar] = av1.w;
        // stage W (32 k x 64 cols)
        const float* wp = W + (size_t)(k0 + wk) * Nc + colb + wcq;
        *(float4*)&Ws[wk][wcq]     = *(const float4*)wp;
        *(float4*)&Ws[wk][wcq + 4] = *(const float4*)(wp + 4);
        __syncthreads();

        #pragma unroll
        for (int kk = 0; kk < 32; ++kk) {
            float4 a = *(const float4*)&As[kk][r4];
            float4 b = *(const float4*)&Ws[kk][c4];
            acc[0].x += a.x * b.x; acc[0].y += a.x * b.y; acc[0].z += a.x * b.z; acc[0].w += a.x * b.w;
            acc[1].x += a.y * b.x; acc[1].y += a.y * b.y; acc[1].z += a.y * b.z; acc[1].w += a.y * b.w;
            acc[2].x += a.z * b.x; acc[2].y += a.z * b.y; acc[2].z += a.z * b.z; acc[2].w += a.z * b.w;
            acc[3].x += a.w * b.x; acc[3].y += a.w * b.y; acc[3].z += a.w * b.z; acc[3].w += a.w * b.w;
        }
        __syncthreads();
    }

    // epilogue
    int gc = colb + c4;
    float4 bs = make_float4(0.f,0.f,0.f,0.f);
    if (bias) bs = *(const float4*)(bias + gc);
    float4 sg = make_float4(1.f,1.f,1.f,1.f), sb = make_float4(0.f,0.f,0.f,0.f);
    if (mode == 1) {
        float4 g = *(const float4*)(bn_g + gc);
        float4 b = *(const float4*)(bn_b + gc);
        float4 m = *(const float4*)(bn_m + gc);
        float4 v = *(const float4*)(bn_v + gc);
        sg.x = g.x / sqrtf(v.x + BNEPS); sb.x = b.x - m.x * sg.x;
        sg.y = g.y / sqrtf(v.y + BNEPS); sb.y = b.y - m.y * sg.y;
        sg.z = g.z / sqrtf(v.z + BNEPS); sb.z = b.z - m.z * sg.z;
        sg.w = g.w / sqrtf(v.w + BNEPS); sb.w = b.w - m.w * sg.w;
    }
    #pragma unroll
    for (int i = 0; i < 4; ++i) {
        int row = row0 + r4 + i;
        if (row >= M) continue;
        float4 o = acc[i];
        o.x += bs.x; o.y += bs.y; o.z += bs.z; o.w += bs.w;
        if (mode == 1) {
            o.x = o.x * sg.x + sb.x; o.y = o.y * sg.y + sb.y;
            o.z = o.z * sg.z + sb.z; o.w = o.w * sg.w + sb.w;
            o.x = o.x > 0.f ? o.x : __expf(o.x) - 1.f;
            o.y = o.y > 0.f ? o.y : __expf(o.y) - 1.f;
            o.z = o.z > 0.f ? o.z : __expf(o.z) - 1.f;
            o.w = o.w > 0.f ? o.w : __expf(o.w) - 1.f;
        }
        *(float4*)(C + (size_t)row * ldc + gc) = o;
    }

    // fused attention dot products (only for xh GEMMs: bias==null, raw acc == xh)
    if (att_s) {
        float4 sa = *(const float4*)(att_s + gc);
        float4 da = *(const float4*)(att_d + gc);
        #pragma unroll
        for (int i = 0; i < 4; ++i) {
            float ps = acc[i].x * sa.x + acc[i].y * sa.y + acc[i].z * sa.z + acc[i].w * sa.w;
            float pd = acc[i].x * da.x + acc[i].y * da.y + acc[i].z * da.z + acc[i].w * da.w;
            #pragma unroll
            for (int o = 1; o < 16; o <<= 1) {
                ps += __shfl_xor(ps, o);
                pd += __shfl_xor(pd, o);
            }
            int row = row0 + r4 + i;
            if ((lane & 15) == 0 && row < M) {
                as_out[row * 4 + blockIdx.y] = ps;
                ad_out[row * 4 + blockIdx.y] = pd;
            }
        }
    }
}

// ---------- CSR build: histogram over dst ----------
__global__ __launch_bounds__(256)
void hist_kernel(const int* __restrict__ ei, int E, int N, int* __restrict__ counts)
{
    int e = blockIdx.x * blockDim.x + threadIdx.x;
    int Etot = E + N;
    if (e >= Etot) return;
    int d = (e < E) ? ei[E + e] : e - E;
    atomicAdd(&counts[d], 1);
}

// ---------- scan phase 1: per-block partial sums (2048 elems/block) ----------
__global__ __launch_bounds__(256)
void scan_phase1(const int* __restrict__ counts, int N, int* __restrict__ blocksum)
{
    __shared__ int wsum[4];
    int tid = threadIdx.x, lane = tid & 63, wave = tid >> 6;
    int base = blockIdx.x * SCAN_CHUNK;
    int s = 0;
    #pragma unroll
    for (int j = 0; j < SCAN_CHUNK / 256; ++j) {
        int idx = base + tid + j * 256;
        if (idx < N) s += counts[idx];
    }
    #pragma unroll
    for (int o = 32; o; o >>= 1) s += __shfl_xor(s, o);
    if (lane == 0) wsum[wave] = s;
    __syncthreads();
    if (tid == 0) blocksum[blockIdx.x] = wsum[0] + wsum[1] + wsum[2] + wsum[3];
}

// ---------- scan phase 2: exclusive scan of block sums (nb <= 64), 1 wave ----------
__global__ void scan_phase2(const int* __restrict__ blocksum, int nb,
                            int* __restrict__ blockoff, int* __restrict__ rowptr, int N)
{
    int lane = threadIdx.x;  // 64 threads
    int v = (lane < nb) ? blocksum[lane] : 0;
    int incl = v;
    #pragma unroll
    for (int o = 1; o < 64; o <<= 1) {
        int t = __shfl_up(incl, o);
        if (lane >= o) incl += t;
    }
    if (lane < nb) blockoff[lane + 1] = incl;
    if (lane == 0) blockoff[0] = 0;
    int total = __shfl(incl, nb - 1);
    if (lane == 0) rowptr[N] = total;
}

// ---------- scan phase 3: per-block exclusive scan + offset ----------
__global__ __launch_bounds__(256)
void scan_phase3(const int* __restrict__ counts, int N,
                 const int* __restrict__ blockoff,
                 int* __restrict__ rowptr, int* __restrict__ cursor)
{
    __shared__ int wsum[4];
    int tid = threadIdx.x, lane = tid & 63, wave = tid >> 6;
    int start = blockIdx.x * SCAN_CHUNK + tid * 8;
    int v[8];
    int s = 0;
    #pragma unroll
    for (int j = 0; j < 8; ++j) {
        v[j] = (start + j < N) ? counts[start + j] : 0;
        s += v[j];
    }
    int incl = s;
    #pragma unroll
    for (int o = 1; o < 64; o <<= 1) {
        int t = __shfl_up(incl, o);
        if (lane >= o) incl += t;
    }
    if (lane == 63) wsum[wave] = incl;
    __syncthreads();
    int woff = 0;
    #pragma unroll
    for (int w = 0; w < 4; ++w) if (w < wave) woff += wsum[w];
    int run = blockoff[blockIdx.x] + woff + incl - s;
    #pragma unroll
    for (int j = 0; j < 8; ++j) {
        int idx = start + j;
        if (idx < N) { rowptr[idx] = run; cursor[idx] = run; }
        run += v[j];
    }
}

// ---------- CSR build: scatter src ids into buckets ----------
__global__ __launch_bounds__(256)
void scatter_kernel(const int* __restrict__ ei, int E, int N,
                    int* __restrict__ cursor, int* __restrict__ csr_src)
{
    int e = blockIdx.x * blockDim.x + threadIdx.x;
    int Etot = E + N;
    if (e >= Etot) return;
    int s, d;
    if (e < E) { s = ei[e]; d = ei[E + e]; } else { s = d = e - E; }
    int pos = atomicAdd(&cursor[d], 1);
    csr_src[pos] = s;
}

// ---------- fused per-node GAT aggregation (no-max softmax) ----------
// one wave per node; lane owns concat channels [lane*4, lane*4+4),
// i.e. head h = lane>>4, in-head channels cin = (lane&15)*4 ...+4.
// mode 0: concat -> out[node*256 + lane*4] (float4)
// mode 1: head-mean -> +bias, BN, ELU, +resid -> outp[node*ldo + cin] (lanes 0..15)
__global__ __launch_bounds__(256)
void aggregate_kernel(const int* __restrict__ rowptr, const int* __restrict__ csr_src,
                      const float* __restrict__ as_n, const float* __restrict__ ad_n,
                      const float* __restrict__ xh,
                      const float* __restrict__ bias,
                      float* __restrict__ outp, int ldo,
                      int N, int mode,
                      const float* __restrict__ bn_g, const float* __restrict__ bn_b,
                      const float* __restrict__ bn_m, const float* __restrict__ bn_v,
                      const float* __restrict__ resid)
{
    int node = (blockIdx.x * blockDim.x + threadIdx.x) >> 6;
    int lane = threadIdx.x & 63;
    if (node >= N) return;
    int h = lane >> 4;
    int e0 = rowptr[node], e1 = rowptr[node + 1];

    float4 adv = ((const float4*)ad_n)[node];
    float adh = (h < 2) ? (h == 0 ? adv.x : adv.y) : (h == 2 ? adv.z : adv.w);

    // weighted accumulation, softmax without max-shift (logits are O(1))
    float4 acc = make_float4(0.f, 0.f, 0.f, 0.f);
    float wsum = 0.f;
    int e = e0;
    for (; e + 1 < e1; e += 2) {
        int s0 = csr_src[e], s1 = csr_src[e + 1];
        float l0 = as_n[s0 * 4 + h] + adh;
        float l1 = as_n[s1 * 4 + h] + adh;
        float4 xv0 = *(const float4*)(xh + (size_t)s0 * 256 + lane * 4);
        float4 xv1 = *(const float4*)(xh + (size_t)s1 * 256 + lane * 4);
        l0 = fmaxf(l0, NEG * l0);
        l1 = fmaxf(l1, NEG * l1);
        float w0 = __expf(l0);
        float w1 = __expf(l1);
        acc.x += w0 * xv0.x; acc.y += w0 * xv0.y;
        acc.z += w0 * xv0.z; acc.w += w0 * xv0.w;
        acc.x += w1 * xv1.x; acc.y += w1 * xv1.y;
        acc.z += w1 * xv1.z; acc.w += w1 * xv1.w;
        wsum += w0 + w1;
    }
    if (e < e1) {
        int s0 = csr_src[e];
        float l0 = as_n[s0 * 4 + h] + adh;
        l0 = fmaxf(l0, NEG * l0);
        float w0 = __expf(l0);
        float4 xv0 = *(const float4*)(xh + (size_t)s0 * 256 + lane * 4);
        acc.x += w0 * xv0.x; acc.y += w0 * xv0.y;
        acc.z += w0 * xv0.z; acc.w += w0 * xv0.w;
        wsum += w0;
    }
    float rw = 1.f / wsum;
    acc.x *= rw; acc.y *= rw; acc.z *= rw; acc.w *= rw;

    if (mode == 0) {
        float4 bs = *(const float4*)(bias + lane * 4);
        acc.x += bs.x; acc.y += bs.y; acc.z += bs.z; acc.w += bs.w;
        *(float4*)(outp + (size_t)node * 256 + lane * 4) = acc;
    } else {
        // mean over heads: sum across the 4 head-groups (xor 16, 32)
        #pragma unroll
        for (int off = 16; off <= 32; off <<= 1) {
            acc.x += __shfl_xor(acc.x, off);
            acc.y += __shfl_xor(acc.y, off);
            acc.z += __shfl_xor(acc.z, off);
            acc.w += __shfl_xor(acc.w, off);
        }
        if (lane < 16) {
            int cin = lane * 4;
            float4 bs = *(const float4*)(bias + cin);
            float4 g = *(const float4*)(bn_g + cin);
            float4 b = *(const float4*)(bn_b + cin);
            float4 m = *(const float4*)(bn_m + cin);
            float4 vv = *(const float4*)(bn_v + cin);
            float4 rs = *(const float4*)(resid + (size_t)node * ldo + cin);
            float o[4] = {acc.x, acc.y, acc.z, acc.w};
            float bb[4] = {bs.x, bs.y, bs.z, bs.w};
            float gg[4] = {g.x, g.y, g.z, g.w};
            float be[4] = {b.x, b.y, b.z, b.w};
            float mm[4] = {m.x, m.y, m.z, m.w};
            float va[4] = {vv.x, vv.y, vv.z, vv.w};
            float rr[4] = {rs.x, rs.y, rs.z, rs.w};
            float4 res;
            float* rp = &res.x;
            #pragma unroll
            for (int j = 0; j < 4; ++j) {
                float v = 0.25f * o[j] + bb[j];
                float sg = gg[j] / sqrtf(va[j] + BNEPS);
                v = (v - mm[j]) * sg + be[j];
                v = v > 0.f ? v : __expf(v) - 1.f;
                rp[j] = v + rr[j];
            }
            *(float4*)(outp + (size_t)node * ldo + cin) = res;
        }
    }
}

// ---------- per-node pooling logits: one wave per node ----------
__global__ __launch_bounds__(256)
void att_logit_kernel(const float* __restrict__ hjk, const float* __restrict__ attW,
                      const float* __restrict__ attb, float* __restrict__ l, int N)
{
    int wid  = (blockIdx.x * blockDim.x + threadIdx.x) >> 6;
    int lane = threadIdx.x & 63;
    if (wid >= N) return;
    float v = hjk[(size_t)wid * 64 + lane] * attW[lane];
    #pragma unroll
    for (int off = 32; off; off >>= 1) v += __shfl_xor(v, off);
    if (lane == 0) l[wid] = v + attb[0];
}

// ---------- graph boundaries (batch is sorted) ----------
__global__ void gstart_kernel(const int* __restrict__ batch, int N, int* __restrict__ gstart)
{
    int t = threadIdx.x;
    if (t > NGRAPH) return;
    int lo = 0, hi = N;
    while (lo < hi) {
        int mid = (lo + hi) >> 1;
        if (batch[mid] < t) lo = mid + 1; else hi = mid;
    }
    gstart[t] = lo;
}

// ---------- attention pooling: one block per graph ----------
__global__ __launch_bounds__(256)
void pool_kernel(const float* __restrict__ hjk, const float* __restrict__ l,
                 const int* __restrict__ gstart, float* __restrict__ hg)
{
    int g = blockIdx.x;
    int s0 = gstart[g], s1 = gstart[g + 1];
    __shared__ float red[256];
    int tid = threadIdx.x;

    float m = -INFINITY;
    for (int n = s0 + tid; n < s1; n += 256) m = fmaxf(m, l[n]);
    red[tid] = m; __syncthreads();
    for (int o = 128; o; o >>= 1) {
        if (tid < o) red[tid] = fmaxf(red[tid], red[tid + o]);
        __syncthreads();
    }
    m = red[0]; __syncthreads();

    float ssum = 0.f;
    for (int n = s0 + tid; n < s1; n += 256) ssum += __expf(l[n] - m);
    red[tid] = ssum; __syncthreads();
    for (int o = 128; o; o >>= 1) {
        if (tid < o) red[tid] += red[tid + o];
        __syncthreads();
    }
    float ssal = red[0]; __syncthreads();

    int c = tid & 63, q = tid >> 6;
    float acc = 0.f;
    for (int n = s0 + q; n < s1; n += 4)
        acc += __expf(l[n] - m) * hjk[(size_t)n * 64 + c];
    red[tid] = acc; __syncthreads();
    if (q == 0) {
        float v = red[c] + red[64 + c] + red[128 + c] + red[192 + c];
        hg[g * 64 + c] = (s1 > s0) ? v / ssal : 0.f;
    }
}

// ---------- classifier head: one block (32 threads) per graph ----------
__global__ void cls_kernel(const float* __restrict__ hg,
                           const float* __restrict__ W1, const float* __restrict__ b1,
                           const float* __restrict__ W2, const float* __restrict__ b2,
                           float* __restrict__ out)
{
    int g = blockIdx.x, t = threadIdx.x;  // 32 threads
    __shared__ float z[32];
    float acc = b1[t];
    for (int k = 0; k < 64; ++k) acc += hg[g * 64 + k] * W1[k * 32 + t];
    z[t] = fmaxf(acc, 0.f);
    __syncthreads();
    if (t < 2) {
        float o = b2[t];
        for (int j = 0; j < 32; ++j) o += z[j] * W2[j * 2 + t];
        out[g * 2 + t] = o;
    }
}

extern "C" void kernel_launch(void* const* d_in, const int* in_sizes, int n_in,
                              void* d_out, int out_size, void* d_ws, size_t ws_size,
                              hipStream_t stream)
{
    const float* x        = (const float*)d_in[0];
    const int*   ei       = (const int*)d_in[1];
    const int*   batch    = (const int*)d_in[2];
    const float* conv0_W  = (const float*)d_in[3];
    const float* conv0_as = (const float*)d_in[4];
    const float* conv0_ad = (const float*)d_in[5];
    const float* conv0_b  = (const float*)d_in[6];
    const float* pre0_W   = (const float*)d_in[7];
    const float* pre0_b   = (const float*)d_in[8];
    const float* convs_W  = (const float*)d_in[9];
    const float* convs_as = (const float*)d_in[10];
    const float* convs_ad = (const float*)d_in[11];
    const float* convs_b  = (const float*)d_in[12];
    const float* bn_g     = (const float*)d_in[13];
    const float* bn_b     = (const float*)d_in[14];
    const float* bn_m     = (const float*)d_in[15];
    const float* bn_v     = (const float*)d_in[16];
    const float* jump_W   = (const float*)d_in[17];
    const float* jump_b   = (const float*)d_in[18];
    const float* att_W    = (const float*)d_in[19];
    const float* att_b    = (const float*)d_in[20];
    const float* cls_W1   = (const float*)d_in[21];
    const float* cls_b1   = (const float*)d_in[22];
    const float* cls_W2   = (const float*)d_in[23];
    const float* cls_b2   = (const float*)d_in[24];
    float* out = (float*)d_out;

    const int N = in_sizes[0] / 128;   // 50000
    const int E = in_sizes[1] / 2;     // 400000
    const int Etot = E + N;
    const int nb = (N + SCAN_CHUNK - 1) / SCAN_CHUNK;   // scan blocks (25), must be <= 64

    // workspace layout
    float* ws      = (float*)d_ws;
    float* xh      = ws;                                 // N*256
    float* h256    = xh + (size_t)N * 256;               // N*256
    float* repsAll = h256 + (size_t)N * 256;             // N*192
    float* as_n    = repsAll + (size_t)N * 192;          // N*4
    float* ad_n    = as_n + (size_t)N * 4;               // N*4
    float* hg      = ad_n + (size_t)N * 4;               // 64*64
    int*   rowptr  = (int*)(hg + NGRAPH * 64);           // N+1
    int*   cursor  = rowptr + (N + 1);                   // N
    int*   counts  = cursor + N;                         // N
    int*   csr_src = counts + N;                         // Etot
    int*   gstart  = csr_src + Etot;                     // 65
    int*   blocksum = gstart + (NGRAPH + 1);             // 64
    int*   blockoff = blocksum + 64;                     // 65
    float* hjk     = xh;    // reuse
    float* lbuf    = as_n;  // reuse

    dim3 blk(256);
    int node_wave_blocks = (N + 3) / 4;          // 1 wave/node
    int edge_blocks      = (Etot + 255) / 256;

    // ---------------- CSR build ----------------
    hipMemsetAsync(counts, 0, (size_t)N * sizeof(int), stream);
    hist_kernel<<<edge_blocks, blk, 0, stream>>>(ei, E, N, counts);
    scan_phase1<<<nb, blk, 0, stream>>>(counts, N, blocksum);
    scan_phase2<<<1, 64, 0, stream>>>(blocksum, nb, blockoff, rowptr, N);
    scan_phase3<<<nb, blk, 0, stream>>>(counts, N, blockoff, rowptr, cursor);
    scatter_kernel<<<edge_blocks, blk, 0, stream>>>(ei, E, N, cursor, csr_src);

    // ---------------- layer 0 ----------------
    {
        dim3 g1((N + 63) / 64, 4);
        gemm_f32<<<g1, blk, 0, stream>>>(x, 128, conv0_W, 256, nullptr, xh, 256,
                                         N, 128, 0, nullptr, nullptr, nullptr, nullptr,
                                         conv0_as, conv0_ad, as_n, ad_n);
        aggregate_kernel<<<node_wave_blocks, blk, 0, stream>>>(
            rowptr, csr_src, as_n, ad_n, xh, conv0_b, h256, 256, N, 0,
            nullptr, nullptr, nullptr, nullptr, nullptr);
        dim3 g2((N + 63) / 64, 1);
        gemm_f32<<<g2, blk, 0, stream>>>(h256, 256, pre0_W, 64, pre0_b, repsAll, 192,
                                         N, 256, 1, bn_g, bn_b, bn_m, bn_v,
                                         nullptr, nullptr, nullptr, nullptr);
    }

    // ---------------- layers 1, 2 ----------------
    for (int i = 0; i < 2; ++i) {
        dim3 g1((N + 63) / 64, 4);
        gemm_f32<<<g1, blk, 0, stream>>>(repsAll + i * 64, 192,
                                         convs_W + (size_t)i * 64 * 256, 256, nullptr,
                                         xh, 256, N, 64, 0, nullptr, nullptr, nullptr, nullptr,
                                         convs_as + i * 256, convs_ad + i * 256, as_n, ad_n);
        aggregate_kernel<<<node_wave_blocks, blk, 0, stream>>>(
            rowptr, csr_src, as_n, ad_n, xh, convs_b + i * 64,
            repsAll + (i + 1) * 64, 192, N, 1,
            bn_g + (i + 1) * 64, bn_b + (i + 1) * 64,
            bn_m + (i + 1) * 64, bn_v + (i + 1) * 64,
            repsAll + i * 64);
    }

    // ---------------- JK projection ----------------
    {
        dim3 g2((N + 63) / 64, 1);
        gemm_f32<<<g2, blk, 0, stream>>>(repsAll, 192, jump_W, 64, jump_b, hjk, 64,
                                         N, 192, 0, nullptr, nullptr, nullptr, nullptr,
                                         nullptr, nullptr, nullptr, nullptr);
    }

    // ---------------- pooling + classifier ----------------
    att_logit_kernel<<<node_wave_blocks, blk, 0, stream>>>(hjk, att_W, att_b, lbuf, N);
    gstart_kernel<<<1, 128, 0, stream>>>(batch, N, gstart);
    pool_kernel<<<NGRAPH, blk, 0, stream>>>(hjk, lbuf, gstart, hg);
    cls_kernel<<<NGRAPH, 32, 0, stream>>>(hg, cls_W1, cls_b1, cls_W2, cls_b2, out);
}

// Round 6
// 556.844 us; speedup vs baseline: 3.8890x; 1.1046x over previous
//
#include <hip/hip_runtime.h>
#include <hip/hip_bf16.h>
#include <math.h>

#define NEG 0.2f
#define BNEPS 1e-5f
#define NGRAPH 64
#define SCAN_CHUNK 2048

__device__ __forceinline__ float bf2f(unsigned short u) {
    return __uint_as_float(((unsigned)u) << 16);
}

// ---------- f32 GEMM: C[M,Nc] = A[M,K]@W[K,Nc] (+bias) (+BN+ELU) (+fused att dots) ----------
// 64x64 tile per 256-thread block, 16 outputs/thread.
// grid: (ceil(M/64), Nc/64). K must be a multiple of 32.
// If att_s != null (xh GEMMs, Nc=256): blockIdx.y == head; epilogue computes
// as_n[row*4+head] (exact, f32, no atomics) and stores xh in BF16 to Cbf
// (f32 C is not written). Otherwise writes f32 C.
__global__ __launch_bounds__(256)
void gemm_f32(const float* __restrict__ A, int lda,
              const float* __restrict__ W, int Nc,
              const float* __restrict__ bias,
              float* __restrict__ C, int ldc,
              int M, int K, int mode,
              const float* __restrict__ bn_g, const float* __restrict__ bn_b,
              const float* __restrict__ bn_m, const float* __restrict__ bn_v,
              const float* __restrict__ att_s, const float* __restrict__ att_d,
              float* __restrict__ as_out, float* __restrict__ ad_out,
              unsigned short* __restrict__ Cbf)
{
    __shared__ __align__(16) float As[32][68];  // As[k][row]
    __shared__ __align__(16) float Ws[32][68];  // Ws[k][col]
    int tid  = threadIdx.x;
    int lane = tid & 63, wave = tid >> 6;
    int row0 = blockIdx.x * 64;
    int colb = blockIdx.y * 64;
    int r4 = wave * 16 + (lane >> 4) * 4;   // tile-local row base (4 rows)
    int c4 = (lane & 15) * 4;               // tile-local col base (4 cols)

    float4 acc[4];
    #pragma unroll
    for (int i = 0; i < 4; ++i) acc[i] = make_float4(0.f, 0.f, 0.f, 0.f);

    // staging coords
    int ar = tid & 63, akq = (tid >> 6) * 8;          // A: row, k-quad
    int wk = tid >> 3, wcq = (tid & 7) * 8;           // W: k, col-quad

    for (int k0 = 0; k0 < K; k0 += 32) {
        // stage A (64 rows x 32 k, transposed)
        int gr = row0 + ar;
        float4 av0, av1;
        if (gr < M) {
            const float* ap = A + (size_t)gr * lda + k0 + akq;
            av0 = *(const float4*)ap;
            av1 = *(const float4*)(ap + 4);
        } else {
            av0 = make_float4(0.f,0.f,0.f,0.f);
            av1 = av0;
        }
        As[akq + 0][ar] = av0.x; As[akq + 1][ar] = av0.y;
        As[akq + 2][ar] = av0.z; As[akq + 3][ar] = av0.w;
        As[akq + 4][ar] = av1.x; As[akq + 5][ar] = av1.y;
        As[akq + 6][ar] = av1.z; As[akq + 7][ar] = av1.w;
        // stage W (32 k x 64 cols)
        const float* wp = W + (size_t)(k0 + wk) * Nc + colb + wcq;
        *(float4*)&Ws[wk][wcq]     = *(const float4*)wp;
        *(float4*)&Ws[wk][wcq + 4] = *(const float4*)(wp + 4);
        __syncthreads();

        #pragma unroll
        for (int kk = 0; kk < 32; ++kk) {
            float4 a = *(const float4*)&As[kk][r4];
            float4 b = *(const float4*)&Ws[kk][c4];
            acc[0].x += a.x * b.x; acc[0].y += a.x * b.y; acc[0].z += a.x * b.z; acc[0].w += a.x * b.w;
            acc[1].x += a.y * b.x; acc[1].y += a.y * b.y; acc[1].z += a.y * b.z; acc[1].w += a.y * b.w;
            acc[2].x += a.z * b.x; acc[2].y += a.z * b.y; acc[2].z += a.z * b.z; acc[2].w += a.z * b.w;
            acc[3].x += a.w * b.x; acc[3].y += a.w * b.y; acc[3].z += a.w * b.z; acc[3].w += a.w * b.w;
        }
        __syncthreads();
    }

    int gc = colb + c4;

    if (att_s) {
        // bf16 xh store + fused attention dots
        #pragma unroll
        for (int i = 0; i < 4; ++i) {
            int row = row0 + r4 + i;
            if (row >= M) continue;
            ushort4 pk;
            pk.x = __bfloat16_as_ushort(__float2bfloat16(acc[i].x));
            pk.y = __bfloat16_as_ushort(__float2bfloat16(acc[i].y));
            pk.z = __bfloat16_as_ushort(__float2bfloat16(acc[i].z));
            pk.w = __bfloat16_as_ushort(__float2bfloat16(acc[i].w));
            *(ushort4*)(Cbf + (size_t)row * 256 + gc) = pk;
        }
        float4 sa = *(const float4*)(att_s + gc);
        float4 da = *(const float4*)(att_d + gc);
        #pragma unroll
        for (int i = 0; i < 4; ++i) {
            float ps = acc[i].x * sa.x + acc[i].y * sa.y + acc[i].z * sa.z + acc[i].w * sa.w;
            float pd = acc[i].x * da.x + acc[i].y * da.y + acc[i].z * da.z + acc[i].w * da.w;
            #pragma unroll
            for (int o = 1; o < 16; o <<= 1) {
                ps += __shfl_xor(ps, o);
                pd += __shfl_xor(pd, o);
            }
            int row = row0 + r4 + i;
            if ((lane & 15) == 0 && row < M) {
                as_out[row * 4 + blockIdx.y] = ps;
                ad_out[row * 4 + blockIdx.y] = pd;
            }
        }
        return;
    }

    // f32 epilogue
    float4 bs = make_float4(0.f,0.f,0.f,0.f);
    if (bias) bs = *(const float4*)(bias + gc);
    float4 sg = make_float4(1.f,1.f,1.f,1.f), sb = make_float4(0.f,0.f,0.f,0.f);
    if (mode == 1) {
        float4 g = *(const float4*)(bn_g + gc);
        float4 b = *(const float4*)(bn_b + gc);
        float4 m = *(const float4*)(bn_m + gc);
        float4 v = *(const float4*)(bn_v + gc);
        sg.x = g.x / sqrtf(v.x + BNEPS); sb.x = b.x - m.x * sg.x;
        sg.y = g.y / sqrtf(v.y + BNEPS); sb.y = b.y - m.y * sg.y;
        sg.z = g.z / sqrtf(v.z + BNEPS); sb.z = b.z - m.z * sg.z;
        sg.w = g.w / sqrtf(v.w + BNEPS); sb.w = b.w - m.w * sg.w;
    }
    #pragma unroll
    for (int i = 0; i < 4; ++i) {
        int row = row0 + r4 + i;
        if (row >= M) continue;
        float4 o = acc[i];
        o.x += bs.x; o.y += bs.y; o.z += bs.z; o.w += bs.w;
        if (mode == 1) {
            o.x = o.x * sg.x + sb.x; o.y = o.y * sg.y + sb.y;
            o.z = o.z * sg.z + sb.z; o.w = o.w * sg.w + sb.w;
            o.x = o.x > 0.f ? o.x : __expf(o.x) - 1.f;
            o.y = o.y > 0.f ? o.y : __expf(o.y) - 1.f;
            o.z = o.z > 0.f ? o.z : __expf(o.z) - 1.f;
            o.w = o.w > 0.f ? o.w : __expf(o.w) - 1.f;
        }
        *(float4*)(C + (size_t)row * ldc + gc) = o;
    }
}

// ---------- CSR build: histogram over dst ----------
__global__ __launch_bounds__(256)
void hist_kernel(const int* __restrict__ ei, int E, int N, int* __restrict__ counts)
{
    int e = blockIdx.x * blockDim.x + threadIdx.x;
    int Etot = E + N;
    if (e >= Etot) return;
    int d = (e < E) ? ei[E + e] : e - E;
    atomicAdd(&counts[d], 1);
}

// ---------- scan phase 1: per-block partial sums (2048 elems/block) ----------
__global__ __launch_bounds__(256)
void scan_phase1(const int* __restrict__ counts, int N, int* __restrict__ blocksum)
{
    __shared__ int wsum[4];
    int tid = threadIdx.x, lane = tid & 63, wave = tid >> 6;
    int base = blockIdx.x * SCAN_CHUNK;
    int s = 0;
    #pragma unroll
    for (int j = 0; j < SCAN_CHUNK / 256; ++j) {
        int idx = base + tid + j * 256;
        if (idx < N) s += counts[idx];
    }
    #pragma unroll
    for (int o = 32; o; o >>= 1) s += __shfl_xor(s, o);
    if (lane == 0) wsum[wave] = s;
    __syncthreads();
    if (tid == 0) blocksum[blockIdx.x] = wsum[0] + wsum[1] + wsum[2] + wsum[3];
}

// ---------- scan phase 2: exclusive scan of block sums (nb <= 64), 1 wave ----------
__global__ void scan_phase2(const int* __restrict__ blocksum, int nb,
                            int* __restrict__ blockoff, int* __restrict__ rowptr, int N)
{
    int lane = threadIdx.x;  // 64 threads
    int v = (lane < nb) ? blocksum[lane] : 0;
    int incl = v;
    #pragma unroll
    for (int o = 1; o < 64; o <<= 1) {
        int t = __shfl_up(incl, o);
        if (lane >= o) incl += t;
    }
    if (lane < nb) blockoff[lane + 1] = incl;
    if (lane == 0) blockoff[0] = 0;
    int total = __shfl(incl, nb - 1);
    if (lane == 0) rowptr[N] = total;
}

// ---------- scan phase 3: per-block exclusive scan + offset ----------
__global__ __launch_bounds__(256)
void scan_phase3(const int* __restrict__ counts, int N,
                 const int* __restrict__ blockoff,
                 int* __restrict__ rowptr, int* __restrict__ cursor)
{
    __shared__ int wsum[4];
    int tid = threadIdx.x, lane = tid & 63, wave = tid >> 6;
    int start = blockIdx.x * SCAN_CHUNK + tid * 8;
    int v[8];
    int s = 0;
    #pragma unroll
    for (int j = 0; j < 8; ++j) {
        v[j] = (start + j < N) ? counts[start + j] : 0;
        s += v[j];
    }
    int incl = s;
    #pragma unroll
    for (int o = 1; o < 64; o <<= 1) {
        int t = __shfl_up(incl, o);
        if (lane >= o) incl += t;
    }
    if (lane == 63) wsum[wave] = incl;
    __syncthreads();
    int woff = 0;
    #pragma unroll
    for (int w = 0; w < 4; ++w) if (w < wave) woff += wsum[w];
    int run = blockoff[blockIdx.x] + woff + incl - s;
    #pragma unroll
    for (int j = 0; j < 8; ++j) {
        int idx = start + j;
        if (idx < N) { rowptr[idx] = run; cursor[idx] = run; }
        run += v[j];
    }
}

// ---------- CSR build: scatter src ids into buckets ----------
__global__ __launch_bounds__(256)
void scatter_kernel(const int* __restrict__ ei, int E, int N,
                    int* __restrict__ cursor, int* __restrict__ csr_src)
{
    int e = blockIdx.x * blockDim.x + threadIdx.x;
    int Etot = E + N;
    if (e >= Etot) return;
    int s, d;
    if (e < E) { s = ei[e]; d = ei[E + e]; } else { s = d = e - E; }
    int pos = atomicAdd(&cursor[d], 1);
    csr_src[pos] = s;
}

// ---------- fused per-node GAT aggregation (no-max softmax, bf16 xh gather) ----------
// one wave per node; lane owns concat channels [lane*4, lane*4+4),
// i.e. head h = lane>>4, in-head channels cin = (lane&15)*4 ...+4.
// mode 0: concat -> out[node*256 + lane*4] (float4)
// mode 1: head-mean -> +bias, BN, ELU, +resid -> outp[node*ldo + cin] (lanes 0..15)
__global__ __launch_bounds__(256)
void aggregate_kernel(const int* __restrict__ rowptr, const int* __restrict__ csr_src,
                      const float* __restrict__ as_n, const float* __restrict__ ad_n,
                      const unsigned short* __restrict__ xh,
                      const float* __restrict__ bias,
                      float* __restrict__ outp, int ldo,
                      int N, int mode,
                      const float* __restrict__ bn_g, const float* __restrict__ bn_b,
                      const float* __restrict__ bn_m, const float* __restrict__ bn_v,
                      const float* __restrict__ resid)
{
    int node = (blockIdx.x * blockDim.x + threadIdx.x) >> 6;
    int lane = threadIdx.x & 63;
    if (node >= N) return;
    int h = lane >> 4;
    int e0 = rowptr[node], e1 = rowptr[node + 1];

    float4 adv = ((const float4*)ad_n)[node];
    float adh = (h < 2) ? (h == 0 ? adv.x : adv.y) : (h == 2 ? adv.z : adv.w);

    // weighted accumulation, softmax without max-shift (logits are O(1))
    float4 acc = make_float4(0.f, 0.f, 0.f, 0.f);
    float wsum = 0.f;
    int e = e0;
    for (; e + 1 < e1; e += 2) {
        int s0 = csr_src[e], s1 = csr_src[e + 1];
        float l0 = as_n[s0 * 4 + h] + adh;
        float l1 = as_n[s1 * 4 + h] + adh;
        ushort4 xv0 = *(const ushort4*)(xh + (size_t)s0 * 256 + lane * 4);
        ushort4 xv1 = *(const ushort4*)(xh + (size_t)s1 * 256 + lane * 4);
        l0 = fmaxf(l0, NEG * l0);
        l1 = fmaxf(l1, NEG * l1);
        float w0 = __expf(l0);
        float w1 = __expf(l1);
        acc.x += w0 * bf2f(xv0.x); acc.y += w0 * bf2f(xv0.y);
        acc.z += w0 * bf2f(xv0.z); acc.w += w0 * bf2f(xv0.w);
        acc.x += w1 * bf2f(xv1.x); acc.y += w1 * bf2f(xv1.y);
        acc.z += w1 * bf2f(xv1.z); acc.w += w1 * bf2f(xv1.w);
        wsum += w0 + w1;
    }
    if (e < e1) {
        int s0 = csr_src[e];
        float l0 = as_n[s0 * 4 + h] + adh;
        l0 = fmaxf(l0, NEG * l0);
        float w0 = __expf(l0);
        ushort4 xv0 = *(const ushort4*)(xh + (size_t)s0 * 256 + lane * 4);
        acc.x += w0 * bf2f(xv0.x); acc.y += w0 * bf2f(xv0.y);
        acc.z += w0 * bf2f(xv0.z); acc.w += w0 * bf2f(xv0.w);
        wsum += w0;
    }
    float rw = 1.f / wsum;
    acc.x *= rw; acc.y *= rw; acc.z *= rw; acc.w *= rw;

    if (mode == 0) {
        float4 bs = *(const float4*)(bias + lane * 4);
        acc.x += bs.x; acc.y += bs.y; acc.z += bs.z; acc.w += bs.w;
        *(float4*)(outp + (size_t)node * 256 + lane * 4) = acc;
    } else {
        // mean over heads: sum across the 4 head-groups (xor 16, 32)
        #pragma unroll
        for (int off = 16; off <= 32; off <<= 1) {
            acc.x += __shfl_xor(acc.x, off);
            acc.y += __shfl_xor(acc.y, off);
            acc.z += __shfl_xor(acc.z, off);
            acc.w += __shfl_xor(acc.w, off);
        }
        if (lane < 16) {
            int cin = lane * 4;
            float4 bs = *(const float4*)(bias + cin);
            float4 g = *(const float4*)(bn_g + cin);
            float4 b = *(const float4*)(bn_b + cin);
            float4 m = *(const float4*)(bn_m + cin);
            float4 vv = *(const float4*)(bn_v + cin);
            float4 rs = *(const float4*)(resid + (size_t)node * ldo + cin);
            float o[4] = {acc.x, acc.y, acc.z, acc.w};
            float bb[4] = {bs.x, bs.y, bs.z, bs.w};
            float gg[4] = {g.x, g.y, g.z, g.w};
            float be[4] = {b.x, b.y, b.z, b.w};
            float mm[4] = {m.x, m.y, m.z, m.w};
            float va[4] = {vv.x, vv.y, vv.z, vv.w};
            float rr[4] = {rs.x, rs.y, rs.z, rs.w};
            float4 res;
            float* rp = &res.x;
            #pragma unroll
            for (int j = 0; j < 4; ++j) {
                float v = 0.25f * o[j] + bb[j];
                float sg = gg[j] / sqrtf(va[j] + BNEPS);
                v = (v - mm[j]) * sg + be[j];
                v = v > 0.f ? v : __expf(v) - 1.f;
                rp[j] = v + rr[j];
            }
            *(float4*)(outp + (size_t)node * ldo + cin) = res;
        }
    }
}

// ---------- per-node pooling logits: one wave per node ----------
__global__ __launch_bounds__(256)
void att_logit_kernel(const float* __restrict__ hjk, const float* __restrict__ attW,
                      const float* __restrict__ attb, float* __restrict__ l, int N)
{
    int wid  = (blockIdx.x * blockDim.x + threadIdx.x) >> 6;
    int lane = threadIdx.x & 63;
    if (wid >= N) return;
    float v = hjk[(size_t)wid * 64 + lane] * attW[lane];
    #pragma unroll
    for (int off = 32; off; off >>= 1) v += __shfl_xor(v, off);
    if (lane == 0) l[wid] = v + attb[0];
}

// ---------- graph boundaries (batch is sorted) ----------
__global__ void gstart_kernel(const int* __restrict__ batch, int N, int* __restrict__ gstart)
{
    int t = threadIdx.x;
    if (t > NGRAPH) return;
    int lo = 0, hi = N;
    while (lo < hi) {
        int mid = (lo + hi) >> 1;
        if (batch[mid] < t) lo = mid + 1; else hi = mid;
    }
    gstart[t] = lo;
}

// ---------- attention pooling: one block per graph ----------
__global__ __launch_bounds__(256)
void pool_kernel(const float* __restrict__ hjk, const float* __restrict__ l,
                 const int* __restrict__ gstart, float* __restrict__ hg)
{
    int g = blockIdx.x;
    int s0 = gstart[g], s1 = gstart[g + 1];
    __shared__ float red[256];
    int tid = threadIdx.x;

    float m = -INFINITY;
    for (int n = s0 + tid; n < s1; n += 256) m = fmaxf(m, l[n]);
    red[tid] = m; __syncthreads();
    for (int o = 128; o; o >>= 1) {
        if (tid < o) red[tid] = fmaxf(red[tid], red[tid + o]);
        __syncthreads();
    }
    m = red[0]; __syncthreads();

    float ssum = 0.f;
    for (int n = s0 + tid; n < s1; n += 256) ssum += __expf(l[n] - m);
    red[tid] = ssum; __syncthreads();
    for (int o = 128; o; o >>= 1) {
        if (tid < o) red[tid] += red[tid + o];
        __syncthreads();
    }
    float ssal = red[0]; __syncthreads();

    int c = tid & 63, q = tid >> 6;
    float acc = 0.f;
    for (int n = s0 + q; n < s1; n += 4)
        acc += __expf(l[n] - m) * hjk[(size_t)n * 64 + c];
    red[tid] = acc; __syncthreads();
    if (q == 0) {
        float v = red[c] + red[64 + c] + red[128 + c] + red[192 + c];
        hg[g * 64 + c] = (s1 > s0) ? v / ssal : 0.f;
    }
}

// ---------- classifier head: one block (32 threads) per graph ----------
__global__ void cls_kernel(const float* __restrict__ hg,
                           const float* __restrict__ W1, const float* __restrict__ b1,
                           const float* __restrict__ W2, const float* __restrict__ b2,
                           float* __restrict__ out)
{
    int g = blockIdx.x, t = threadIdx.x;  // 32 threads
    __shared__ float z[32];
    float acc = b1[t];
    for (int k = 0; k < 64; ++k) acc += hg[g * 64 + k] * W1[k * 32 + t];
    z[t] = fmaxf(acc, 0.f);
    __syncthreads();
    if (t < 2) {
        float o = b2[t];
        for (int j = 0; j < 32; ++j) o += z[j] * W2[j * 2 + t];
        out[g * 2 + t] = o;
    }
}

extern "C" void kernel_launch(void* const* d_in, const int* in_sizes, int n_in,
                              void* d_out, int out_size, void* d_ws, size_t ws_size,
                              hipStream_t stream)
{
    const float* x        = (const float*)d_in[0];
    const int*   ei       = (const int*)d_in[1];
    const int*   batch    = (const int*)d_in[2];
    const float* conv0_W  = (const float*)d_in[3];
    const float* conv0_as = (const float*)d_in[4];
    const float* conv0_ad = (const float*)d_in[5];
    const float* conv0_b  = (const float*)d_in[6];
    const float* pre0_W   = (const float*)d_in[7];
    const float* pre0_b   = (const float*)d_in[8];
    const float* convs_W  = (const float*)d_in[9];
    const float* convs_as = (const float*)d_in[10];
    const float* convs_ad = (const float*)d_in[11];
    const float* convs_b  = (const float*)d_in[12];
    const float* bn_g     = (const float*)d_in[13];
    const float* bn_b     = (const float*)d_in[14];
    const float* bn_m     = (const float*)d_in[15];
    const float* bn_v     = (const float*)d_in[16];
    const float* jump_W   = (const float*)d_in[17];
    const float* jump_b   = (const float*)d_in[18];
    const float* att_W    = (const float*)d_in[19];
    const float* att_b    = (const float*)d_in[20];
    const float* cls_W1   = (const float*)d_in[21];
    const float* cls_b1   = (const float*)d_in[22];
    const float* cls_W2   = (const float*)d_in[23];
    const float* cls_b2   = (const float*)d_in[24];
    float* out = (float*)d_out;

    const int N = in_sizes[0] / 128;   // 50000
    const int E = in_sizes[1] / 2;     // 400000
    const int Etot = E + N;
    const int nb = (N + SCAN_CHUNK - 1) / SCAN_CHUNK;   // scan blocks (25), must be <= 64

    // workspace layout
    float* ws      = (float*)d_ws;
    unsigned short* xh_bf = (unsigned short*)ws;         // N*256 bf16
    float* h256    = (float*)(xh_bf + (size_t)N * 256);  // N*256 f32
    float* repsAll = h256 + (size_t)N * 256;             // N*192
    float* as_n    = repsAll + (size_t)N * 192;          // N*4
    float* ad_n    = as_n + (size_t)N * 4;               // N*4
    float* hg      = ad_n + (size_t)N * 4;               // 64*64
    int*   rowptr  = (int*)(hg + NGRAPH * 64);           // N+1
    int*   cursor  = rowptr + (N + 1);                   // N
    int*   counts  = cursor + N;                         // N
    int*   csr_src = counts + N;                         // Etot
    int*   gstart  = csr_src + Etot;                     // 65
    int*   blocksum = gstart + (NGRAPH + 1);             // 64
    int*   blockoff = blocksum + 64;                     // 65
    float* hjk     = h256;  // reuse (h256 free after pre0 GEMM)
    float* lbuf    = as_n;  // reuse

    dim3 blk(256);
    int node_wave_blocks = (N + 3) / 4;          // 1 wave/node
    int edge_blocks      = (Etot + 255) / 256;

    // ---------------- CSR build ----------------
    hipMemsetAsync(counts, 0, (size_t)N * sizeof(int), stream);
    hist_kernel<<<edge_blocks, blk, 0, stream>>>(ei, E, N, counts);
    scan_phase1<<<nb, blk, 0, stream>>>(counts, N, blocksum);
    scan_phase2<<<1, 64, 0, stream>>>(blocksum, nb, blockoff, rowptr, N);
    scan_phase3<<<nb, blk, 0, stream>>>(counts, N, blockoff, rowptr, cursor);
    scatter_kernel<<<edge_blocks, blk, 0, stream>>>(ei, E, N, cursor, csr_src);

    // ---------------- layer 0 ----------------
    {
        dim3 g1((N + 63) / 64, 4);
        gemm_f32<<<g1, blk, 0, stream>>>(x, 128, conv0_W, 256, nullptr, nullptr, 256,
                                         N, 128, 0, nullptr, nullptr, nullptr, nullptr,
                                         conv0_as, conv0_ad, as_n, ad_n, xh_bf);
        aggregate_kernel<<<node_wave_blocks, blk, 0, stream>>>(
            rowptr, csr_src, as_n, ad_n, xh_bf, conv0_b, h256, 256, N, 0,
            nullptr, nullptr, nullptr, nullptr, nullptr);
        dim3 g2((N + 63) / 64, 1);
        gemm_f32<<<g2, blk, 0, stream>>>(h256, 256, pre0_W, 64, pre0_b, repsAll, 192,
                                         N, 256, 1, bn_g, bn_b, bn_m, bn_v,
                                         nullptr, nullptr, nullptr, nullptr, nullptr);
    }

    // ---------------- layers 1, 2 ----------------
    for (int i = 0; i < 2; ++i) {
        dim3 g1((N + 63) / 64, 4);
        gemm_f32<<<g1, blk, 0, stream>>>(repsAll + i * 64, 192,
                                         convs_W + (size_t)i * 64 * 256, 256, nullptr,
                                         nullptr, 256, N, 64, 0,
                                         nullptr, nullptr, nullptr, nullptr,
                                         convs_as + i * 256, convs_ad + i * 256,
                                         as_n, ad_n, xh_bf);
        aggregate_kernel<<<node_wave_blocks, blk, 0, stream>>>(
            rowptr, csr_src, as_n, ad_n, xh_bf, convs_b + i * 64,
            repsAll + (i + 1) * 64, 192, N, 1,
            bn_g + (i + 1) * 64, bn_b + (i + 1) * 64,
            bn_m + (i + 1) * 64, bn_v + (i + 1) * 64,
            repsAll + i * 64);
    }

    // ---------------- JK projection ----------------
    {
        dim3 g2((N + 63) / 64, 1);
        gemm_f32<<<g2, blk, 0, stream>>>(repsAll, 192, jump_W, 64, jump_b, hjk, 64,
                                         N, 192, 0, nullptr, nullptr, nullptr, nullptr,
                                         nullptr, nullptr, nullptr, nullptr, nullptr);
    }

    // ---------------- pooling + classifier ----------------
    att_logit_kernel<<<node_wave_blocks, blk, 0, stream>>>(hjk, att_W, att_b, lbuf, N);
    gstart_kernel<<<1, 128, 0, stream>>>(batch, N, gstart);
    pool_kernel<<<NGRAPH, blk, 0, stream>>>(hjk, lbuf, gstart, hg);
    cls_kernel<<<NGRAPH, 32, 0, stream>>>(hg, cls_W1, cls_b1, cls_W2, cls_b2, out);
}

// Round 7
// 528.665 us; speedup vs baseline: 4.0963x; 1.0533x over previous
//
#include <hip/hip_runtime.h>
#include <hip/hip_bf16.h>
#include <math.h>

#define NEG 0.2f
#define BNEPS 1e-5f
#define NGRAPH 64
#define SCAN_CHUNK 2048
#define POOL_BLOCKS 256

__device__ __forceinline__ float bf2f(unsigned short u) {
    return __uint_as_float(((unsigned)u) << 16);
}

// ---------- f32 GEMM: C[M,Nc] = A[M,K]@W[K,Nc] (+bias) (+BN+ELU) (+fused att dots) ----------
// 64x64 tile per 256-thread block, 16 outputs/thread.
// grid: (ceil(M/64), Nc/64). K must be a multiple of 32.
// If att_s != null (xh GEMMs, Nc=256): blockIdx.y == head; epilogue computes
// as_n[row*4+head] (exact, f32, no atomics) and stores xh in BF16 to Cbf
// (f32 C is not written). Otherwise writes f32 C.
__global__ __launch_bounds__(256)
void gemm_f32(const float* __restrict__ A, int lda,
              const float* __restrict__ W, int Nc,
              const float* __restrict__ bias,
              float* __restrict__ C, int ldc,
              int M, int K, int mode,
              const float* __restrict__ bn_g, const float* __restrict__ bn_b,
              const float* __restrict__ bn_m, const float* __restrict__ bn_v,
              const float* __restrict__ att_s, const float* __restrict__ att_d,
              float* __restrict__ as_out, float* __restrict__ ad_out,
              unsigned short* __restrict__ Cbf)
{
    __shared__ __align__(16) float As[32][68];  // As[k][row]
    __shared__ __align__(16) float Ws[32][68];  // Ws[k][col]
    int tid  = threadIdx.x;
    int lane = tid & 63, wave = tid >> 6;
    int row0 = blockIdx.x * 64;
    int colb = blockIdx.y * 64;
    int r4 = wave * 16 + (lane >> 4) * 4;   // tile-local row base (4 rows)
    int c4 = (lane & 15) * 4;               // tile-local col base (4 cols)

    float4 acc[4];
    #pragma unroll
    for (int i = 0; i < 4; ++i) acc[i] = make_float4(0.f, 0.f, 0.f, 0.f);

    // staging coords
    int ar = tid & 63, akq = (tid >> 6) * 8;          // A: row, k-quad
    int wk = tid >> 3, wcq = (tid & 7) * 8;           // W: k, col-quad

    for (int k0 = 0; k0 < K; k0 += 32) {
        // stage A (64 rows x 32 k, transposed)
        int gr = row0 + ar;
        float4 av0, av1;
        if (gr < M) {
            const float* ap = A + (size_t)gr * lda + k0 + akq;
            av0 = *(const float4*)ap;
            av1 = *(const float4*)(ap + 4);
        } else {
            av0 = make_float4(0.f,0.f,0.f,0.f);
            av1 = av0;
        }
        As[akq + 0][ar] = av0.x; As[akq + 1][ar] = av0.y;
        As[akq + 2][ar] = av0.z; As[akq + 3][ar] = av0.w;
        As[akq + 4][ar] = av1.x; As[akq + 5][ar] = av1.y;
        As[akq + 6][ar] = av1.z; As[akq + 7][ar] = av1.w;
        // stage W (32 k x 64 cols)
        const float* wp = W + (size_t)(k0 + wk) * Nc + colb + wcq;
        *(float4*)&Ws[wk][wcq]     = *(const float4*)wp;
        *(float4*)&Ws[wk][wcq + 4] = *(const float4*)(wp + 4);
        __syncthreads();

        #pragma unroll
        for (int kk = 0; kk < 32; ++kk) {
            float4 a = *(const float4*)&As[kk][r4];
            float4 b = *(const float4*)&Ws[kk][c4];
            acc[0].x += a.x * b.x; acc[0].y += a.x * b.y; acc[0].z += a.x * b.z; acc[0].w += a.x * b.w;
            acc[1].x += a.y * b.x; acc[1].y += a.y * b.y; acc[1].z += a.y * b.z; acc[1].w += a.y * b.w;
            acc[2].x += a.z * b.x; acc[2].y += a.z * b.y; acc[2].z += a.z * b.z; acc[2].w += a.z * b.w;
            acc[3].x += a.w * b.x; acc[3].y += a.w * b.y; acc[3].z += a.w * b.z; acc[3].w += a.w * b.w;
        }
        __syncthreads();
    }

    int gc = colb + c4;

    if (att_s) {
        // bf16 xh store + fused attention dots
        #pragma unroll
        for (int i = 0; i < 4; ++i) {
            int row = row0 + r4 + i;
            if (row >= M) continue;
            ushort4 pk;
            pk.x = __bfloat16_as_ushort(__float2bfloat16(acc[i].x));
            pk.y = __bfloat16_as_ushort(__float2bfloat16(acc[i].y));
            pk.z = __bfloat16_as_ushort(__float2bfloat16(acc[i].z));
            pk.w = __bfloat16_as_ushort(__float2bfloat16(acc[i].w));
            *(ushort4*)(Cbf + (size_t)row * 256 + gc) = pk;
        }
        float4 sa = *(const float4*)(att_s + gc);
        float4 da = *(const float4*)(att_d + gc);
        #pragma unroll
        for (int i = 0; i < 4; ++i) {
            float ps = acc[i].x * sa.x + acc[i].y * sa.y + acc[i].z * sa.z + acc[i].w * sa.w;
            float pd = acc[i].x * da.x + acc[i].y * da.y + acc[i].z * da.z + acc[i].w * da.w;
            #pragma unroll
            for (int o = 1; o < 16; o <<= 1) {
                ps += __shfl_xor(ps, o);
                pd += __shfl_xor(pd, o);
            }
            int row = row0 + r4 + i;
            if ((lane & 15) == 0 && row < M) {
                as_out[row * 4 + blockIdx.y] = ps;
                ad_out[row * 4 + blockIdx.y] = pd;
            }
        }
        return;
    }

    // f32 epilogue
    float4 bs = make_float4(0.f,0.f,0.f,0.f);
    if (bias) bs = *(const float4*)(bias + gc);
    float4 sg = make_float4(1.f,1.f,1.f,1.f), sb = make_float4(0.f,0.f,0.f,0.f);
    if (mode == 1) {
        float4 g = *(const float4*)(bn_g + gc);
        float4 b = *(const float4*)(bn_b + gc);
        float4 m = *(const float4*)(bn_m + gc);
        float4 v = *(const float4*)(bn_v + gc);
        sg.x = g.x / sqrtf(v.x + BNEPS); sb.x = b.x - m.x * sg.x;
        sg.y = g.y / sqrtf(v.y + BNEPS); sb.y = b.y - m.y * sg.y;
        sg.z = g.z / sqrtf(v.z + BNEPS); sb.z = b.z - m.z * sg.z;
        sg.w = g.w / sqrtf(v.w + BNEPS); sb.w = b.w - m.w * sg.w;
    }
    #pragma unroll
    for (int i = 0; i < 4; ++i) {
        int row = row0 + r4 + i;
        if (row >= M) continue;
        float4 o = acc[i];
        o.x += bs.x; o.y += bs.y; o.z += bs.z; o.w += bs.w;
        if (mode == 1) {
            o.x = o.x * sg.x + sb.x; o.y = o.y * sg.y + sb.y;
            o.z = o.z * sg.z + sb.z; o.w = o.w * sg.w + sb.w;
            o.x = o.x > 0.f ? o.x : __expf(o.x) - 1.f;
            o.y = o.y > 0.f ? o.y : __expf(o.y) - 1.f;
            o.z = o.z > 0.f ? o.z : __expf(o.z) - 1.f;
            o.w = o.w > 0.f ? o.w : __expf(o.w) - 1.f;
        }
        *(float4*)(C + (size_t)row * ldc + gc) = o;
    }
}

// ---------- CSR build: histogram over dst ----------
__global__ __launch_bounds__(256)
void hist_kernel(const int* __restrict__ ei, int E, int N, int* __restrict__ counts)
{
    int e = blockIdx.x * blockDim.x + threadIdx.x;
    int Etot = E + N;
    if (e >= Etot) return;
    int d = (e < E) ? ei[E + e] : e - E;
    atomicAdd(&counts[d], 1);
}

// ---------- scan phase 1: per-block partial sums (2048 elems/block) ----------
__global__ __launch_bounds__(256)
void scan_phase1(const int* __restrict__ counts, int N, int* __restrict__ blocksum)
{
    __shared__ int wsum[4];
    int tid = threadIdx.x, lane = tid & 63, wave = tid >> 6;
    int base = blockIdx.x * SCAN_CHUNK;
    int s = 0;
    #pragma unroll
    for (int j = 0; j < SCAN_CHUNK / 256; ++j) {
        int idx = base + tid + j * 256;
        if (idx < N) s += counts[idx];
    }
    #pragma unroll
    for (int o = 32; o; o >>= 1) s += __shfl_xor(s, o);
    if (lane == 0) wsum[wave] = s;
    __syncthreads();
    if (tid == 0) blocksum[blockIdx.x] = wsum[0] + wsum[1] + wsum[2] + wsum[3];
}

// ---------- scan phase 2: exclusive scan of block sums (nb <= 64), 1 wave ----------
__global__ void scan_phase2(const int* __restrict__ blocksum, int nb,
                            int* __restrict__ blockoff, int* __restrict__ rowptr, int N)
{
    int lane = threadIdx.x;  // 64 threads
    int v = (lane < nb) ? blocksum[lane] : 0;
    int incl = v;
    #pragma unroll
    for (int o = 1; o < 64; o <<= 1) {
        int t = __shfl_up(incl, o);
        if (lane >= o) incl += t;
    }
    if (lane < nb) blockoff[lane + 1] = incl;
    if (lane == 0) blockoff[0] = 0;
    int total = __shfl(incl, nb - 1);
    if (lane == 0) rowptr[N] = total;
}

// ---------- scan phase 3: per-block exclusive scan + offset ----------
__global__ __launch_bounds__(256)
void scan_phase3(const int* __restrict__ counts, int N,
                 const int* __restrict__ blockoff,
                 int* __restrict__ rowptr, int* __restrict__ cursor)
{
    __shared__ int wsum[4];
    int tid = threadIdx.x, lane = tid & 63, wave = tid >> 6;
    int start = blockIdx.x * SCAN_CHUNK + tid * 8;
    int v[8];
    int s = 0;
    #pragma unroll
    for (int j = 0; j < 8; ++j) {
        v[j] = (start + j < N) ? counts[start + j] : 0;
        s += v[j];
    }
    int incl = s;
    #pragma unroll
    for (int o = 1; o < 64; o <<= 1) {
        int t = __shfl_up(incl, o);
        if (lane >= o) incl += t;
    }
    if (lane == 63) wsum[wave] = incl;
    __syncthreads();
    int woff = 0;
    #pragma unroll
    for (int w = 0; w < 4; ++w) if (w < wave) woff += wsum[w];
    int run = blockoff[blockIdx.x] + woff + incl - s;
    #pragma unroll
    for (int j = 0; j < 8; ++j) {
        int idx = start + j;
        if (idx < N) { rowptr[idx] = run; cursor[idx] = run; }
        run += v[j];
    }
}

// ---------- CSR build: scatter src ids into buckets ----------
__global__ __launch_bounds__(256)
void scatter_kernel(const int* __restrict__ ei, int E, int N,
                    int* __restrict__ cursor, int* __restrict__ csr_src)
{
    int e = blockIdx.x * blockDim.x + threadIdx.x;
    int Etot = E + N;
    if (e >= Etot) return;
    int s, d;
    if (e < E) { s = ei[e]; d = ei[E + e]; } else { s = d = e - E; }
    int pos = atomicAdd(&cursor[d], 1);
    csr_src[pos] = s;
}

// ---------- fused per-node GAT aggregation (no-max softmax, bf16 xh gather) ----------
__global__ __launch_bounds__(256)
void aggregate_kernel(const int* __restrict__ rowptr, const int* __restrict__ csr_src,
                      const float* __restrict__ as_n, const float* __restrict__ ad_n,
                      const unsigned short* __restrict__ xh,
                      const float* __restrict__ bias,
                      float* __restrict__ outp, int ldo,
                      int N, int mode,
                      const float* __restrict__ bn_g, const float* __restrict__ bn_b,
                      const float* __restrict__ bn_m, const float* __restrict__ bn_v,
                      const float* __restrict__ resid)
{
    int node = (blockIdx.x * blockDim.x + threadIdx.x) >> 6;
    int lane = threadIdx.x & 63;
    if (node >= N) return;
    int h = lane >> 4;
    int e0 = rowptr[node], e1 = rowptr[node + 1];

    float4 adv = ((const float4*)ad_n)[node];
    float adh = (h < 2) ? (h == 0 ? adv.x : adv.y) : (h == 2 ? adv.z : adv.w);

    float4 acc = make_float4(0.f, 0.f, 0.f, 0.f);
    float wsum = 0.f;
    int e = e0;
    for (; e + 1 < e1; e += 2) {
        int s0 = csr_src[e], s1 = csr_src[e + 1];
        float l0 = as_n[s0 * 4 + h] + adh;
        float l1 = as_n[s1 * 4 + h] + adh;
        ushort4 xv0 = *(const ushort4*)(xh + (size_t)s0 * 256 + lane * 4);
        ushort4 xv1 = *(const ushort4*)(xh + (size_t)s1 * 256 + lane * 4);
        l0 = fmaxf(l0, NEG * l0);
        l1 = fmaxf(l1, NEG * l1);
        float w0 = __expf(l0);
        float w1 = __expf(l1);
        acc.x += w0 * bf2f(xv0.x); acc.y += w0 * bf2f(xv0.y);
        acc.z += w0 * bf2f(xv0.z); acc.w += w0 * bf2f(xv0.w);
        acc.x += w1 * bf2f(xv1.x); acc.y += w1 * bf2f(xv1.y);
        acc.z += w1 * bf2f(xv1.z); acc.w += w1 * bf2f(xv1.w);
        wsum += w0 + w1;
    }
    if (e < e1) {
        int s0 = csr_src[e];
        float l0 = as_n[s0 * 4 + h] + adh;
        l0 = fmaxf(l0, NEG * l0);
        float w0 = __expf(l0);
        ushort4 xv0 = *(const ushort4*)(xh + (size_t)s0 * 256 + lane * 4);
        acc.x += w0 * bf2f(xv0.x); acc.y += w0 * bf2f(xv0.y);
        acc.z += w0 * bf2f(xv0.z); acc.w += w0 * bf2f(xv0.w);
        wsum += w0;
    }
    float rw = 1.f / wsum;
    acc.x *= rw; acc.y *= rw; acc.z *= rw; acc.w *= rw;

    if (mode == 0) {
        float4 bs = *(const float4*)(bias + lane * 4);
        acc.x += bs.x; acc.y += bs.y; acc.z += bs.z; acc.w += bs.w;
        *(float4*)(outp + (size_t)node * 256 + lane * 4) = acc;
    } else {
        #pragma unroll
        for (int off = 16; off <= 32; off <<= 1) {
            acc.x += __shfl_xor(acc.x, off);
            acc.y += __shfl_xor(acc.y, off);
            acc.z += __shfl_xor(acc.z, off);
            acc.w += __shfl_xor(acc.w, off);
        }
        if (lane < 16) {
            int cin = lane * 4;
            float4 bs = *(const float4*)(bias + cin);
            float4 g = *(const float4*)(bn_g + cin);
            float4 b = *(const float4*)(bn_b + cin);
            float4 m = *(const float4*)(bn_m + cin);
            float4 vv = *(const float4*)(bn_v + cin);
            float4 rs = *(const float4*)(resid + (size_t)node * ldo + cin);
            float o[4] = {acc.x, acc.y, acc.z, acc.w};
            float bb[4] = {bs.x, bs.y, bs.z, bs.w};
            float gg[4] = {g.x, g.y, g.z, g.w};
            float be[4] = {b.x, b.y, b.z, b.w};
            float mm[4] = {m.x, m.y, m.z, m.w};
            float va[4] = {vv.x, vv.y, vv.z, vv.w};
            float rr[4] = {rs.x, rs.y, rs.z, rs.w};
            float4 res;
            float* rp = &res.x;
            #pragma unroll
            for (int j = 0; j < 4; ++j) {
                float v = 0.25f * o[j] + bb[j];
                float sg = gg[j] / sqrtf(va[j] + BNEPS);
                v = (v - mm[j]) * sg + be[j];
                v = v > 0.f ? v : __expf(v) - 1.f;
                rp[j] = v + rr[j];
            }
            *(float4*)(outp + (size_t)node * ldo + cin) = res;
        }
    }
}

// ---------- per-node pooling weights: one wave per node, writes w = exp(logit) ----------
__global__ __launch_bounds__(256)
void att_logit_kernel(const float* __restrict__ hjk, const float* __restrict__ attW,
                      const float* __restrict__ attb, float* __restrict__ wout, int N)
{
    int wid  = (blockIdx.x * blockDim.x + threadIdx.x) >> 6;
    int lane = threadIdx.x & 63;
    if (wid >= N) return;
    float v = hjk[(size_t)wid * 64 + lane] * attW[lane];
    #pragma unroll
    for (int off = 32; off; off >>= 1) v += __shfl_xor(v, off);
    if (lane == 0) wout[wid] = __expf(v + attb[0]);   // no-max softmax (|logit| ~ O(1))
}

// ---------- graph boundaries (batch is sorted) ----------
__global__ void gstart_kernel(const int* __restrict__ batch, int N, int* __restrict__ gstart)
{
    int t = threadIdx.x;
    if (t > NGRAPH) return;
    int lo = 0, hi = N;
    while (lo < hi) {
        int mid = (lo + hi) >> 1;
        if (batch[mid] < t) lo = mid + 1; else hi = mid;
    }
    gstart[t] = lo;
}

// ---------- pooling partial sums: node-parallel, LDS-staged, atomic flush ----------
// grid POOL_BLOCKS x 256; each block owns a contiguous node slab and walks the
// graph segments intersecting it (batch sorted). hg_acc[G*64], wsum_acc[G] must be 0.
__global__ __launch_bounds__(256)
void pool_partial(const float* __restrict__ hjk, const float* __restrict__ w,
                  const int* __restrict__ batch, const int* __restrict__ gstart,
                  float* __restrict__ hg_acc, float* __restrict__ wsum_acc, int N)
{
    __shared__ float red[256];
    __shared__ float wred[4];
    int tid = threadIdx.x;
    int c = tid & 63, q = tid >> 6;
    int slab = (N + POOL_BLOCKS - 1) / POOL_BLOCKS;
    int n0 = blockIdx.x * slab;
    int n1 = n0 + slab; if (n1 > N) n1 = N;
    if (n0 >= n1) return;
    int g0 = batch[n0], g1 = batch[n1 - 1];

    for (int g = g0; g <= g1; ++g) {
        int s = gstart[g];     if (s < n0) s = n0;
        int e = gstart[g + 1]; if (e > n1) e = n1;
        float acc = 0.f, ws = 0.f;
        for (int n = s + q; n < e; n += 4) {
            float wn = w[n];
            acc += wn * hjk[(size_t)n * 64 + c];
            if (c == 0) ws += wn;
        }
        red[tid] = acc;
        if (c == 0) wred[q] = ws;
        __syncthreads();
        if (q == 0) {
            float v = red[c] + red[64 + c] + red[128 + c] + red[192 + c];
            if (v != 0.f) atomicAdd(&hg_acc[g * 64 + c], v);
            if (c == 0) {
                float t = wred[0] + wred[1] + wred[2] + wred[3];
                if (t != 0.f) atomicAdd(&wsum_acc[g], t);
            }
        }
        __syncthreads();
    }
}

// ---------- classifier head: one block (32 threads) per graph ----------
__global__ void cls_kernel(const float* __restrict__ hg_acc,
                           const float* __restrict__ wsum_acc,
                           const float* __restrict__ W1, const float* __restrict__ b1,
                           const float* __restrict__ W2, const float* __restrict__ b2,
                           float* __restrict__ out)
{
    int g = blockIdx.x, t = threadIdx.x;  // 32 threads
    __shared__ float z[32];
    __shared__ float h[64];
    float wsum = wsum_acc[g];
    float rw = (wsum > 0.f) ? 1.f / wsum : 0.f;
    h[t] = hg_acc[g * 64 + t] * rw;
    h[t + 32] = hg_acc[g * 64 + t + 32] * rw;
    __syncthreads();
    float acc = b1[t];
    for (int k = 0; k < 64; ++k) acc += h[k] * W1[k * 32 + t];
    z[t] = fmaxf(acc, 0.f);
    __syncthreads();
    if (t < 2) {
        float o = b2[t];
        for (int j = 0; j < 32; ++j) o += z[j] * W2[j * 2 + t];
        out[g * 2 + t] = o;
    }
}

extern "C" void kernel_launch(void* const* d_in, const int* in_sizes, int n_in,
                              void* d_out, int out_size, void* d_ws, size_t ws_size,
                              hipStream_t stream)
{
    const float* x        = (const float*)d_in[0];
    const int*   ei       = (const int*)d_in[1];
    const int*   batch    = (const int*)d_in[2];
    const float* conv0_W  = (const float*)d_in[3];
    const float* conv0_as = (const float*)d_in[4];
    const float* conv0_ad = (const float*)d_in[5];
    const float* conv0_b  = (const float*)d_in[6];
    const float* pre0_W   = (const float*)d_in[7];
    const float* pre0_b   = (const float*)d_in[8];
    const float* convs_W  = (const float*)d_in[9];
    const float* convs_as = (const float*)d_in[10];
    const float* convs_ad = (const float*)d_in[11];
    const float* convs_b  = (const float*)d_in[12];
    const float* bn_g     = (const float*)d_in[13];
    const float* bn_b     = (const float*)d_in[14];
    const float* bn_m     = (const float*)d_in[15];
    const float* bn_v     = (const float*)d_in[16];
    const float* jump_W   = (const float*)d_in[17];
    const float* jump_b   = (const float*)d_in[18];
    const float* att_W    = (const float*)d_in[19];
    const float* att_b    = (const float*)d_in[20];
    const float* cls_W1   = (const float*)d_in[21];
    const float* cls_b1   = (const float*)d_in[22];
    const float* cls_W2   = (const float*)d_in[23];
    const float* cls_b2   = (const float*)d_in[24];
    float* out = (float*)d_out;

    const int N = in_sizes[0] / 128;   // 50000
    const int E = in_sizes[1] / 2;     // 400000
    const int Etot = E + N;
    const int nb = (N + SCAN_CHUNK - 1) / SCAN_CHUNK;   // scan blocks (25), must be <= 64

    // workspace layout
    float* ws      = (float*)d_ws;
    unsigned short* xh_bf = (unsigned short*)ws;         // N*256 bf16
    float* h256    = (float*)(xh_bf + (size_t)N * 256);  // N*256 f32
    float* repsAll = h256 + (size_t)N * 256;             // N*192
    float* as_n    = repsAll + (size_t)N * 192;          // N*4
    float* ad_n    = as_n + (size_t)N * 4;               // N*4
    float* hg_acc  = ad_n + (size_t)N * 4;               // 64*64
    float* wsum_acc= hg_acc + NGRAPH * 64;               // 64
    int*   rowptr  = (int*)(wsum_acc + NGRAPH);          // N+1
    int*   cursor  = rowptr + (N + 1);                   // N
    int*   counts  = cursor + N;                         // N
    int*   csr_src = counts + N;                         // Etot
    int*   gstart  = csr_src + Etot;                     // 65
    int*   blocksum = gstart + (NGRAPH + 1);             // 64
    int*   blockoff = blocksum + 64;                     // 65
    float* hjk     = h256;  // reuse (h256 free after pre0 GEMM)
    float* wbuf    = as_n;  // reuse (free after last layer)

    dim3 blk(256);
    int node_wave_blocks = (N + 3) / 4;          // 1 wave/node
    int edge_blocks      = (Etot + 255) / 256;

    // ---------------- CSR build ----------------
    hipMemsetAsync(counts, 0, (size_t)N * sizeof(int), stream);
    hist_kernel<<<edge_blocks, blk, 0, stream>>>(ei, E, N, counts);
    scan_phase1<<<nb, blk, 0, stream>>>(counts, N, blocksum);
    scan_phase2<<<1, 64, 0, stream>>>(blocksum, nb, blockoff, rowptr, N);
    scan_phase3<<<nb, blk, 0, stream>>>(counts, N, blockoff, rowptr, cursor);
    scatter_kernel<<<edge_blocks, blk, 0, stream>>>(ei, E, N, cursor, csr_src);

    // ---------------- layer 0 ----------------
    {
        dim3 g1((N + 63) / 64, 4);
        gemm_f32<<<g1, blk, 0, stream>>>(x, 128, conv0_W, 256, nullptr, nullptr, 256,
                                         N, 128, 0, nullptr, nullptr, nullptr, nullptr,
                                         conv0_as, conv0_ad, as_n, ad_n, xh_bf);
        aggregate_kernel<<<node_wave_blocks, blk, 0, stream>>>(
            rowptr, csr_src, as_n, ad_n, xh_bf, conv0_b, h256, 256, N, 0,
            nullptr, nullptr, nullptr, nullptr, nullptr);
        dim3 g2((N + 63) / 64, 1);
        gemm_f32<<<g2, blk, 0, stream>>>(h256, 256, pre0_W, 64, pre0_b, repsAll, 192,
                                         N, 256, 1, bn_g, bn_b, bn_m, bn_v,
                                         nullptr, nullptr, nullptr, nullptr, nullptr);
    }

    // ---------------- layers 1, 2 ----------------
    for (int i = 0; i < 2; ++i) {
        dim3 g1((N + 63) / 64, 4);
        gemm_f32<<<g1, blk, 0, stream>>>(repsAll + i * 64, 192,
                                         convs_W + (size_t)i * 64 * 256, 256, nullptr,
                                         nullptr, 256, N, 64, 0,
                                         nullptr, nullptr, nullptr, nullptr,
                                         convs_as + i * 256, convs_ad + i * 256,
                                         as_n, ad_n, xh_bf);
        aggregate_kernel<<<node_wave_blocks, blk, 0, stream>>>(
            rowptr, csr_src, as_n, ad_n, xh_bf, convs_b + i * 64,
            repsAll + (i + 1) * 64, 192, N, 1,
            bn_g + (i + 1) * 64, bn_b + (i + 1) * 64,
            bn_m + (i + 1) * 64, bn_v + (i + 1) * 64,
            repsAll + i * 64);
    }

    // ---------------- JK projection ----------------
    {
        dim3 g2((N + 63) / 64, 1);
        gemm_f32<<<g2, blk, 0, stream>>>(repsAll, 192, jump_W, 64, jump_b, hjk, 64,
                                         N, 192, 0, nullptr, nullptr, nullptr, nullptr,
                                         nullptr, nullptr, nullptr, nullptr, nullptr);
    }

    // ---------------- pooling + classifier ----------------
    att_logit_kernel<<<node_wave_blocks, blk, 0, stream>>>(hjk, att_W, att_b, wbuf, N);
    gstart_kernel<<<1, 128, 0, stream>>>(batch, N, gstart);
    hipMemsetAsync(hg_acc, 0, (NGRAPH * 64 + NGRAPH) * sizeof(float), stream);
    pool_partial<<<POOL_BLOCKS, blk, 0, stream>>>(hjk, wbuf, batch, gstart,
                                                  hg_acc, wsum_acc, N);
    cls_kernel<<<NGRAPH, 32, 0, stream>>>(hg_acc, wsum_acc, cls_W1, cls_b1,
                                          cls_W2, cls_b2, out);
}

// Round 8
// 472.679 us; speedup vs baseline: 4.5815x; 1.1184x over previous
//
#include <hip/hip_runtime.h>
#include <hip/hip_bf16.h>
#include <math.h>

#define NEG 0.2f
#define BNEPS 1e-5f
#define NGRAPH 64
#define SCAN_CHUNK 2048
#define POOL_BLOCKS 256

typedef short bf16x8 __attribute__((ext_vector_type(8)));   // 8 bf16 (4 VGPRs)
typedef float f32x4  __attribute__((ext_vector_type(4)));   // MFMA accumulator

__device__ __forceinline__ float bf2f(unsigned short u) {
    return __uint_as_float(((unsigned)u) << 16);
}
__device__ __forceinline__ short f2bf(float f) {
    return (short)__bfloat16_as_ushort(__float2bfloat16(f));
}

// ---------- MFMA bf16 GEMM for xh: Cbf[M,256] = bf16(A[M,K] @ W[K,256]) ----------
// + fused attention dots: as_out[row*4+head], ad_out[row*4+head] (head = blockIdx.y).
// grid (ceil(M/64), 4), block 256 (4 waves). Wave w computes rows [row0+16w, +16).
// A-fragments loaded straight from global in MFMA layout (m=lane&15, k=quad*8+j).
// W^T staged once in LDS as bf16, stride KP=K+8 shorts (16B-aligned b128 reads).
__global__ __launch_bounds__(256)
void gemm_xh_mfma(const float* __restrict__ A, int lda,
                  const float* __restrict__ W, int Nc, int M, int K,
                  const float* __restrict__ att_s, const float* __restrict__ att_d,
                  float* __restrict__ as_out, float* __restrict__ ad_out,
                  unsigned short* __restrict__ Cbf)
{
    __shared__ short Wt[64 * 136];           // max K=128 -> KP=136
    const int KP = K + 8;
    int tid  = threadIdx.x;
    int lane = tid & 63, wave = tid >> 6;
    int row0 = blockIdx.x * 64;
    int colb = blockIdx.y * 64;
    int c15 = lane & 15, q = lane >> 4;

    // stage W^T (bf16): thread t covers col n=t&63, k = (t>>6) + 4*j
    {
        int n = tid & 63;
        for (int k = tid >> 6; k < K; k += 4)
            Wt[n * KP + k] = f2bf(W[(size_t)k * Nc + colb + n]);
    }
    __syncthreads();

    int row = row0 + wave * 16 + c15;
    bool rok = row < M;
    const float* arow = A + (size_t)row * lda + q * 8;

    f32x4 acc[4];
    #pragma unroll
    for (int st = 0; st < 4; ++st) acc[st] = (f32x4){0.f, 0.f, 0.f, 0.f};

    for (int k0 = 0; k0 < K; k0 += 32) {
        bf16x8 av;
        if (rok) {
            float4 a0 = *(const float4*)(arow + k0);
            float4 a1 = *(const float4*)(arow + k0 + 4);
            av[0] = f2bf(a0.x); av[1] = f2bf(a0.y); av[2] = f2bf(a0.z); av[3] = f2bf(a0.w);
            av[4] = f2bf(a1.x); av[5] = f2bf(a1.y); av[6] = f2bf(a1.z); av[7] = f2bf(a1.w);
        } else {
            av = (bf16x8){0,0,0,0,0,0,0,0};
        }
        #pragma unroll
        for (int st = 0; st < 4; ++st) {
            bf16x8 bv = *(const bf16x8*)(Wt + (st * 16 + c15) * KP + k0 + q * 8);
            acc[st] = __builtin_amdgcn_mfma_f32_16x16x32_bf16(av, bv, acc[st], 0, 0, 0);
        }
    }

    // C/D layout: col = colb + st*16 + c15, row = row0 + wave*16 + q*4 + r
    // bf16 xh store
    #pragma unroll
    for (int r = 0; r < 4; ++r) {
        int orow = row0 + wave * 16 + q * 4 + r;
        if (orow >= M) continue;
        unsigned short* cb = Cbf + (size_t)orow * 256 + colb + c15;
        #pragma unroll
        for (int st = 0; st < 4; ++st)
            cb[st * 16] = (unsigned short)f2bf(acc[st][r]);
    }
    // fused attention dots: reduce over the 64 head channels
    float sa[4], da[4];
    #pragma unroll
    for (int st = 0; st < 4; ++st) {
        sa[st] = att_s[colb + st * 16 + c15];
        da[st] = att_d[colb + st * 16 + c15];
    }
    #pragma unroll
    for (int r = 0; r < 4; ++r) {
        float ps = acc[0][r] * sa[0] + acc[1][r] * sa[1] + acc[2][r] * sa[2] + acc[3][r] * sa[3];
        float pd = acc[0][r] * da[0] + acc[1][r] * da[1] + acc[2][r] * da[2] + acc[3][r] * da[3];
        #pragma unroll
        for (int o = 1; o < 16; o <<= 1) {
            ps += __shfl_xor(ps, o);
            pd += __shfl_xor(pd, o);
        }
        int orow = row0 + wave * 16 + q * 4 + r;
        if (c15 == 0 && orow < M) {
            as_out[orow * 4 + blockIdx.y] = ps;
            ad_out[orow * 4 + blockIdx.y] = pd;
        }
    }
}

// ---------- f32 GEMM (pre0 / jump): C[M,Nc] = A[M,K]@W[K,Nc] (+bias) (+BN+ELU) ----------
// 64x64 tile per 256-thread block, 16 outputs/thread. grid (ceil(M/64), Nc/64).
__global__ __launch_bounds__(256)
void gemm_f32(const float* __restrict__ A, int lda,
              const float* __restrict__ W, int Nc,
              const float* __restrict__ bias,
              float* __restrict__ C, int ldc,
              int M, int K, int mode,
              const float* __restrict__ bn_g, const float* __restrict__ bn_b,
              const float* __restrict__ bn_m, const float* __restrict__ bn_v)
{
    __shared__ __align__(16) float As[32][68];  // As[k][row]
    __shared__ __align__(16) float Ws[32][68];  // Ws[k][col]
    int tid  = threadIdx.x;
    int lane = tid & 63, wave = tid >> 6;
    int row0 = blockIdx.x * 64;
    int colb = blockIdx.y * 64;
    int r4 = wave * 16 + (lane >> 4) * 4;
    int c4 = (lane & 15) * 4;

    float4 acc[4];
    #pragma unroll
    for (int i = 0; i < 4; ++i) acc[i] = make_float4(0.f, 0.f, 0.f, 0.f);

    int ar = tid & 63, akq = (tid >> 6) * 8;
    int wk = tid >> 3, wcq = (tid & 7) * 8;

    for (int k0 = 0; k0 < K; k0 += 32) {
        int gr = row0 + ar;
        float4 av0, av1;
        if (gr < M) {
            const float* ap = A + (size_t)gr * lda + k0 + akq;
            av0 = *(const float4*)ap;
            av1 = *(const float4*)(ap + 4);
        } else {
            av0 = make_float4(0.f,0.f,0.f,0.f);
            av1 = av0;
        }
        As[akq + 0][ar] = av0.x; As[akq + 1][ar] = av0.y;
        As[akq + 2][ar] = av0.z; As[akq + 3][ar] = av0.w;
        As[akq + 4][ar] = av1.x; As[akq + 5][ar] = av1.y;
        As[akq + 6][ar] = av1.z; As[akq + 7][ar] = av1.w;
        const float* wp = W + (size_t)(k0 + wk) * Nc + colb + wcq;
        *(float4*)&Ws[wk][wcq]     = *(const float4*)wp;
        *(float4*)&Ws[wk][wcq + 4] = *(const float4*)(wp + 4);
        __syncthreads();

        #pragma unroll
        for (int kk = 0; kk < 32; ++kk) {
            float4 a = *(const float4*)&As[kk][r4];
            float4 b = *(const float4*)&Ws[kk][c4];
            acc[0].x += a.x * b.x; acc[0].y += a.x * b.y; acc[0].z += a.x * b.z; acc[0].w += a.x * b.w;
            acc[1].x += a.y * b.x; acc[1].y += a.y * b.y; acc[1].z += a.y * b.z; acc[1].w += a.y * b.w;
            acc[2].x += a.z * b.x; acc[2].y += a.z * b.y; acc[2].z += a.z * b.z; acc[2].w += a.z * b.w;
            acc[3].x += a.w * b.x; acc[3].y += a.w * b.y; acc[3].z += a.w * b.z; acc[3].w += a.w * b.w;
        }
        __syncthreads();
    }

    int gc = colb + c4;
    float4 bs = make_float4(0.f,0.f,0.f,0.f);
    if (bias) bs = *(const float4*)(bias + gc);
    float4 sg = make_float4(1.f,1.f,1.f,1.f), sb = make_float4(0.f,0.f,0.f,0.f);
    if (mode == 1) {
        float4 g = *(const float4*)(bn_g + gc);
        float4 b = *(const float4*)(bn_b + gc);
        float4 m = *(const float4*)(bn_m + gc);
        float4 v = *(const float4*)(bn_v + gc);
        sg.x = g.x / sqrtf(v.x + BNEPS); sb.x = b.x - m.x * sg.x;
        sg.y = g.y / sqrtf(v.y + BNEPS); sb.y = b.y - m.y * sg.y;
        sg.z = g.z / sqrtf(v.z + BNEPS); sb.z = b.z - m.z * sg.z;
        sg.w = g.w / sqrtf(v.w + BNEPS); sb.w = b.w - m.w * sg.w;
    }
    #pragma unroll
    for (int i = 0; i < 4; ++i) {
        int row = row0 + r4 + i;
        if (row >= M) continue;
        float4 o = acc[i];
        o.x += bs.x; o.y += bs.y; o.z += bs.z; o.w += bs.w;
        if (mode == 1) {
            o.x = o.x * sg.x + sb.x; o.y = o.y * sg.y + sb.y;
            o.z = o.z * sg.z + sb.z; o.w = o.w * sg.w + sb.w;
            o.x = o.x > 0.f ? o.x : __expf(o.x) - 1.f;
            o.y = o.y > 0.f ? o.y : __expf(o.y) - 1.f;
            o.z = o.z > 0.f ? o.z : __expf(o.z) - 1.f;
            o.w = o.w > 0.f ? o.w : __expf(o.w) - 1.f;
        }
        *(float4*)(C + (size_t)row * ldc + gc) = o;
    }
}

// ---------- CSR build: histogram over dst ----------
__global__ __launch_bounds__(256)
void hist_kernel(const int* __restrict__ ei, int E, int N, int* __restrict__ counts)
{
    int e = blockIdx.x * blockDim.x + threadIdx.x;
    int Etot = E + N;
    if (e >= Etot) return;
    int d = (e < E) ? ei[E + e] : e - E;
    atomicAdd(&counts[d], 1);
}

// ---------- scan phase 1 ----------
__global__ __launch_bounds__(256)
void scan_phase1(const int* __restrict__ counts, int N, int* __restrict__ blocksum)
{
    __shared__ int wsum[4];
    int tid = threadIdx.x, lane = tid & 63, wave = tid >> 6;
    int base = blockIdx.x * SCAN_CHUNK;
    int s = 0;
    #pragma unroll
    for (int j = 0; j < SCAN_CHUNK / 256; ++j) {
        int idx = base + tid + j * 256;
        if (idx < N) s += counts[idx];
    }
    #pragma unroll
    for (int o = 32; o; o >>= 1) s += __shfl_xor(s, o);
    if (lane == 0) wsum[wave] = s;
    __syncthreads();
    if (tid == 0) blocksum[blockIdx.x] = wsum[0] + wsum[1] + wsum[2] + wsum[3];
}

// ---------- scan phase 2 ----------
__global__ void scan_phase2(const int* __restrict__ blocksum, int nb,
                            int* __restrict__ blockoff, int* __restrict__ rowptr, int N)
{
    int lane = threadIdx.x;  // 64 threads
    int v = (lane < nb) ? blocksum[lane] : 0;
    int incl = v;
    #pragma unroll
    for (int o = 1; o < 64; o <<= 1) {
        int t = __shfl_up(incl, o);
        if (lane >= o) incl += t;
    }
    if (lane < nb) blockoff[lane + 1] = incl;
    if (lane == 0) blockoff[0] = 0;
    int total = __shfl(incl, nb - 1);
    if (lane == 0) rowptr[N] = total;
}

// ---------- scan phase 3 ----------
__global__ __launch_bounds__(256)
void scan_phase3(const int* __restrict__ counts, int N,
                 const int* __restrict__ blockoff,
                 int* __restrict__ rowptr, int* __restrict__ cursor)
{
    __shared__ int wsum[4];
    int tid = threadIdx.x, lane = tid & 63, wave = tid >> 6;
    int start = blockIdx.x * SCAN_CHUNK + tid * 8;
    int v[8];
    int s = 0;
    #pragma unroll
    for (int j = 0; j < 8; ++j) {
        v[j] = (start + j < N) ? counts[start + j] : 0;
        s += v[j];
    }
    int incl = s;
    #pragma unroll
    for (int o = 1; o < 64; o <<= 1) {
        int t = __shfl_up(incl, o);
        if (lane >= o) incl += t;
    }
    if (lane == 63) wsum[wave] = incl;
    __syncthreads();
    int woff = 0;
    #pragma unroll
    for (int w = 0; w < 4; ++w) if (w < wave) woff += wsum[w];
    int run = blockoff[blockIdx.x] + woff + incl - s;
    #pragma unroll
    for (int j = 0; j < 8; ++j) {
        int idx = start + j;
        if (idx < N) { rowptr[idx] = run; cursor[idx] = run; }
        run += v[j];
    }
}

// ---------- CSR build: scatter ----------
__global__ __launch_bounds__(256)
void scatter_kernel(const int* __restrict__ ei, int E, int N,
                    int* __restrict__ cursor, int* __restrict__ csr_src)
{
    int e = blockIdx.x * blockDim.x + threadIdx.x;
    int Etot = E + N;
    if (e >= Etot) return;
    int s, d;
    if (e < E) { s = ei[e]; d = ei[E + e]; } else { s = d = e - E; }
    int pos = atomicAdd(&cursor[d], 1);
    csr_src[pos] = s;
}

// ---------- fused per-node GAT aggregation (no-max softmax, bf16 xh gather) ----------
__global__ __launch_bounds__(256)
void aggregate_kernel(const int* __restrict__ rowptr, const int* __restrict__ csr_src,
                      const float* __restrict__ as_n, const float* __restrict__ ad_n,
                      const unsigned short* __restrict__ xh,
                      const float* __restrict__ bias,
                      float* __restrict__ outp, int ldo,
                      int N, int mode,
                      const float* __restrict__ bn_g, const float* __restrict__ bn_b,
                      const float* __restrict__ bn_m, const float* __restrict__ bn_v,
                      const float* __restrict__ resid)
{
    int node = (blockIdx.x * blockDim.x + threadIdx.x) >> 6;
    int lane = threadIdx.x & 63;
    if (node >= N) return;
    int h = lane >> 4;
    int e0 = rowptr[node], e1 = rowptr[node + 1];

    float4 adv = ((const float4*)ad_n)[node];
    float adh = (h < 2) ? (h == 0 ? adv.x : adv.y) : (h == 2 ? adv.z : adv.w);

    float4 acc = make_float4(0.f, 0.f, 0.f, 0.f);
    float wsum = 0.f;
    int e = e0;
    for (; e + 1 < e1; e += 2) {
        int s0 = csr_src[e], s1 = csr_src[e + 1];
        float l0 = as_n[s0 * 4 + h] + adh;
        float l1 = as_n[s1 * 4 + h] + adh;
        ushort4 xv0 = *(const ushort4*)(xh + (size_t)s0 * 256 + lane * 4);
        ushort4 xv1 = *(const ushort4*)(xh + (size_t)s1 * 256 + lane * 4);
        l0 = fmaxf(l0, NEG * l0);
        l1 = fmaxf(l1, NEG * l1);
        float w0 = __expf(l0);
        float w1 = __expf(l1);
        acc.x += w0 * bf2f(xv0.x); acc.y += w0 * bf2f(xv0.y);
        acc.z += w0 * bf2f(xv0.z); acc.w += w0 * bf2f(xv0.w);
        acc.x += w1 * bf2f(xv1.x); acc.y += w1 * bf2f(xv1.y);
        acc.z += w1 * bf2f(xv1.z); acc.w += w1 * bf2f(xv1.w);
        wsum += w0 + w1;
    }
    if (e < e1) {
        int s0 = csr_src[e];
        float l0 = as_n[s0 * 4 + h] + adh;
        l0 = fmaxf(l0, NEG * l0);
        float w0 = __expf(l0);
        ushort4 xv0 = *(const ushort4*)(xh + (size_t)s0 * 256 + lane * 4);
        acc.x += w0 * bf2f(xv0.x); acc.y += w0 * bf2f(xv0.y);
        acc.z += w0 * bf2f(xv0.z); acc.w += w0 * bf2f(xv0.w);
        wsum += w0;
    }
    float rw = 1.f / wsum;
    acc.x *= rw; acc.y *= rw; acc.z *= rw; acc.w *= rw;

    if (mode == 0) {
        float4 bs = *(const float4*)(bias + lane * 4);
        acc.x += bs.x; acc.y += bs.y; acc.z += bs.z; acc.w += bs.w;
        *(float4*)(outp + (size_t)node * 256 + lane * 4) = acc;
    } else {
        #pragma unroll
        for (int off = 16; off <= 32; off <<= 1) {
            acc.x += __shfl_xor(acc.x, off);
            acc.y += __shfl_xor(acc.y, off);
            acc.z += __shfl_xor(acc.z, off);
            acc.w += __shfl_xor(acc.w, off);
        }
        if (lane < 16) {
            int cin = lane * 4;
            float4 bs = *(const float4*)(bias + cin);
            float4 g = *(const float4*)(bn_g + cin);
            float4 b = *(const float4*)(bn_b + cin);
            float4 m = *(const float4*)(bn_m + cin);
            float4 vv = *(const float4*)(bn_v + cin);
            float4 rs = *(const float4*)(resid + (size_t)node * ldo + cin);
            float o[4] = {acc.x, acc.y, acc.z, acc.w};
            float bb[4] = {bs.x, bs.y, bs.z, bs.w};
            float gg[4] = {g.x, g.y, g.z, g.w};
            float be[4] = {b.x, b.y, b.z, b.w};
            float mm[4] = {m.x, m.y, m.z, m.w};
            float va[4] = {vv.x, vv.y, vv.z, vv.w};
            float rr[4] = {rs.x, rs.y, rs.z, rs.w};
            float4 res;
            float* rp = &res.x;
            #pragma unroll
            for (int j = 0; j < 4; ++j) {
                float v = 0.25f * o[j] + bb[j];
                float sg = gg[j] / sqrtf(va[j] + BNEPS);
                v = (v - mm[j]) * sg + be[j];
                v = v > 0.f ? v : __expf(v) - 1.f;
                rp[j] = v + rr[j];
            }
            *(float4*)(outp + (size_t)node * ldo + cin) = res;
        }
    }
}

// ---------- per-node pooling weights ----------
__global__ __launch_bounds__(256)
void att_logit_kernel(const float* __restrict__ hjk, const float* __restrict__ attW,
                      const float* __restrict__ attb, float* __restrict__ wout, int N)
{
    int wid  = (blockIdx.x * blockDim.x + threadIdx.x) >> 6;
    int lane = threadIdx.x & 63;
    if (wid >= N) return;
    float v = hjk[(size_t)wid * 64 + lane] * attW[lane];
    #pragma unroll
    for (int off = 32; off; off >>= 1) v += __shfl_xor(v, off);
    if (lane == 0) wout[wid] = __expf(v + attb[0]);
}

// ---------- graph boundaries ----------
__global__ void gstart_kernel(const int* __restrict__ batch, int N, int* __restrict__ gstart)
{
    int t = threadIdx.x;
    if (t > NGRAPH) return;
    int lo = 0, hi = N;
    while (lo < hi) {
        int mid = (lo + hi) >> 1;
        if (batch[mid] < t) lo = mid + 1; else hi = mid;
    }
    gstart[t] = lo;
}

// ---------- pooling partial sums ----------
__global__ __launch_bounds__(256)
void pool_partial(const float* __restrict__ hjk, const float* __restrict__ w,
                  const int* __restrict__ batch, const int* __restrict__ gstart,
                  float* __restrict__ hg_acc, float* __restrict__ wsum_acc, int N)
{
    __shared__ float red[256];
    __shared__ float wred[4];
    int tid = threadIdx.x;
    int c = tid & 63, q = tid >> 6;
    int slab = (N + POOL_BLOCKS - 1) / POOL_BLOCKS;
    int n0 = blockIdx.x * slab;
    int n1 = n0 + slab; if (n1 > N) n1 = N;
    if (n0 >= n1) return;
    int g0 = batch[n0], g1 = batch[n1 - 1];

    for (int g = g0; g <= g1; ++g) {
        int s = gstart[g];     if (s < n0) s = n0;
        int e = gstart[g + 1]; if (e > n1) e = n1;
        float acc = 0.f, ws = 0.f;
        for (int n = s + q; n < e; n += 4) {
            float wn = w[n];
            acc += wn * hjk[(size_t)n * 64 + c];
            if (c == 0) ws += wn;
        }
        red[tid] = acc;
        if (c == 0) wred[q] = ws;
        __syncthreads();
        if (q == 0) {
            float v = red[c] + red[64 + c] + red[128 + c] + red[192 + c];
            if (v != 0.f) atomicAdd(&hg_acc[g * 64 + c], v);
            if (c == 0) {
                float t = wred[0] + wred[1] + wred[2] + wred[3];
                if (t != 0.f) atomicAdd(&wsum_acc[g], t);
            }
        }
        __syncthreads();
    }
}

// ---------- classifier head ----------
__global__ void cls_kernel(const float* __restrict__ hg_acc,
                           const float* __restrict__ wsum_acc,
                           const float* __restrict__ W1, const float* __restrict__ b1,
                           const float* __restrict__ W2, const float* __restrict__ b2,
                           float* __restrict__ out)
{
    int g = blockIdx.x, t = threadIdx.x;  // 32 threads
    __shared__ float z[32];
    __shared__ float h[64];
    float wsum = wsum_acc[g];
    float rw = (wsum > 0.f) ? 1.f / wsum : 0.f;
    h[t] = hg_acc[g * 64 + t] * rw;
    h[t + 32] = hg_acc[g * 64 + t + 32] * rw;
    __syncthreads();
    float acc = b1[t];
    for (int k = 0; k < 64; ++k) acc += h[k] * W1[k * 32 + t];
    z[t] = fmaxf(acc, 0.f);
    __syncthreads();
    if (t < 2) {
        float o = b2[t];
        for (int j = 0; j < 32; ++j) o += z[j] * W2[j * 2 + t];
        out[g * 2 + t] = o;
    }
}

extern "C" void kernel_launch(void* const* d_in, const int* in_sizes, int n_in,
                              void* d_out, int out_size, void* d_ws, size_t ws_size,
                              hipStream_t stream)
{
    const float* x        = (const float*)d_in[0];
    const int*   ei       = (const int*)d_in[1];
    const int*   batch    = (const int*)d_in[2];
    const float* conv0_W  = (const float*)d_in[3];
    const float* conv0_as = (const float*)d_in[4];
    const float* conv0_ad = (const float*)d_in[5];
    const float* conv0_b  = (const float*)d_in[6];
    const float* pre0_W   = (const float*)d_in[7];
    const float* pre0_b   = (const float*)d_in[8];
    const float* convs_W  = (const float*)d_in[9];
    const float* convs_as = (const float*)d_in[10];
    const float* convs_ad = (const float*)d_in[11];
    const float* convs_b  = (const float*)d_in[12];
    const float* bn_g     = (const float*)d_in[13];
    const float* bn_b     = (const float*)d_in[14];
    const float* bn_m     = (const float*)d_in[15];
    const float* bn_v     = (const float*)d_in[16];
    const float* jump_W   = (const float*)d_in[17];
    const float* jump_b   = (const float*)d_in[18];
    const float* att_W    = (const float*)d_in[19];
    const float* att_b    = (const float*)d_in[20];
    const float* cls_W1   = (const float*)d_in[21];
    const float* cls_b1   = (const float*)d_in[22];
    const float* cls_W2   = (const float*)d_in[23];
    const float* cls_b2   = (const float*)d_in[24];
    float* out = (float*)d_out;

    const int N = in_sizes[0] / 128;   // 50000
    const int E = in_sizes[1] / 2;     // 400000
    const int Etot = E + N;
    const int nb = (N + SCAN_CHUNK - 1) / SCAN_CHUNK;   // 25 <= 64

    // workspace layout
    float* ws      = (float*)d_ws;
    unsigned short* xh_bf = (unsigned short*)ws;         // N*256 bf16
    float* h256    = (float*)(xh_bf + (size_t)N * 256);  // N*256 f32
    float* repsAll = h256 + (size_t)N * 256;             // N*192
    float* as_n    = repsAll + (size_t)N * 192;          // N*4
    float* ad_n    = as_n + (size_t)N * 4;               // N*4
    float* hg_acc  = ad_n + (size_t)N * 4;               // 64*64
    float* wsum_acc= hg_acc + NGRAPH * 64;               // 64
    int*   rowptr  = (int*)(wsum_acc + NGRAPH);          // N+1
    int*   cursor  = rowptr + (N + 1);                   // N
    int*   counts  = cursor + N;                         // N
    int*   csr_src = counts + N;                         // Etot
    int*   gstart  = csr_src + Etot;                     // 65
    int*   blocksum = gstart + (NGRAPH + 1);             // 64
    int*   blockoff = blocksum + 64;                     // 65
    float* hjk     = h256;  // reuse
    float* wbuf    = as_n;  // reuse

    dim3 blk(256);
    int node_wave_blocks = (N + 3) / 4;
    int edge_blocks      = (Etot + 255) / 256;

    // ---------------- CSR build ----------------
    hipMemsetAsync(counts, 0, (size_t)N * sizeof(int), stream);
    hist_kernel<<<edge_blocks, blk, 0, stream>>>(ei, E, N, counts);
    scan_phase1<<<nb, blk, 0, stream>>>(counts, N, blocksum);
    scan_phase2<<<1, 64, 0, stream>>>(blocksum, nb, blockoff, rowptr, N);
    scan_phase3<<<nb, blk, 0, stream>>>(counts, N, blockoff, rowptr, cursor);
    scatter_kernel<<<edge_blocks, blk, 0, stream>>>(ei, E, N, cursor, csr_src);

    // ---------------- layer 0 ----------------
    {
        dim3 g1((N + 63) / 64, 4);
        gemm_xh_mfma<<<g1, blk, 0, stream>>>(x, 128, conv0_W, 256, N, 128,
                                             conv0_as, conv0_ad, as_n, ad_n, xh_bf);
        aggregate_kernel<<<node_wave_blocks, blk, 0, stream>>>(
            rowptr, csr_src, as_n, ad_n, xh_bf, conv0_b, h256, 256, N, 0,
            nullptr, nullptr, nullptr, nullptr, nullptr);
        dim3 g2((N + 63) / 64, 1);
        gemm_f32<<<g2, blk, 0, stream>>>(h256, 256, pre0_W, 64, pre0_b, repsAll, 192,
                                         N, 256, 1, bn_g, bn_b, bn_m, bn_v);
    }

    // ---------------- layers 1, 2 ----------------
    for (int i = 0; i < 2; ++i) {
        dim3 g1((N + 63) / 64, 4);
        gemm_xh_mfma<<<g1, blk, 0, stream>>>(repsAll + i * 64, 192,
                                             convs_W + (size_t)i * 64 * 256, 256, N, 64,
                                             convs_as + i * 256, convs_ad + i * 256,
                                             as_n, ad_n, xh_bf);
        aggregate_kernel<<<node_wave_blocks, blk, 0, stream>>>(
            rowptr, csr_src, as_n, ad_n, xh_bf, convs_b + i * 64,
            repsAll + (i + 1) * 64, 192, N, 1,
            bn_g + (i + 1) * 64, bn_b + (i + 1) * 64,
            bn_m + (i + 1) * 64, bn_v + (i + 1) * 64,
            repsAll + i * 64);
    }

    // ---------------- JK projection ----------------
    {
        dim3 g2((N + 63) / 64, 1);
        gemm_f32<<<g2, blk, 0, stream>>>(repsAll, 192, jump_W, 64, jump_b, hjk, 64,
                                         N, 192, 0, nullptr, nullptr, nullptr, nullptr);
    }

    // ---------------- pooling + classifier ----------------
    att_logit_kernel<<<node_wave_blocks, blk, 0, stream>>>(hjk, att_W, att_b, wbuf, N);
    gstart_kernel<<<1, 128, 0, stream>>>(batch, N, gstart);
    hipMemsetAsync(hg_acc, 0, (NGRAPH * 64 + NGRAPH) * sizeof(float), stream);
    pool_partial<<<POOL_BLOCKS, blk, 0, stream>>>(hjk, wbuf, batch, gstart,
                                                  hg_acc, wsum_acc, N);
    cls_kernel<<<NGRAPH, 32, 0, stream>>>(hg_acc, wsum_acc, cls_W1, cls_b1,
                                          cls_W2, cls_b2, out);
}

// Round 9
// 429.674 us; speedup vs baseline: 5.0401x; 1.1001x over previous
//
#include <hip/hip_runtime.h>
#include <hip/hip_bf16.h>
#include <math.h>

#define NEG 0.2f
#define BNEPS 1e-5f
#define NGRAPH 64
#define SCAN_CHUNK 2048
#define POOL_BLOCKS 256

typedef short bf16x8 __attribute__((ext_vector_type(8)));   // 8 bf16 (4 VGPRs)
typedef float f32x4  __attribute__((ext_vector_type(4)));   // MFMA accumulator

__device__ __forceinline__ float bf2f(unsigned short u) {
    return __uint_as_float(((unsigned)u) << 16);
}
__device__ __forceinline__ short f2bf(float f) {
    return (short)__bfloat16_as_ushort(__float2bfloat16(f));
}

// ---------- MFMA bf16 GEMM for xh: Cbf[M,256] = bf16(A[M,K] @ W[K,256]) ----------
// + fused attention dots. grid (ceil(M/64), 4), block 256. head = blockIdx.y.
__global__ __launch_bounds__(256)
void gemm_xh_mfma(const float* __restrict__ A, int lda,
                  const float* __restrict__ W, int Nc, int M, int K,
                  const float* __restrict__ att_s, const float* __restrict__ att_d,
                  float* __restrict__ as_out, float* __restrict__ ad_out,
                  unsigned short* __restrict__ Cbf)
{
    __shared__ short Wt[64 * 136];           // max K=128 -> KP=136
    const int KP = K + 8;
    int tid  = threadIdx.x;
    int lane = tid & 63, wave = tid >> 6;
    int row0 = blockIdx.x * 64;
    int colb = blockIdx.y * 64;
    int c15 = lane & 15, q = lane >> 4;

    {
        int n = tid & 63;
        for (int k = tid >> 6; k < K; k += 4)
            Wt[n * KP + k] = f2bf(W[(size_t)k * Nc + colb + n]);
    }
    __syncthreads();

    int row = row0 + wave * 16 + c15;
    bool rok = row < M;
    const float* arow = A + (size_t)row * lda + q * 8;

    f32x4 acc[4];
    #pragma unroll
    for (int st = 0; st < 4; ++st) acc[st] = (f32x4){0.f, 0.f, 0.f, 0.f};

    for (int k0 = 0; k0 < K; k0 += 32) {
        bf16x8 av;
        if (rok) {
            float4 a0 = *(const float4*)(arow + k0);
            float4 a1 = *(const float4*)(arow + k0 + 4);
            av[0] = f2bf(a0.x); av[1] = f2bf(a0.y); av[2] = f2bf(a0.z); av[3] = f2bf(a0.w);
            av[4] = f2bf(a1.x); av[5] = f2bf(a1.y); av[6] = f2bf(a1.z); av[7] = f2bf(a1.w);
        } else {
            av = (bf16x8){0,0,0,0,0,0,0,0};
        }
        #pragma unroll
        for (int st = 0; st < 4; ++st) {
            bf16x8 bv = *(const bf16x8*)(Wt + (st * 16 + c15) * KP + k0 + q * 8);
            acc[st] = __builtin_amdgcn_mfma_f32_16x16x32_bf16(av, bv, acc[st], 0, 0, 0);
        }
    }

    #pragma unroll
    for (int r = 0; r < 4; ++r) {
        int orow = row0 + wave * 16 + q * 4 + r;
        if (orow >= M) continue;
        unsigned short* cb = Cbf + (size_t)orow * 256 + colb + c15;
        #pragma unroll
        for (int st = 0; st < 4; ++st)
            cb[st * 16] = (unsigned short)f2bf(acc[st][r]);
    }
    float sa[4], da[4];
    #pragma unroll
    for (int st = 0; st < 4; ++st) {
        sa[st] = att_s[colb + st * 16 + c15];
        da[st] = att_d[colb + st * 16 + c15];
    }
    #pragma unroll
    for (int r = 0; r < 4; ++r) {
        float ps = acc[0][r] * sa[0] + acc[1][r] * sa[1] + acc[2][r] * sa[2] + acc[3][r] * sa[3];
        float pd = acc[0][r] * da[0] + acc[1][r] * da[1] + acc[2][r] * da[2] + acc[3][r] * da[3];
        #pragma unroll
        for (int o = 1; o < 16; o <<= 1) {
            ps += __shfl_xor(ps, o);
            pd += __shfl_xor(pd, o);
        }
        int orow = row0 + wave * 16 + q * 4 + r;
        if (c15 == 0 && orow < M) {
            as_out[orow * 4 + blockIdx.y] = ps;
            ad_out[orow * 4 + blockIdx.y] = pd;
        }
    }
}

// ---------- MFMA bf16 GEMM, Nc=64 (pre0 / jump): C[M,64] = A[M,K] @ W[K,64] ----------
// grid (ceil(M/64), 1), block 256. a_is_bf16: A rows are bf16 (lda in shorts).
// mode 1: +bias, BN, ELU; mode 0: +bias only. C is f32, leading dim ldc.
__global__ __launch_bounds__(256)
void gemm_n64_mfma(const void* __restrict__ Araw, int lda, int a_is_bf16,
                   const float* __restrict__ W, int M, int K,
                   const float* __restrict__ bias,
                   float* __restrict__ C, int ldc, int mode,
                   const float* __restrict__ bn_g, const float* __restrict__ bn_b,
                   const float* __restrict__ bn_m, const float* __restrict__ bn_v)
{
    __shared__ short Wt[64 * 264];           // max K=256 -> KP=264
    const int KP = K + 8;
    int tid  = threadIdx.x;
    int lane = tid & 63, wave = tid >> 6;
    int row0 = blockIdx.x * 64;
    int c15 = lane & 15, q = lane >> 4;

    {
        int n = tid & 63;
        for (int k = tid >> 6; k < K; k += 4)
            Wt[n * KP + k] = f2bf(W[(size_t)k * 64 + n]);
    }
    __syncthreads();

    int row = row0 + wave * 16 + c15;
    bool rok = row < M;

    f32x4 acc[4];
    #pragma unroll
    for (int st = 0; st < 4; ++st) acc[st] = (f32x4){0.f, 0.f, 0.f, 0.f};

    for (int k0 = 0; k0 < K; k0 += 32) {
        bf16x8 av;
        if (rok) {
            if (a_is_bf16) {
                av = *(const bf16x8*)((const unsigned short*)Araw
                                      + (size_t)row * lda + k0 + q * 8);
            } else {
                const float* ap = (const float*)Araw + (size_t)row * lda + k0 + q * 8;
                float4 a0 = *(const float4*)ap;
                float4 a1 = *(const float4*)(ap + 4);
                av[0] = f2bf(a0.x); av[1] = f2bf(a0.y); av[2] = f2bf(a0.z); av[3] = f2bf(a0.w);
                av[4] = f2bf(a1.x); av[5] = f2bf(a1.y); av[6] = f2bf(a1.z); av[7] = f2bf(a1.w);
            }
        } else {
            av = (bf16x8){0,0,0,0,0,0,0,0};
        }
        #pragma unroll
        for (int st = 0; st < 4; ++st) {
            bf16x8 bv = *(const bf16x8*)(Wt + (st * 16 + c15) * KP + k0 + q * 8);
            acc[st] = __builtin_amdgcn_mfma_f32_16x16x32_bf16(av, bv, acc[st], 0, 0, 0);
        }
    }

    // epilogue: col = st*16 + c15, row = row0 + wave*16 + q*4 + r
    #pragma unroll
    for (int st = 0; st < 4; ++st) {
        int col = st * 16 + c15;
        float bs = bias ? bias[col] : 0.f;
        float sg = 1.f, sb = 0.f;
        if (mode == 1) {
            sg = bn_g[col] / sqrtf(bn_v[col] + BNEPS);
            sb = bn_b[col] - bn_m[col] * sg;
        }
        #pragma unroll
        for (int r = 0; r < 4; ++r) {
            int orow = row0 + wave * 16 + q * 4 + r;
            if (orow >= M) continue;
            float v = acc[st][r] + bs;
            if (mode == 1) {
                v = v * sg + sb;
                v = v > 0.f ? v : __expf(v) - 1.f;
            }
            C[(size_t)orow * ldc + col] = v;
        }
    }
}

// ---------- CSR build: histogram over dst ----------
__global__ __launch_bounds__(256)
void hist_kernel(const int* __restrict__ ei, int E, int N, int* __restrict__ counts)
{
    int e = blockIdx.x * blockDim.x + threadIdx.x;
    int Etot = E + N;
    if (e >= Etot) return;
    int d = (e < E) ? ei[E + e] : e - E;
    atomicAdd(&counts[d], 1);
}

// ---------- scan phase 1 ----------
__global__ __launch_bounds__(256)
void scan_phase1(const int* __restrict__ counts, int N, int* __restrict__ blocksum)
{
    __shared__ int wsum[4];
    int tid = threadIdx.x, lane = tid & 63, wave = tid >> 6;
    int base = blockIdx.x * SCAN_CHUNK;
    int s = 0;
    #pragma unroll
    for (int j = 0; j < SCAN_CHUNK / 256; ++j) {
        int idx = base + tid + j * 256;
        if (idx < N) s += counts[idx];
    }
    #pragma unroll
    for (int o = 32; o; o >>= 1) s += __shfl_xor(s, o);
    if (lane == 0) wsum[wave] = s;
    __syncthreads();
    if (tid == 0) blocksum[blockIdx.x] = wsum[0] + wsum[1] + wsum[2] + wsum[3];
}

// ---------- scan phase 2 ----------
__global__ void scan_phase2(const int* __restrict__ blocksum, int nb,
                            int* __restrict__ blockoff, int* __restrict__ rowptr, int N)
{
    int lane = threadIdx.x;  // 64 threads
    int v = (lane < nb) ? blocksum[lane] : 0;
    int incl = v;
    #pragma unroll
    for (int o = 1; o < 64; o <<= 1) {
        int t = __shfl_up(incl, o);
        if (lane >= o) incl += t;
    }
    if (lane < nb) blockoff[lane + 1] = incl;
    if (lane == 0) blockoff[0] = 0;
    int total = __shfl(incl, nb - 1);
    if (lane == 0) rowptr[N] = total;
}

// ---------- scan phase 3 ----------
__global__ __launch_bounds__(256)
void scan_phase3(const int* __restrict__ counts, int N,
                 const int* __restrict__ blockoff,
                 int* __restrict__ rowptr, int* __restrict__ cursor)
{
    __shared__ int wsum[4];
    int tid = threadIdx.x, lane = tid & 63, wave = tid >> 6;
    int start = blockIdx.x * SCAN_CHUNK + tid * 8;
    int v[8];
    int s = 0;
    #pragma unroll
    for (int j = 0; j < 8; ++j) {
        v[j] = (start + j < N) ? counts[start + j] : 0;
        s += v[j];
    }
    int incl = s;
    #pragma unroll
    for (int o = 1; o < 64; o <<= 1) {
        int t = __shfl_up(incl, o);
        if (lane >= o) incl += t;
    }
    if (lane == 63) wsum[wave] = incl;
    __syncthreads();
    int woff = 0;
    #pragma unroll
    for (int w = 0; w < 4; ++w) if (w < wave) woff += wsum[w];
    int run = blockoff[blockIdx.x] + woff + incl - s;
    #pragma unroll
    for (int j = 0; j < 8; ++j) {
        int idx = start + j;
        if (idx < N) { rowptr[idx] = run; cursor[idx] = run; }
        run += v[j];
    }
}

// ---------- CSR build: scatter ----------
__global__ __launch_bounds__(256)
void scatter_kernel(const int* __restrict__ ei, int E, int N,
                    int* __restrict__ cursor, int* __restrict__ csr_src)
{
    int e = blockIdx.x * blockDim.x + threadIdx.x;
    int Etot = E + N;
    if (e >= Etot) return;
    int s, d;
    if (e < E) { s = ei[e]; d = ei[E + e]; } else { s = d = e - E; }
    int pos = atomicAdd(&cursor[d], 1);
    csr_src[pos] = s;
}

// ---------- fused per-node GAT aggregation (no-max softmax, bf16 gather, 4x ILP) ----------
// mode 0: concat -> bf16 out (ushort4 at node*256+lane*4)
// mode 1: head-mean -> +bias, BN, ELU, +resid -> f32 outp[node*ldo + cin]
__global__ __launch_bounds__(256)
void aggregate_kernel(const int* __restrict__ rowptr, const int* __restrict__ csr_src,
                      const float* __restrict__ as_n, const float* __restrict__ ad_n,
                      const unsigned short* __restrict__ xh,
                      const float* __restrict__ bias,
                      float* __restrict__ outp, int ldo,
                      int N, int mode,
                      const float* __restrict__ bn_g, const float* __restrict__ bn_b,
                      const float* __restrict__ bn_m, const float* __restrict__ bn_v,
                      const float* __restrict__ resid)
{
    int node = (blockIdx.x * blockDim.x + threadIdx.x) >> 6;
    int lane = threadIdx.x & 63;
    if (node >= N) return;
    int h = lane >> 4;
    int e0 = rowptr[node], e1 = rowptr[node + 1];

    float4 adv = ((const float4*)ad_n)[node];
    float adh = (h < 2) ? (h == 0 ? adv.x : adv.y) : (h == 2 ? adv.z : adv.w);

    float4 acc = make_float4(0.f, 0.f, 0.f, 0.f);
    float wsum = 0.f;
    int e = e0;
    for (; e + 3 < e1; e += 4) {
        // issue all index loads, then all gathers, then math (max MLP)
        int s0 = csr_src[e], s1 = csr_src[e + 1];
        int s2 = csr_src[e + 2], s3 = csr_src[e + 3];
        ushort4 xv0 = *(const ushort4*)(xh + (size_t)s0 * 256 + lane * 4);
        ushort4 xv1 = *(const ushort4*)(xh + (size_t)s1 * 256 + lane * 4);
        ushort4 xv2 = *(const ushort4*)(xh + (size_t)s2 * 256 + lane * 4);
        ushort4 xv3 = *(const ushort4*)(xh + (size_t)s3 * 256 + lane * 4);
        float a0 = as_n[s0 * 4 + h], a1 = as_n[s1 * 4 + h];
        float a2 = as_n[s2 * 4 + h], a3 = as_n[s3 * 4 + h];
        float l0 = a0 + adh, l1 = a1 + adh, l2 = a2 + adh, l3 = a3 + adh;
        l0 = fmaxf(l0, NEG * l0); l1 = fmaxf(l1, NEG * l1);
        l2 = fmaxf(l2, NEG * l2); l3 = fmaxf(l3, NEG * l3);
        float w0 = __expf(l0), w1 = __expf(l1), w2 = __expf(l2), w3 = __expf(l3);
        acc.x += w0 * bf2f(xv0.x); acc.y += w0 * bf2f(xv0.y);
        acc.z += w0 * bf2f(xv0.z); acc.w += w0 * bf2f(xv0.w);
        acc.x += w1 * bf2f(xv1.x); acc.y += w1 * bf2f(xv1.y);
        acc.z += w1 * bf2f(xv1.z); acc.w += w1 * bf2f(xv1.w);
        acc.x += w2 * bf2f(xv2.x); acc.y += w2 * bf2f(xv2.y);
        acc.z += w2 * bf2f(xv2.z); acc.w += w2 * bf2f(xv2.w);
        acc.x += w3 * bf2f(xv3.x); acc.y += w3 * bf2f(xv3.y);
        acc.z += w3 * bf2f(xv3.z); acc.w += w3 * bf2f(xv3.w);
        wsum += (w0 + w1) + (w2 + w3);
    }
    for (; e < e1; ++e) {
        int s0 = csr_src[e];
        float l0 = as_n[s0 * 4 + h] + adh;
        l0 = fmaxf(l0, NEG * l0);
        float w0 = __expf(l0);
        ushort4 xv0 = *(const ushort4*)(xh + (size_t)s0 * 256 + lane * 4);
        acc.x += w0 * bf2f(xv0.x); acc.y += w0 * bf2f(xv0.y);
        acc.z += w0 * bf2f(xv0.z); acc.w += w0 * bf2f(xv0.w);
        wsum += w0;
    }
    float rw = 1.f / wsum;
    acc.x *= rw; acc.y *= rw; acc.z *= rw; acc.w *= rw;

    if (mode == 0) {
        float4 bs = *(const float4*)(bias + lane * 4);
        ushort4 pk;
        pk.x = (unsigned short)f2bf(acc.x + bs.x);
        pk.y = (unsigned short)f2bf(acc.y + bs.y);
        pk.z = (unsigned short)f2bf(acc.z + bs.z);
        pk.w = (unsigned short)f2bf(acc.w + bs.w);
        *(ushort4*)((unsigned short*)outp + (size_t)node * 256 + lane * 4) = pk;
    } else {
        #pragma unroll
        for (int off = 16; off <= 32; off <<= 1) {
            acc.x += __shfl_xor(acc.x, off);
            acc.y += __shfl_xor(acc.y, off);
            acc.z += __shfl_xor(acc.z, off);
            acc.w += __shfl_xor(acc.w, off);
        }
        if (lane < 16) {
            int cin = lane * 4;
            float4 bs = *(const float4*)(bias + cin);
            float4 g = *(const float4*)(bn_g + cin);
            float4 b = *(const float4*)(bn_b + cin);
            float4 m = *(const float4*)(bn_m + cin);
            float4 vv = *(const float4*)(bn_v + cin);
            float4 rs = *(const float4*)(resid + (size_t)node * ldo + cin);
            float o[4] = {acc.x, acc.y, acc.z, acc.w};
            float bb[4] = {bs.x, bs.y, bs.z, bs.w};
            float gg[4] = {g.x, g.y, g.z, g.w};
            float be[4] = {b.x, b.y, b.z, b.w};
            float mm[4] = {m.x, m.y, m.z, m.w};
            float va[4] = {vv.x, vv.y, vv.z, vv.w};
            float rr[4] = {rs.x, rs.y, rs.z, rs.w};
            float4 res;
            float* rp = &res.x;
            #pragma unroll
            for (int j = 0; j < 4; ++j) {
                float v = 0.25f * o[j] + bb[j];
                float sg = gg[j] / sqrtf(va[j] + BNEPS);
                v = (v - mm[j]) * sg + be[j];
                v = v > 0.f ? v : __expf(v) - 1.f;
                rp[j] = v + rr[j];
            }
            *(float4*)(outp + (size_t)node * ldo + cin) = res;
        }
    }
}

// ---------- per-node pooling weights ----------
__global__ __launch_bounds__(256)
void att_logit_kernel(const float* __restrict__ hjk, const float* __restrict__ attW,
                      const float* __restrict__ attb, float* __restrict__ wout, int N)
{
    int wid  = (blockIdx.x * blockDim.x + threadIdx.x) >> 6;
    int lane = threadIdx.x & 63;
    if (wid >= N) return;
    float v = hjk[(size_t)wid * 64 + lane] * attW[lane];
    #pragma unroll
    for (int off = 32; off; off >>= 1) v += __shfl_xor(v, off);
    if (lane == 0) wout[wid] = __expf(v + attb[0]);
}

// ---------- graph boundaries ----------
__global__ void gstart_kernel(const int* __restrict__ batch, int N, int* __restrict__ gstart)
{
    int t = threadIdx.x;
    if (t > NGRAPH) return;
    int lo = 0, hi = N;
    while (lo < hi) {
        int mid = (lo + hi) >> 1;
        if (batch[mid] < t) lo = mid + 1; else hi = mid;
    }
    gstart[t] = lo;
}

// ---------- pooling partial sums ----------
__global__ __launch_bounds__(256)
void pool_partial(const float* __restrict__ hjk, const float* __restrict__ w,
                  const int* __restrict__ batch, const int* __restrict__ gstart,
                  float* __restrict__ hg_acc, float* __restrict__ wsum_acc, int N)
{
    __shared__ float red[256];
    __shared__ float wred[4];
    int tid = threadIdx.x;
    int c = tid & 63, q = tid >> 6;
    int slab = (N + POOL_BLOCKS - 1) / POOL_BLOCKS;
    int n0 = blockIdx.x * slab;
    int n1 = n0 + slab; if (n1 > N) n1 = N;
    if (n0 >= n1) return;
    int g0 = batch[n0], g1 = batch[n1 - 1];

    for (int g = g0; g <= g1; ++g) {
        int s = gstart[g];     if (s < n0) s = n0;
        int e = gstart[g + 1]; if (e > n1) e = n1;
        float acc = 0.f, ws = 0.f;
        for (int n = s + q; n < e; n += 4) {
            float wn = w[n];
            acc += wn * hjk[(size_t)n * 64 + c];
            if (c == 0) ws += wn;
        }
        red[tid] = acc;
        if (c == 0) wred[q] = ws;
        __syncthreads();
        if (q == 0) {
            float v = red[c] + red[64 + c] + red[128 + c] + red[192 + c];
            if (v != 0.f) atomicAdd(&hg_acc[g * 64 + c], v);
            if (c == 0) {
                float t = wred[0] + wred[1] + wred[2] + wred[3];
                if (t != 0.f) atomicAdd(&wsum_acc[g], t);
            }
        }
        __syncthreads();
    }
}

// ---------- classifier head ----------
__global__ void cls_kernel(const float* __restrict__ hg_acc,
                           const float* __restrict__ wsum_acc,
                           const float* __restrict__ W1, const float* __restrict__ b1,
                           const float* __restrict__ W2, const float* __restrict__ b2,
                           float* __restrict__ out)
{
    int g = blockIdx.x, t = threadIdx.x;  // 32 threads
    __shared__ float z[32];
    __shared__ float h[64];
    float wsum = wsum_acc[g];
    float rw = (wsum > 0.f) ? 1.f / wsum : 0.f;
    h[t] = hg_acc[g * 64 + t] * rw;
    h[t + 32] = hg_acc[g * 64 + t + 32] * rw;
    __syncthreads();
    float acc = b1[t];
    for (int k = 0; k < 64; ++k) acc += h[k] * W1[k * 32 + t];
    z[t] = fmaxf(acc, 0.f);
    __syncthreads();
    if (t < 2) {
        float o = b2[t];
        for (int j = 0; j < 32; ++j) o += z[j] * W2[j * 2 + t];
        out[g * 2 + t] = o;
    }
}

extern "C" void kernel_launch(void* const* d_in, const int* in_sizes, int n_in,
                              void* d_out, int out_size, void* d_ws, size_t ws_size,
                              hipStream_t stream)
{
    const float* x        = (const float*)d_in[0];
    const int*   ei       = (const int*)d_in[1];
    const int*   batch    = (const int*)d_in[2];
    const float* conv0_W  = (const float*)d_in[3];
    const float* conv0_as = (const float*)d_in[4];
    const float* conv0_ad = (const float*)d_in[5];
    const float* conv0_b  = (const float*)d_in[6];
    const float* pre0_W   = (const float*)d_in[7];
    const float* pre0_b   = (const float*)d_in[8];
    const float* convs_W  = (const float*)d_in[9];
    const float* convs_as = (const float*)d_in[10];
    const float* convs_ad = (const float*)d_in[11];
    const float* convs_b  = (const float*)d_in[12];
    const float* bn_g     = (const float*)d_in[13];
    const float* bn_b     = (const float*)d_in[14];
    const float* bn_m     = (const float*)d_in[15];
    const float* bn_v     = (const float*)d_in[16];
    const float* jump_W   = (const float*)d_in[17];
    const float* jump_b   = (const float*)d_in[18];
    const float* att_W    = (const float*)d_in[19];
    const float* att_b    = (const float*)d_in[20];
    const float* cls_W1   = (const float*)d_in[21];
    const float* cls_b1   = (const float*)d_in[22];
    const float* cls_W2   = (const float*)d_in[23];
    const float* cls_b2   = (const float*)d_in[24];
    float* out = (float*)d_out;

    const int N = in_sizes[0] / 128;   // 50000
    const int E = in_sizes[1] / 2;     // 400000
    const int Etot = E + N;
    const int nb = (N + SCAN_CHUNK - 1) / SCAN_CHUNK;   // 25 <= 64

    // workspace layout
    float* ws      = (float*)d_ws;
    unsigned short* xh_bf   = (unsigned short*)ws;          // N*256 bf16
    unsigned short* h256_bf = xh_bf + (size_t)N * 256;      // N*256 bf16
    float* repsAll = (float*)(h256_bf + (size_t)N * 256);   // N*192 f32
    float* as_n    = repsAll + (size_t)N * 192;             // N*4
    float* ad_n    = as_n + (size_t)N * 4;                  // N*4
    float* hjk     = ad_n + (size_t)N * 4;                  // N*64
    float* hg_acc  = hjk + (size_t)N * 64;                  // 64*64
    float* wsum_acc= hg_acc + NGRAPH * 64;                  // 64
    int*   rowptr  = (int*)(wsum_acc + NGRAPH);             // N+1
    int*   cursor  = rowptr + (N + 1);                      // N
    int*   counts  = cursor + N;                            // N
    int*   csr_src = counts + N;                            // Etot
    int*   gstart  = csr_src + Etot;                        // 65
    int*   blocksum = gstart + (NGRAPH + 1);                // 64
    int*   blockoff = blocksum + 64;                        // 65
    float* wbuf    = as_n;  // reuse (free after last layer)

    dim3 blk(256);
    int node_wave_blocks = (N + 3) / 4;
    int edge_blocks      = (Etot + 255) / 256;

    // ---------------- CSR build ----------------
    hipMemsetAsync(counts, 0, (size_t)N * sizeof(int), stream);
    hist_kernel<<<edge_blocks, blk, 0, stream>>>(ei, E, N, counts);
    scan_phase1<<<nb, blk, 0, stream>>>(counts, N, blocksum);
    scan_phase2<<<1, 64, 0, stream>>>(blocksum, nb, blockoff, rowptr, N);
    scan_phase3<<<nb, blk, 0, stream>>>(counts, N, blockoff, rowptr, cursor);
    scatter_kernel<<<edge_blocks, blk, 0, stream>>>(ei, E, N, cursor, csr_src);

    // ---------------- layer 0 ----------------
    {
        dim3 g1((N + 63) / 64, 4);
        gemm_xh_mfma<<<g1, blk, 0, stream>>>(x, 128, conv0_W, 256, N, 128,
                                             conv0_as, conv0_ad, as_n, ad_n, xh_bf);
        aggregate_kernel<<<node_wave_blocks, blk, 0, stream>>>(
            rowptr, csr_src, as_n, ad_n, xh_bf, conv0_b, (float*)h256_bf, 256, N, 0,
            nullptr, nullptr, nullptr, nullptr, nullptr);
        dim3 g2((N + 63) / 64, 1);
        gemm_n64_mfma<<<g2, blk, 0, stream>>>(h256_bf, 256, 1, pre0_W, N, 256,
                                              pre0_b, repsAll, 192, 1,
                                              bn_g, bn_b, bn_m, bn_v);
    }

    // ---------------- layers 1, 2 ----------------
    for (int i = 0; i < 2; ++i) {
        dim3 g1((N + 63) / 64, 4);
        gemm_xh_mfma<<<g1, blk, 0, stream>>>(repsAll + i * 64, 192,
                                             convs_W + (size_t)i * 64 * 256, 256, N, 64,
                                             convs_as + i * 256, convs_ad + i * 256,
                                             as_n, ad_n, xh_bf);
        aggregate_kernel<<<node_wave_blocks, blk, 0, stream>>>(
            rowptr, csr_src, as_n, ad_n, xh_bf, convs_b + i * 64,
            repsAll + (i + 1) * 64, 192, N, 1,
            bn_g + (i + 1) * 64, bn_b + (i + 1) * 64,
            bn_m + (i + 1) * 64, bn_v + (i + 1) * 64,
            repsAll + i * 64);
    }

    // ---------------- JK projection ----------------
    {
        dim3 g2((N + 63) / 64, 1);
        gemm_n64_mfma<<<g2, blk, 0, stream>>>(repsAll, 192, 0, jump_W, N, 192,
                                              jump_b, hjk, 64, 0,
                                              nullptr, nullptr, nullptr, nullptr);
    }

    // ---------------- pooling + classifier ----------------
    att_logit_kernel<<<node_wave_blocks, blk, 0, stream>>>(hjk, att_W, att_b, wbuf, N);
    gstart_kernel<<<1, 128, 0, stream>>>(batch, N, gstart);
    hipMemsetAsync(hg_acc, 0, (NGRAPH * 64 + NGRAPH) * sizeof(float), stream);
    pool_partial<<<POOL_BLOCKS, blk, 0, stream>>>(hjk, wbuf, batch, gstart,
                                                  hg_acc, wsum_acc, N);
    cls_kernel<<<NGRAPH, 32, 0, stream>>>(hg_acc, wsum_acc, cls_W1, cls_b1,
                                          cls_W2, cls_b2, out);
}

// Round 10
// 428.715 us; speedup vs baseline: 5.0513x; 1.0022x over previous
//
#include <hip/hip_runtime.h>
#include <hip/hip_bf16.h>
#include <math.h>

#define NEG 0.2f
#define BNEPS 1e-5f
#define NGRAPH 64
#define SCAN_CHUNK 2048
#define POOL_BLOCKS 256

typedef short bf16x8 __attribute__((ext_vector_type(8)));            // 8 bf16 (4 VGPRs)
typedef float f32x4  __attribute__((ext_vector_type(4)));            // MFMA accumulator
typedef unsigned short ushort8 __attribute__((ext_vector_type(8)));  // 16B bf16 load

__device__ __forceinline__ float bf2f(unsigned short u) {
    return __uint_as_float(((unsigned)u) << 16);
}
__device__ __forceinline__ short f2bf(float f) {
    return (short)__bfloat16_as_ushort(__float2bfloat16(f));
}

// ---------- MFMA bf16 GEMM for xh: Cbf[M,256] = bf16(A[M,K] @ W[K,256]) ----------
// + fused attention dots. grid (ceil(M/64), 4), block 256. head = blockIdx.y.
__global__ __launch_bounds__(256)
void gemm_xh_mfma(const float* __restrict__ A, int lda,
                  const float* __restrict__ W, int Nc, int M, int K,
                  const float* __restrict__ att_s, const float* __restrict__ att_d,
                  float* __restrict__ as_out, float* __restrict__ ad_out,
                  unsigned short* __restrict__ Cbf)
{
    __shared__ short Wt[64 * 136];           // max K=128 -> KP=136
    const int KP = K + 8;
    int tid  = threadIdx.x;
    int lane = tid & 63, wave = tid >> 6;
    int row0 = blockIdx.x * 64;
    int colb = blockIdx.y * 64;
    int c15 = lane & 15, q = lane >> 4;

    {
        int n = tid & 63;
        for (int k = tid >> 6; k < K; k += 4)
            Wt[n * KP + k] = f2bf(W[(size_t)k * Nc + colb + n]);
    }
    __syncthreads();

    int row = row0 + wave * 16 + c15;
    bool rok = row < M;
    const float* arow = A + (size_t)row * lda + q * 8;

    f32x4 acc[4];
    #pragma unroll
    for (int st = 0; st < 4; ++st) acc[st] = (f32x4){0.f, 0.f, 0.f, 0.f};

    for (int k0 = 0; k0 < K; k0 += 32) {
        bf16x8 av;
        if (rok) {
            float4 a0 = *(const float4*)(arow + k0);
            float4 a1 = *(const float4*)(arow + k0 + 4);
            av[0] = f2bf(a0.x); av[1] = f2bf(a0.y); av[2] = f2bf(a0.z); av[3] = f2bf(a0.w);
            av[4] = f2bf(a1.x); av[5] = f2bf(a1.y); av[6] = f2bf(a1.z); av[7] = f2bf(a1.w);
        } else {
            av = (bf16x8){0,0,0,0,0,0,0,0};
        }
        #pragma unroll
        for (int st = 0; st < 4; ++st) {
            bf16x8 bv = *(const bf16x8*)(Wt + (st * 16 + c15) * KP + k0 + q * 8);
            acc[st] = __builtin_amdgcn_mfma_f32_16x16x32_bf16(av, bv, acc[st], 0, 0, 0);
        }
    }

    #pragma unroll
    for (int r = 0; r < 4; ++r) {
        int orow = row0 + wave * 16 + q * 4 + r;
        if (orow >= M) continue;
        unsigned short* cb = Cbf + (size_t)orow * 256 + colb + c15;
        #pragma unroll
        for (int st = 0; st < 4; ++st)
            cb[st * 16] = (unsigned short)f2bf(acc[st][r]);
    }
    float sa[4], da[4];
    #pragma unroll
    for (int st = 0; st < 4; ++st) {
        sa[st] = att_s[colb + st * 16 + c15];
        da[st] = att_d[colb + st * 16 + c15];
    }
    #pragma unroll
    for (int r = 0; r < 4; ++r) {
        float ps = acc[0][r] * sa[0] + acc[1][r] * sa[1] + acc[2][r] * sa[2] + acc[3][r] * sa[3];
        float pd = acc[0][r] * da[0] + acc[1][r] * da[1] + acc[2][r] * da[2] + acc[3][r] * da[3];
        #pragma unroll
        for (int o = 1; o < 16; o <<= 1) {
            ps += __shfl_xor(ps, o);
            pd += __shfl_xor(pd, o);
        }
        int orow = row0 + wave * 16 + q * 4 + r;
        if (c15 == 0 && orow < M) {
            as_out[orow * 4 + blockIdx.y] = ps;
            ad_out[orow * 4 + blockIdx.y] = pd;
        }
    }
}

// ---------- MFMA bf16 GEMM, Nc=64 (pre0 / jump): C[M,64] = A[M,K] @ W[K,64] ----------
// mode 1: +bias, BN, ELU. If wout != null: also write wout[row] = exp(C_raw . attW + attb)
// (pool logits fused; uses post-bias C values).
__global__ __launch_bounds__(256)
void gemm_n64_mfma(const void* __restrict__ Araw, int lda, int a_is_bf16,
                   const float* __restrict__ W, int M, int K,
                   const float* __restrict__ bias,
                   float* __restrict__ C, int ldc, int mode,
                   const float* __restrict__ bn_g, const float* __restrict__ bn_b,
                   const float* __restrict__ bn_m, const float* __restrict__ bn_v,
                   const float* __restrict__ attW, const float* __restrict__ attb,
                   float* __restrict__ wout)
{
    __shared__ short Wt[64 * 264];           // max K=256 -> KP=264
    const int KP = K + 8;
    int tid  = threadIdx.x;
    int lane = tid & 63, wave = tid >> 6;
    int row0 = blockIdx.x * 64;
    int c15 = lane & 15, q = lane >> 4;

    {
        int n = tid & 63;
        for (int k = tid >> 6; k < K; k += 4)
            Wt[n * KP + k] = f2bf(W[(size_t)k * 64 + n]);
    }
    __syncthreads();

    int row = row0 + wave * 16 + c15;
    bool rok = row < M;

    f32x4 acc[4];
    #pragma unroll
    for (int st = 0; st < 4; ++st) acc[st] = (f32x4){0.f, 0.f, 0.f, 0.f};

    for (int k0 = 0; k0 < K; k0 += 32) {
        bf16x8 av;
        if (rok) {
            if (a_is_bf16) {
                av = *(const bf16x8*)((const unsigned short*)Araw
                                      + (size_t)row * lda + k0 + q * 8);
            } else {
                const float* ap = (const float*)Araw + (size_t)row * lda + k0 + q * 8;
                float4 a0 = *(const float4*)ap;
                float4 a1 = *(const float4*)(ap + 4);
                av[0] = f2bf(a0.x); av[1] = f2bf(a0.y); av[2] = f2bf(a0.z); av[3] = f2bf(a0.w);
                av[4] = f2bf(a1.x); av[5] = f2bf(a1.y); av[6] = f2bf(a1.z); av[7] = f2bf(a1.w);
            }
        } else {
            av = (bf16x8){0,0,0,0,0,0,0,0};
        }
        #pragma unroll
        for (int st = 0; st < 4; ++st) {
            bf16x8 bv = *(const bf16x8*)(Wt + (st * 16 + c15) * KP + k0 + q * 8);
            acc[st] = __builtin_amdgcn_mfma_f32_16x16x32_bf16(av, bv, acc[st], 0, 0, 0);
        }
    }

    // epilogue: col = st*16 + c15, row = row0 + wave*16 + q*4 + r
    #pragma unroll
    for (int st = 0; st < 4; ++st) {
        int col = st * 16 + c15;
        float bs = bias ? bias[col] : 0.f;
        float sg = 1.f, sb = 0.f;
        if (mode == 1) {
            sg = bn_g[col] / sqrtf(bn_v[col] + BNEPS);
            sb = bn_b[col] - bn_m[col] * sg;
        }
        #pragma unroll
        for (int r = 0; r < 4; ++r) {
            int orow = row0 + wave * 16 + q * 4 + r;
            if (orow >= M) continue;
            float v = acc[st][r] + bs;
            if (mode == 1) {
                v = v * sg + sb;
                v = v > 0.f ? v : __expf(v) - 1.f;
            }
            acc[st][r] = v;   // keep final value for fused pool logits
            C[(size_t)orow * ldc + col] = v;
        }
    }

    // fused pool logits: wout[row] = exp(sum_col C[row,col]*attW[col] + attb)
    if (wout) {
        float sa[4];
        #pragma unroll
        for (int st = 0; st < 4; ++st) sa[st] = attW[st * 16 + c15];
        float ab = attb[0];
        #pragma unroll
        for (int r = 0; r < 4; ++r) {
            float ps = acc[0][r] * sa[0] + acc[1][r] * sa[1]
                     + acc[2][r] * sa[2] + acc[3][r] * sa[3];
            #pragma unroll
            for (int o = 1; o < 16; o <<= 1) ps += __shfl_xor(ps, o);
            int orow = row0 + wave * 16 + q * 4 + r;
            if (c15 == 0 && orow < M) wout[orow] = __expf(ps + ab);
        }
    }
}

// ---------- CSR build: histogram over dst ----------
__global__ __launch_bounds__(256)
void hist_kernel(const int* __restrict__ ei, int E, int N, int* __restrict__ counts)
{
    int e = blockIdx.x * blockDim.x + threadIdx.x;
    int Etot = E + N;
    if (e >= Etot) return;
    int d = (e < E) ? ei[E + e] : e - E;
    atomicAdd(&counts[d], 1);
}

// ---------- scan phase 1 ----------
__global__ __launch_bounds__(256)
void scan_phase1(const int* __restrict__ counts, int N, int* __restrict__ blocksum)
{
    __shared__ int wsum[4];
    int tid = threadIdx.x, lane = tid & 63, wave = tid >> 6;
    int base = blockIdx.x * SCAN_CHUNK;
    int s = 0;
    #pragma unroll
    for (int j = 0; j < SCAN_CHUNK / 256; ++j) {
        int idx = base + tid + j * 256;
        if (idx < N) s += counts[idx];
    }
    #pragma unroll
    for (int o = 32; o; o >>= 1) s += __shfl_xor(s, o);
    if (lane == 0) wsum[wave] = s;
    __syncthreads();
    if (tid == 0) blocksum[blockIdx.x] = wsum[0] + wsum[1] + wsum[2] + wsum[3];
}

// ---------- scan phase 2 ----------
__global__ void scan_phase2(const int* __restrict__ blocksum, int nb,
                            int* __restrict__ blockoff, int* __restrict__ rowptr, int N)
{
    int lane = threadIdx.x;  // 64 threads
    int v = (lane < nb) ? blocksum[lane] : 0;
    int incl = v;
    #pragma unroll
    for (int o = 1; o < 64; o <<= 1) {
        int t = __shfl_up(incl, o);
        if (lane >= o) incl += t;
    }
    if (lane < nb) blockoff[lane + 1] = incl;
    if (lane == 0) blockoff[0] = 0;
    int total = __shfl(incl, nb - 1);
    if (lane == 0) rowptr[N] = total;
}

// ---------- scan phase 3 ----------
__global__ __launch_bounds__(256)
void scan_phase3(const int* __restrict__ counts, int N,
                 const int* __restrict__ blockoff,
                 int* __restrict__ rowptr, int* __restrict__ cursor)
{
    __shared__ int wsum[4];
    int tid = threadIdx.x, lane = tid & 63, wave = tid >> 6;
    int start = blockIdx.x * SCAN_CHUNK + tid * 8;
    int v[8];
    int s = 0;
    #pragma unroll
    for (int j = 0; j < 8; ++j) {
        v[j] = (start + j < N) ? counts[start + j] : 0;
        s += v[j];
    }
    int incl = s;
    #pragma unroll
    for (int o = 1; o < 64; o <<= 1) {
        int t = __shfl_up(incl, o);
        if (lane >= o) incl += t;
    }
    if (lane == 63) wsum[wave] = incl;
    __syncthreads();
    int woff = 0;
    #pragma unroll
    for (int w = 0; w < 4; ++w) if (w < wave) woff += wsum[w];
    int run = blockoff[blockIdx.x] + woff + incl - s;
    #pragma unroll
    for (int j = 0; j < 8; ++j) {
        int idx = start + j;
        if (idx < N) { rowptr[idx] = run; cursor[idx] = run; }
        run += v[j];
    }
}

// ---------- CSR build: scatter ----------
__global__ __launch_bounds__(256)
void scatter_kernel(const int* __restrict__ ei, int E, int N,
                    int* __restrict__ cursor, int* __restrict__ csr_src)
{
    int e = blockIdx.x * blockDim.x + threadIdx.x;
    int Etot = E + N;
    if (e >= Etot) return;
    int s, d;
    if (e < E) { s = ei[e]; d = ei[E + e]; } else { s = d = e - E; }
    int pos = atomicAdd(&cursor[d], 1);
    csr_src[pos] = s;
}

// ---------- fused per-node GAT aggregation v2 ----------
// One wave per node, split into two 32-lane halves; each half processes one
// edge per iteration with 16B/lane xh loads (lane li covers concat channels
// [li*8, li*8+8), head = li>>3). Halves combine via shfl_xor(32).
// mode 0: concat -> bf16 out (ushort8, lanes 0..31)
// mode 1: head-mean -> +bias, BN, ELU, +resid -> f32 (lanes 0..7, 2x float4)
__global__ __launch_bounds__(256)
void aggregate_kernel(const int* __restrict__ rowptr, const int* __restrict__ csr_src,
                      const float* __restrict__ as_n, const float* __restrict__ ad_n,
                      const unsigned short* __restrict__ xh,
                      const float* __restrict__ bias,
                      float* __restrict__ outp, int ldo,
                      int N, int mode,
                      const float* __restrict__ bn_g, const float* __restrict__ bn_b,
                      const float* __restrict__ bn_m, const float* __restrict__ bn_v,
                      const float* __restrict__ resid)
{
    int node = (blockIdx.x * blockDim.x + threadIdx.x) >> 6;
    int lane = threadIdx.x & 63;
    if (node >= N) return;
    int half = lane >> 5;      // which edge stream
    int li   = lane & 31;      // channel group: [li*8, li*8+8)
    int h    = li >> 3;        // head

    int e0 = rowptr[node], e1 = rowptr[node + 1];
    float adh = ad_n[node * 4 + h];

    float acc[8] = {0.f,0.f,0.f,0.f,0.f,0.f,0.f,0.f};
    float wsum = 0.f;

    int e = e0 + half;
    // ILP-2 within each half (up to 4 edges in flight per wave)
    for (; e + 2 < e1; e += 4) {
        int sA = csr_src[e], sB = csr_src[e + 2];
        ushort8 xvA = *(const ushort8*)(xh + (size_t)sA * 256 + li * 8);
        ushort8 xvB = *(const ushort8*)(xh + (size_t)sB * 256 + li * 8);
        float aA = as_n[sA * 4 + h];
        float aB = as_n[sB * 4 + h];
        float lA = aA + adh; lA = fmaxf(lA, NEG * lA);
        float lB = aB + adh; lB = fmaxf(lB, NEG * lB);
        float wA = __expf(lA), wB = __expf(lB);
        #pragma unroll
        for (int j = 0; j < 8; ++j) acc[j] += wA * bf2f(xvA[j]);
        #pragma unroll
        for (int j = 0; j < 8; ++j) acc[j] += wB * bf2f(xvB[j]);
        wsum += wA + wB;
    }
    for (; e < e1; e += 2) {
        int sA = csr_src[e];
        ushort8 xvA = *(const ushort8*)(xh + (size_t)sA * 256 + li * 8);
        float lA = as_n[sA * 4 + h] + adh;
        lA = fmaxf(lA, NEG * lA);
        float wA = __expf(lA);
        #pragma unroll
        for (int j = 0; j < 8; ++j) acc[j] += wA * bf2f(xvA[j]);
        wsum += wA;
    }

    // combine the two halves
    #pragma unroll
    for (int j = 0; j < 8; ++j) acc[j] += __shfl_xor(acc[j], 32);
    wsum += __shfl_xor(wsum, 32);
    float rw = 1.f / wsum;

    if (mode == 0) {
        if (half == 0) {
            int c0 = li * 8;
            ushort8 pk;
            #pragma unroll
            for (int j = 0; j < 8; ++j)
                pk[j] = (unsigned short)f2bf(acc[j] * rw + bias[c0 + j]);
            *(ushort8*)((unsigned short*)outp + (size_t)node * 256 + c0) = pk;
        }
    } else {
        #pragma unroll
        for (int j = 0; j < 8; ++j) acc[j] *= rw;      // per-head normalize
        // sum over the 4 heads (lanes li, li^8, li^16, li^24)
        #pragma unroll
        for (int j = 0; j < 8; ++j) {
            acc[j] += __shfl_xor(acc[j], 8);
            acc[j] += __shfl_xor(acc[j], 16);
        }
        if (lane < 8) {
            int cin = lane * 8;   // in-head channels cin..cin+8
            float res[8];
            #pragma unroll
            for (int j = 0; j < 8; ++j) {
                int c = cin + j;
                float v = 0.25f * acc[j] + bias[c];
                float sg = bn_g[c] / sqrtf(bn_v[c] + BNEPS);
                v = (v - bn_m[c]) * sg + bn_b[c];
                v = v > 0.f ? v : __expf(v) - 1.f;
                res[j] = v + resid[(size_t)node * ldo + c];
            }
            float* op = outp + (size_t)node * ldo + cin;
            *(float4*)op       = make_float4(res[0], res[1], res[2], res[3]);
            *(float4*)(op + 4) = make_float4(res[4], res[5], res[6], res[7]);
        }
    }
}

// ---------- graph boundaries ----------
__global__ void gstart_kernel(const int* __restrict__ batch, int N, int* __restrict__ gstart)
{
    int t = threadIdx.x;
    if (t > NGRAPH) return;
    int lo = 0, hi = N;
    while (lo < hi) {
        int mid = (lo + hi) >> 1;
        if (batch[mid] < t) lo = mid + 1; else hi = mid;
    }
    gstart[t] = lo;
}

// ---------- pooling partial sums ----------
__global__ __launch_bounds__(256)
void pool_partial(const float* __restrict__ hjk, const float* __restrict__ w,
                  const int* __restrict__ batch, const int* __restrict__ gstart,
                  float* __restrict__ hg_acc, float* __restrict__ wsum_acc, int N)
{
    __shared__ float red[256];
    __shared__ float wred[4];
    int tid = threadIdx.x;
    int c = tid & 63, q = tid >> 6;
    int slab = (N + POOL_BLOCKS - 1) / POOL_BLOCKS;
    int n0 = blockIdx.x * slab;
    int n1 = n0 + slab; if (n1 > N) n1 = N;
    if (n0 >= n1) return;
    int g0 = batch[n0], g1 = batch[n1 - 1];

    for (int g = g0; g <= g1; ++g) {
        int s = gstart[g];     if (s < n0) s = n0;
        int e = gstart[g + 1]; if (e > n1) e = n1;
        float acc = 0.f, ws = 0.f;
        for (int n = s + q; n < e; n += 4) {
            float wn = w[n];
            acc += wn * hjk[(size_t)n * 64 + c];
            if (c == 0) ws += wn;
        }
        red[tid] = acc;
        if (c == 0) wred[q] = ws;
        __syncthreads();
        if (q == 0) {
            float v = red[c] + red[64 + c] + red[128 + c] + red[192 + c];
            if (v != 0.f) atomicAdd(&hg_acc[g * 64 + c], v);
            if (c == 0) {
                float t = wred[0] + wred[1] + wred[2] + wred[3];
                if (t != 0.f) atomicAdd(&wsum_acc[g], t);
            }
        }
        __syncthreads();
    }
}

// ---------- classifier head ----------
__global__ void cls_kernel(const float* __restrict__ hg_acc,
                           const float* __restrict__ wsum_acc,
                           const float* __restrict__ W1, const float* __restrict__ b1,
                           const float* __restrict__ W2, const float* __restrict__ b2,
                           float* __restrict__ out)
{
    int g = blockIdx.x, t = threadIdx.x;  // 32 threads
    __shared__ float z[32];
    __shared__ float h[64];
    float wsum = wsum_acc[g];
    float rw = (wsum > 0.f) ? 1.f / wsum : 0.f;
    h[t] = hg_acc[g * 64 + t] * rw;
    h[t + 32] = hg_acc[g * 64 + t + 32] * rw;
    __syncthreads();
    float acc = b1[t];
    for (int k = 0; k < 64; ++k) acc += h[k] * W1[k * 32 + t];
    z[t] = fmaxf(acc, 0.f);
    __syncthreads();
    if (t < 2) {
        float o = b2[t];
        for (int j = 0; j < 32; ++j) o += z[j] * W2[j * 2 + t];
        out[g * 2 + t] = o;
    }
}

extern "C" void kernel_launch(void* const* d_in, const int* in_sizes, int n_in,
                              void* d_out, int out_size, void* d_ws, size_t ws_size,
                              hipStream_t stream)
{
    const float* x        = (const float*)d_in[0];
    const int*   ei       = (const int*)d_in[1];
    const int*   batch    = (const int*)d_in[2];
    const float* conv0_W  = (const float*)d_in[3];
    const float* conv0_as = (const float*)d_in[4];
    const float* conv0_ad = (const float*)d_in[5];
    const float* conv0_b  = (const float*)d_in[6];
    const float* pre0_W   = (const float*)d_in[7];
    const float* pre0_b   = (const float*)d_in[8];
    const float* convs_W  = (const float*)d_in[9];
    const float* convs_as = (const float*)d_in[10];
    const float* convs_ad = (const float*)d_in[11];
    const float* convs_b  = (const float*)d_in[12];
    const float* bn_g     = (const float*)d_in[13];
    const float* bn_b     = (const float*)d_in[14];
    const float* bn_m     = (const float*)d_in[15];
    const float* bn_v     = (const float*)d_in[16];
    const float* jump_W   = (const float*)d_in[17];
    const float* jump_b   = (const float*)d_in[18];
    const float* att_W    = (const float*)d_in[19];
    const float* att_b    = (const float*)d_in[20];
    const float* cls_W1   = (const float*)d_in[21];
    const float* cls_b1   = (const float*)d_in[22];
    const float* cls_W2   = (const float*)d_in[23];
    const float* cls_b2   = (const float*)d_in[24];
    float* out = (float*)d_out;

    const int N = in_sizes[0] / 128;   // 50000
    const int E = in_sizes[1] / 2;     // 400000
    const int Etot = E + N;
    const int nb = (N + SCAN_CHUNK - 1) / SCAN_CHUNK;   // 25 <= 64

    // workspace layout
    float* ws      = (float*)d_ws;
    unsigned short* xh_bf   = (unsigned short*)ws;          // N*256 bf16
    unsigned short* h256_bf = xh_bf + (size_t)N * 256;      // N*256 bf16
    float* repsAll = (float*)(h256_bf + (size_t)N * 256);   // N*192 f32
    float* as_n    = repsAll + (size_t)N * 192;             // N*4
    float* ad_n    = as_n + (size_t)N * 4;                  // N*4
    float* hjk     = ad_n + (size_t)N * 4;                  // N*64
    float* hg_acc  = hjk + (size_t)N * 64;                  // 64*64
    float* wsum_acc= hg_acc + NGRAPH * 64;                  // 64
    int*   rowptr  = (int*)(wsum_acc + NGRAPH);             // N+1
    int*   cursor  = rowptr + (N + 1);                      // N
    int*   counts  = cursor + N;                            // N
    int*   csr_src = counts + N;                            // Etot
    int*   gstart  = csr_src + Etot;                        // 65
    int*   blocksum = gstart + (NGRAPH + 1);                // 64
    int*   blockoff = blocksum + 64;                        // 65
    float* wbuf    = as_n;  // reuse (free after last layer)

    dim3 blk(256);
    int node_wave_blocks = (N + 3) / 4;
    int edge_blocks      = (Etot + 255) / 256;

    // ---------------- CSR build ----------------
    hipMemsetAsync(counts, 0, (size_t)N * sizeof(int), stream);
    hist_kernel<<<edge_blocks, blk, 0, stream>>>(ei, E, N, counts);
    scan_phase1<<<nb, blk, 0, stream>>>(counts, N, blocksum);
    scan_phase2<<<1, 64, 0, stream>>>(blocksum, nb, blockoff, rowptr, N);
    scan_phase3<<<nb, blk, 0, stream>>>(counts, N, blockoff, rowptr, cursor);
    scatter_kernel<<<edge_blocks, blk, 0, stream>>>(ei, E, N, cursor, csr_src);

    // ---------------- layer 0 ----------------
    {
        dim3 g1((N + 63) / 64, 4);
        gemm_xh_mfma<<<g1, blk, 0, stream>>>(x, 128, conv0_W, 256, N, 128,
                                             conv0_as, conv0_ad, as_n, ad_n, xh_bf);
        aggregate_kernel<<<node_wave_blocks, blk, 0, stream>>>(
            rowptr, csr_src, as_n, ad_n, xh_bf, conv0_b, (float*)h256_bf, 256, N, 0,
            nullptr, nullptr, nullptr, nullptr, nullptr);
        dim3 g2((N + 63) / 64, 1);
        gemm_n64_mfma<<<g2, blk, 0, stream>>>(h256_bf, 256, 1, pre0_W, N, 256,
                                              pre0_b, repsAll, 192, 1,
                                              bn_g, bn_b, bn_m, bn_v,
                                              nullptr, nullptr, nullptr);
    }

    // ---------------- layers 1, 2 ----------------
    for (int i = 0; i < 2; ++i) {
        dim3 g1((N + 63) / 64, 4);
        gemm_xh_mfma<<<g1, blk, 0, stream>>>(repsAll + i * 64, 192,
                                             convs_W + (size_t)i * 64 * 256, 256, N, 64,
                                             convs_as + i * 256, convs_ad + i * 256,
                                             as_n, ad_n, xh_bf);
        aggregate_kernel<<<node_wave_blocks, blk, 0, stream>>>(
            rowptr, csr_src, as_n, ad_n, xh_bf, convs_b + i * 64,
            repsAll + (i + 1) * 64, 192, N, 1,
            bn_g + (i + 1) * 64, bn_b + (i + 1) * 64,
            bn_m + (i + 1) * 64, bn_v + (i + 1) * 64,
            repsAll + i * 64);
    }

    // ---------------- JK projection + fused pool logits ----------------
    {
        dim3 g2((N + 63) / 64, 1);
        gemm_n64_mfma<<<g2, blk, 0, stream>>>(repsAll, 192, 0, jump_W, N, 192,
                                              jump_b, hjk, 64, 0,
                                              nullptr, nullptr, nullptr, nullptr,
                                              att_W, att_b, wbuf);
    }

    // ---------------- pooling + classifier ----------------
    gstart_kernel<<<1, 128, 0, stream>>>(batch, N, gstart);
    hipMemsetAsync(hg_acc, 0, (NGRAPH * 64 + NGRAPH) * sizeof(float), stream);
    pool_partial<<<POOL_BLOCKS, blk, 0, stream>>>(hjk, wbuf, batch, gstart,
                                                  hg_acc, wsum_acc, N);
    cls_kernel<<<NGRAPH, 32, 0, stream>>>(hg_acc, wsum_acc, cls_W1, cls_b1,
                                          cls_W2, cls_b2, out);
}